// Round 2
// baseline (1232.875 us; speedup 1.0000x reference)
//
#include <hip/hip_runtime.h>

#define DEV static __device__ __forceinline__

typedef __attribute__((ext_vector_type(8))) short v8s;
typedef __attribute__((ext_vector_type(4))) float v4f;

constexpr int Bn = 4, Sn = 1024, Dn = 768, NHn = 12, HDn = 64, En = 8, DFFn = 3072;
constexpr int Tn = Bn * Sn;          // 4096 tokens
constexpr int NROWS = 2 * Tn;        // 8192 gathered expert rows
constexpr int DHALF = DFFn / 2;      // 1536 (MoE processed in two DFF halves)
constexpr size_t MB = 1024 * 1024;

// ---- workspace map (~93.2 MB; lifetime-overlaid regions) ----
// era A (QKV):  [12,24) h1 hi/lo | [24,36) qf32 [36,48) kf32 [48,60) vf32 (atomic f32)
//   convs: q->[0,12) hi/lo, k->[24,36) hi/lo, v->[60,72) hi/lo; vtrans -> [72,84)
// era B (attn): q[0,12) k[24,36) vt[72,84) | phi[12,24) plo[48,60) | of[36,48) | rsum @84
// era C (proj): ohi/olo[0,12) | x2f[48,60) | woT @90.75
// era D (MoE):  eh[12,36) | whalf[60,78) | h2hi[78,84) | buf[36,48) | x2f[48,60)
// [84,93.2) wqkvTh wqkvTl woTh woTl | bqkv rwt gates ind meta rows ; rsum overlays wqkvTh

DEV float bf2f(unsigned short h) {
    union { unsigned int u; float f; } c; c.u = ((unsigned int)h) << 16; return c.f;
}
DEV unsigned short f2bf(float f) {   // round-to-nearest-even
    union { float f; unsigned int u; } c; c.f = f;
    return (unsigned short)((c.u + 0x7fffu + ((c.u >> 16) & 1u)) >> 16);
}
DEV v4f mfma16(v8s a, v8s b, v4f c) {
    return __builtin_amdgcn_mfma_f32_16x16x32_bf16(a, b, c, 0, 0, 0);
}

// ---------------- transpose fp32 src -> bf16 hi (+ optional lo) ----------------
__global__ __launch_bounds__(256) void transpose_f32(const float* __restrict__ src,
                                                     int src_ld, long src_zs,
                                                     unsigned short* __restrict__ dsthi,
                                                     unsigned short* __restrict__ dstlo,
                                                     int dst_ld, long dst_zs) {
    src += (long)blockIdx.z * src_zs;
    dsthi += (long)blockIdx.z * dst_zs;
    if (dstlo) dstlo += (long)blockIdx.z * dst_zs;
    __shared__ float tile[64][65];
    int tid = threadIdx.x, tx = blockIdx.x, ty = blockIdx.y;
    int r = tid >> 2, c0 = (tid & 3) * 16;
    const float* sp = src + (long)(ty * 64 + r) * src_ld + tx * 64 + c0;
#pragma unroll
    for (int i = 0; i < 4; ++i) {
        float4 f = *(const float4*)(sp + i * 4);
        tile[r][c0 + i * 4 + 0] = f.x;
        tile[r][c0 + i * 4 + 1] = f.y;
        tile[r][c0 + i * 4 + 2] = f.z;
        tile[r][c0 + i * 4 + 3] = f.w;
    }
    __syncthreads();
    int dl = tid >> 2, s0 = (tid & 3) * 16;
    unsigned short hh[16] __attribute__((aligned(16)));
    unsigned short ll[16] __attribute__((aligned(16)));
#pragma unroll
    for (int i = 0; i < 16; ++i) {
        float f = tile[s0 + i][dl];
        unsigned short h0 = f2bf(f);
        hh[i] = h0;
        ll[i] = f2bf(f - bf2f(h0));
    }
    long o = (long)(tx * 64 + dl) * dst_ld + ty * 64 + s0;
    *(uint4*)(dsthi + o) = ((uint4*)hh)[0];
    *(uint4*)(dsthi + o + 8) = ((uint4*)hh)[1];
    if (dstlo) {
        *(uint4*)(dstlo + o) = ((uint4*)ll)[0];
        *(uint4*)(dstlo + o + 8) = ((uint4*)ll)[1];
    }
}

// ---------------- LN1: f32 in -> split bf16 out ----------------
__global__ __launch_bounds__(256) void ln1_split(const float* __restrict__ in_f,
                                                 const float* __restrict__ sc,
                                                 const float* __restrict__ bi,
                                                 unsigned short* __restrict__ hi,
                                                 unsigned short* __restrict__ lo) {
    int row = blockIdx.x, tid = threadIdx.x;
    long base = (long)row * Dn;
    float x[3];
#pragma unroll
    for (int j = 0; j < 3; ++j) x[j] = in_f[base + tid + j * 256];
    __shared__ float red[4];
    float s = x[0] + x[1] + x[2];
    for (int off = 32; off; off >>= 1) s += __shfl_down(s, off, 64);
    if ((tid & 63) == 0) red[tid >> 6] = s;
    __syncthreads();
    float mean = (red[0] + red[1] + red[2] + red[3]) * (1.0f / Dn);
    __syncthreads();
    float ss = 0.f;
#pragma unroll
    for (int j = 0; j < 3; ++j) { float d0 = x[j] - mean; ss += d0 * d0; }
    for (int off = 32; off; off >>= 1) ss += __shfl_down(ss, off, 64);
    if ((tid & 63) == 0) red[tid >> 6] = ss;
    __syncthreads();
    float var = (red[0] + red[1] + red[2] + red[3]) * (1.0f / Dn);
    float rstd = 1.0f / sqrtf(var + 1e-5f);
#pragma unroll
    for (int j = 0; j < 3; ++j) {
        int d = tid + j * 256;
        float y = (x[j] - mean) * rstd * sc[d] + bi[d];
        unsigned short h0 = f2bf(y);
        hi[base + d] = h0;
        lo[base + d] = f2bf(y - bf2f(h0));
    }
}

// ---------------- LN2 fused with router (input = x2f + x residual) ----------------
__global__ __launch_bounds__(256) void ln2_router(const float* __restrict__ in_f,
                                                  const float* __restrict__ xres,
                                                  const float* __restrict__ sc,
                                                  const float* __restrict__ bi,
                                                  const float* __restrict__ rwt,
                                                  const float* __restrict__ rb,
                                                  const float* __restrict__ nb,
                                                  const float* __restrict__ noise,
                                                  unsigned short* __restrict__ h2hi,
                                                  float* __restrict__ gates,
                                                  int* __restrict__ ind) {
    int t = blockIdx.x, tid = threadIdx.x;
    int w = tid >> 6, lane = tid & 63;
    long base = (long)t * Dn;
    float x[3];
#pragma unroll
    for (int j = 0; j < 3; ++j) x[j] = in_f[base + tid + j * 256] + xres[base + tid + j * 256];
    __shared__ float red[4];
    float s = x[0] + x[1] + x[2];
    for (int off = 32; off; off >>= 1) s += __shfl_down(s, off, 64);
    if ((tid & 63) == 0) red[tid >> 6] = s;
    __syncthreads();
    float mean = (red[0] + red[1] + red[2] + red[3]) * (1.0f / Dn);
    __syncthreads();
    float ss = 0.f;
#pragma unroll
    for (int j = 0; j < 3; ++j) { float d0 = x[j] - mean; ss += d0 * d0; }
    for (int off = 32; off; off >>= 1) ss += __shfl_down(ss, off, 64);
    if ((tid & 63) == 0) red[tid >> 6] = ss;
    __syncthreads();
    float var = (red[0] + red[1] + red[2] + red[3]) * (1.0f / Dn);
    float rstd = 1.0f / sqrtf(var + 1e-5f);
    float y[3];
#pragma unroll
    for (int j = 0; j < 3; ++j) {
        int d = tid + j * 256;
        y[j] = (x[j] - mean) * rstd * sc[d] + bi[d];
        h2hi[base + d] = f2bf(y[j]);
    }
    float acc[16];
#pragma unroll
    for (int e = 0; e < 16; ++e) {
        const float* wp = rwt + e * Dn + tid;
        acc[e] = y[0] * wp[0] + y[1] * wp[256] + y[2] * wp[512];
    }
#pragma unroll
    for (int e = 0; e < 16; ++e)
        for (int off = 32; off; off >>= 1) acc[e] += __shfl_down(acc[e], off, 64);
    __shared__ float red2[4][16];
    if (lane == 0)
#pragma unroll
        for (int e = 0; e < 16; ++e) red2[w][e] = acc[e];
    __syncthreads();
    if (tid == 0) {
        float noisy[8];
#pragma unroll
        for (int e = 0; e < 8; ++e) {
            float lg = red2[0][e] + red2[1][e] + red2[2][e] + red2[3][e] + rb[e];
            float nv = red2[0][8 + e] + red2[1][8 + e] + red2[2][8 + e] + red2[3][8 + e] + nb[e];
            float sp = fmaxf(nv, 0.f) + log1pf(expf(-fabsf(nv)));
            noisy[e] = lg + noise[(long)t * En + e] * sp;
        }
        int i0 = 0;
        for (int e = 1; e < 8; ++e) if (noisy[e] > noisy[i0]) i0 = e;
        int i1 = (i0 == 0) ? 1 : 0;
        for (int e = 0; e < 8; ++e) if (e != i0 && noisy[e] > noisy[i1]) i1 = e;
        float mm = fmaxf(noisy[i0], noisy[i1]);
        float e0 = expf(noisy[i0] - mm), e1 = expf(noisy[i1] - mm);
        float inv = 1.0f / (e0 + e1);
        gates[t] = e0 * inv;
        gates[Tn + t] = e1 * inv;
        ind[t] = i0;
        ind[Tn + t] = i1;
    }
}

// ---------------- deterministic counting sort of 8192 (tok,slot) entries ----------------
__global__ __launch_bounds__(1024) void sort_rows(const int* __restrict__ ind,
                                                  int* __restrict__ meta,
                                                  int* __restrict__ rows) {
    __shared__ int hist[1024][8];
    __shared__ int bb[9];
    __shared__ int tot[8];
    int tid = threadIdx.x;
    int codes[8];
    int h[8] = {0, 0, 0, 0, 0, 0, 0, 0};
#pragma unroll
    for (int k = 0; k < 8; ++k) {
        int i = tid * 8 + k;
        int e = ind[(i & 1) * Tn + (i >> 1)];
        codes[k] = e;
        ++h[e];
    }
#pragma unroll
    for (int e = 0; e < 8; ++e) hist[tid][e] = h[e];
    __syncthreads();
    if (tid < 8) {
        int run = 0;
        for (int tt = 0; tt < 1024; ++tt) {
            int v = hist[tt][tid];
            hist[tt][tid] = run;
            run += v;
        }
        tot[tid] = run;
        meta[tid] = run;            // counts
    }
    __syncthreads();
    if (tid == 0) {
        int b = 0;
        for (int e = 0; e < 8; ++e) {
            bb[e] = b;
            meta[16 + e] = b;
            b += tot[e];
        }
        bb[8] = b;
        meta[24] = b;
    }
    __syncthreads();
    int c[8];
#pragma unroll
    for (int e = 0; e < 8; ++e) c[e] = hist[tid][e];
#pragma unroll
    for (int k = 0; k < 8; ++k) {
        int e = codes[k];
        rows[bb[e] + c[e]] = tid * 8 + k;   // value == t*2+slot
        ++c[e];
    }
}

// ---------------- tiny packers ----------------
__global__ void pack_router(const float* __restrict__ rw, const float* __restrict__ nw,
                            float* __restrict__ rwt) {
    int idx = blockIdx.x * 256 + threadIdx.x;   // [0, 16*768)
    int e = idx / Dn, d = idx - e * Dn;
    rwt[idx] = (e < 8) ? rw[d * En + e] : nw[d * En + (e - 8)];
}

__global__ void pack_bias(const float* __restrict__ bq, const float* __restrict__ bk,
                          const float* __restrict__ bv, float* __restrict__ bqkv) {
    int i = blockIdx.x * 256 + threadIdx.x;     // [0, 2304)
    bqkv[i] = (i < 768) ? bq[i] : (i < 1536 ? bk[i - 768] : bv[i - 1536]);
}

// ---------------- f32 -> split bf16 converter (with scale) ----------------
__global__ __launch_bounds__(256) void split_conv(const float* __restrict__ in,
                                                  unsigned short* __restrict__ hi,
                                                  unsigned short* __restrict__ lo,
                                                  float scale) {
    long i = ((long)blockIdx.x * 256 + threadIdx.x) * 4;
    float4 f = *(const float4*)(in + i);
    float vv[4] = {f.x * scale, f.y * scale, f.z * scale, f.w * scale};
    unsigned short hh[4] __attribute__((aligned(8)));
    unsigned short ll[4] __attribute__((aligned(8)));
#pragma unroll
    for (int j = 0; j < 4; ++j) {
        unsigned short h0 = f2bf(vv[j]);
        hh[j] = h0;
        ll[j] = f2bf(vv[j] - bf2f(h0));
    }
    *(uint2*)(hi + i) = *(uint2*)hh;
    *(uint2*)(lo + i) = *(uint2*)ll;
}

// ---------------- of * (1/rowsum) -> split bf16 (attn normalization) ----------------
__global__ __launch_bounds__(256) void scale_split_conv(const float* __restrict__ of,
                                                        const float* __restrict__ rsum,
                                                        unsigned short* __restrict__ hi,
                                                        unsigned short* __restrict__ lo) {
    long i = ((long)blockIdx.x * 256 + threadIdx.x) * 4;
    long t = i / Dn;
    int d = (int)(i - t * Dn);
    int b = (int)(t >> 10), s = (int)(t & 1023);
    int head = d >> 6;
    float inv = 1.0f / rsum[((long)b * 12 + head) * Sn + s];
    float4 f = *(const float4*)(of + i);
    float vv[4] = {f.x * inv, f.y * inv, f.z * inv, f.w * inv};
    unsigned short hh[4] __attribute__((aligned(8)));
    unsigned short ll[4] __attribute__((aligned(8)));
#pragma unroll
    for (int j = 0; j < 4; ++j) {
        unsigned short h0 = f2bf(vv[j]);
        hh[j] = h0;
        ll[j] = f2bf(vv[j] - bf2f(h0));
    }
    *(uint2*)(hi + i) = *(uint2*)hh;
    *(uint2*)(lo + i) = *(uint2*)ll;
}

// ---------------- pure-bf16 split GEMM, 128x128 tile, 3-product, K-splittable ----------------
// mode 0: f32 C (store or atomic), bias @ks==0, optional resid
// mode 1: QKV: cols [0,768)->Cf, [768,1536)->Ck, [1536,2304)->Cv, f32 atomicAdd
// mode 2: attn P: p=exp(acc) -> split bf16 phi/plo [zi][row][col], row-sums atomicAdd to rsum
__global__ __launch_bounds__(256) void gemm_bs(
    const unsigned short* __restrict__ Ahi, const unsigned short* __restrict__ Alo,
    int lda, long za,
    const unsigned short* __restrict__ Bhi, const unsigned short* __restrict__ Blo,
    int ldb, long zb,
    const float* __restrict__ bias, const float* __restrict__ resid,
    float* __restrict__ Cf, float* __restrict__ Ck, float* __restrict__ Cv,
    int ldc, long zc, int K, int zdiv, int catomic, int mode,
    unsigned short* __restrict__ phi, unsigned short* __restrict__ plo,
    float* __restrict__ rsum) {
    int z = blockIdx.z;
    int zi = z / zdiv, ks = z - zi * zdiv;
    int Klen = K / zdiv, k0base = ks * Klen;
    Ahi += (long)zi * za;
    Alo += (long)zi * za;
    Bhi += (long)zi * zb;
    Blo += (long)zi * zb;
    int n0 = blockIdx.x * 128, m0 = blockIdx.y * 128;
    int tid = threadIdx.x, w = tid >> 6, lane = tid & 63, quad = lane >> 4, l16 = lane & 15;
    int wm = w >> 1, wn = w & 1;
    __shared__ unsigned short Ah[128][40], Al[128][40], Bh[128][40], Bl[128][40];
    v4f acc[4][4] = {};
    int ar = tid >> 1, ac = (tid & 1) * 16;
    int nsteps = Klen >> 5;
    for (int kt = 0; kt < nsteps; ++kt) {
        int k0 = k0base + (kt << 5);
        const unsigned short* pah = Ahi + (long)(m0 + ar) * lda + k0 + ac;
        const unsigned short* pal = Alo + (long)(m0 + ar) * lda + k0 + ac;
        const unsigned short* pbh = Bhi + (long)(n0 + ar) * ldb + k0 + ac;
        const unsigned short* pbl = Blo + (long)(n0 + ar) * ldb + k0 + ac;
        uint4 ra0 = ((const uint4*)pah)[0], ra1 = ((const uint4*)pah)[1];
        uint4 rb0 = ((const uint4*)pal)[0], rb1 = ((const uint4*)pal)[1];
        uint4 rc0 = ((const uint4*)pbh)[0], rc1 = ((const uint4*)pbh)[1];
        uint4 rd0 = ((const uint4*)pbl)[0], rd1 = ((const uint4*)pbl)[1];
        *(uint4*)&Ah[ar][ac] = ra0;
        *(uint4*)&Ah[ar][ac + 8] = ra1;
        *(uint4*)&Al[ar][ac] = rb0;
        *(uint4*)&Al[ar][ac + 8] = rb1;
        *(uint4*)&Bh[ar][ac] = rc0;
        *(uint4*)&Bh[ar][ac + 8] = rc1;
        *(uint4*)&Bl[ar][ac] = rd0;
        *(uint4*)&Bl[ar][ac + 8] = rd1;
        __syncthreads();
        v8s afh[4], afl[4];
#pragma unroll
        for (int mt = 0; mt < 4; ++mt) {
            afh[mt] = *(const v8s*)&Ah[wm * 64 + mt * 16 + l16][quad * 8];
            afl[mt] = *(const v8s*)&Al[wm * 64 + mt * 16 + l16][quad * 8];
        }
#pragma unroll
        for (int nt = 0; nt < 4; ++nt) {
            v8s bbh = *(const v8s*)&Bh[wn * 64 + nt * 16 + l16][quad * 8];
            v8s bbl = *(const v8s*)&Bl[wn * 64 + nt * 16 + l16][quad * 8];
#pragma unroll
            for (int mt = 0; mt < 4; ++mt) acc[mt][nt] = mfma16(afh[mt], bbh, acc[mt][nt]);
#pragma unroll
            for (int mt = 0; mt < 4; ++mt) acc[mt][nt] = mfma16(afl[mt], bbh, acc[mt][nt]);
#pragma unroll
            for (int mt = 0; mt < 4; ++mt) acc[mt][nt] = mfma16(afh[mt], bbl, acc[mt][nt]);
        }
        __syncthreads();
    }
    if (mode == 2) {
        unsigned short* ph = phi + (long)zi * zc;
        unsigned short* pl = plo + (long)zi * zc;
        float* rs = rsum + (long)zi * Sn;
#pragma unroll
        for (int mt = 0; mt < 4; ++mt)
#pragma unroll
            for (int r = 0; r < 4; ++r) {
                int row = m0 + wm * 64 + mt * 16 + quad * 4 + r;
                float p[4];
#pragma unroll
                for (int nt = 0; nt < 4; ++nt) p[nt] = expf(acc[mt][nt][r]);
                float sum = p[0] + p[1] + p[2] + p[3];
#pragma unroll
                for (int off = 1; off < 16; off <<= 1) sum += __shfl_xor(sum, off, 64);
                if (l16 == 0) atomicAdd(rs + row, sum);
#pragma unroll
                for (int nt = 0; nt < 4; ++nt) {
                    int col = n0 + wn * 64 + nt * 16 + l16;
                    long ci = (long)row * ldc + col;
                    unsigned short h = f2bf(p[nt]);
                    ph[ci] = h;
                    pl[ci] = f2bf(p[nt] - bf2f(h));
                }
            }
    } else if (mode == 1) {
#pragma unroll
        for (int mt = 0; mt < 4; ++mt)
#pragma unroll
            for (int nt = 0; nt < 4; ++nt)
#pragma unroll
                for (int r = 0; r < 4; ++r) {
                    int row = m0 + wm * 64 + mt * 16 + quad * 4 + r;
                    int col = n0 + wn * 64 + nt * 16 + l16;
                    float v = acc[mt][nt][r];
                    if (ks == 0 && bias) v += bias[col];
                    int seg = (col >= 1536) ? 2 : (col >= 768 ? 1 : 0);
                    int c = col - seg * 768;
                    float* dst = (seg == 0) ? Cf : (seg == 1 ? Ck : Cv);
                    atomicAdd(&dst[(long)row * Dn + c], v);
                }
    } else {
        long coff = (long)zi * zc;
#pragma unroll
        for (int mt = 0; mt < 4; ++mt)
#pragma unroll
            for (int nt = 0; nt < 4; ++nt)
#pragma unroll
                for (int r = 0; r < 4; ++r) {
                    int row = m0 + wm * 64 + mt * 16 + quad * 4 + r;
                    int col = n0 + wn * 64 + nt * 16 + l16;
                    float v = acc[mt][nt][r];
                    if (ks == 0 && bias) v += bias[col];
                    long ci = coff + (long)row * ldc + col;
                    if (resid) v += resid[ci];
                    if (catomic) atomicAdd(&Cf[ci], v);
                    else Cf[ci] = v;
                }
    }
}

// ---------------- PV GEMM: A = split bf16 P (copy-staged), 128x64 tile, K-split atomic ----------
__global__ __launch_bounds__(256) void gemm_pv(
    const unsigned short* __restrict__ Ahi, const unsigned short* __restrict__ Alo,
    int lda, long za,
    const unsigned short* __restrict__ Bhi, const unsigned short* __restrict__ Blo,
    int ldb, long zb,
    float* __restrict__ Cf, int ldc, long zc, int K, int zdiv) {
    int z = blockIdx.z;
    int zi = z / zdiv, ks = z - zi * zdiv;
    int Klen = K / zdiv, k0base = ks * Klen;
    Ahi += (long)zi * za;
    Alo += (long)zi * za;
    Bhi += (long)zi * zb;
    Blo += (long)zi * zb;
    long coff = (long)zi * zc;
    int n0 = blockIdx.x * 64, m0 = blockIdx.y * 128;
    int tid = threadIdx.x, w = tid >> 6, lane = tid & 63, quad = lane >> 4, l16 = lane & 15;
    __shared__ unsigned short Ah[128][40], Al[128][40], Bh[64][40], Bl[64][40];
    v4f acc[2][4] = {};
    int ar = tid >> 1, ac = (tid & 1) * 16;
    int br = tid >> 2, bc = (tid & 3) * 8;
    int nsteps = Klen >> 5;
    for (int kt = 0; kt < nsteps; ++kt) {
        int k0 = k0base + (kt << 5);
        const unsigned short* pah = Ahi + (long)(m0 + ar) * lda + k0 + ac;
        const unsigned short* pal = Alo + (long)(m0 + ar) * lda + k0 + ac;
        *(uint4*)&Ah[ar][ac] = ((const uint4*)pah)[0];
        *(uint4*)&Ah[ar][ac + 8] = ((const uint4*)pah)[1];
        *(uint4*)&Al[ar][ac] = ((const uint4*)pal)[0];
        *(uint4*)&Al[ar][ac + 8] = ((const uint4*)pal)[1];
        const unsigned short* bph = Bhi + (long)(n0 + br) * ldb + (k0 + bc);
        const unsigned short* bpl = Blo + (long)(n0 + br) * ldb + (k0 + bc);
        *(uint4*)&Bh[br][bc] = *(const uint4*)bph;
        *(uint4*)&Bl[br][bc] = *(const uint4*)bpl;
        __syncthreads();
        v8s ah0 = *(const v8s*)&Ah[w * 32 + l16][quad * 8];
        v8s ah1 = *(const v8s*)&Ah[w * 32 + 16 + l16][quad * 8];
        v8s al0 = *(const v8s*)&Al[w * 32 + l16][quad * 8];
        v8s al1 = *(const v8s*)&Al[w * 32 + 16 + l16][quad * 8];
#pragma unroll
        for (int nt = 0; nt < 4; ++nt) {
            v8s bh = *(const v8s*)&Bh[nt * 16 + l16][quad * 8];
            v8s bl = *(const v8s*)&Bl[nt * 16 + l16][quad * 8];
            acc[0][nt] = mfma16(ah0, bh, acc[0][nt]);
            acc[1][nt] = mfma16(ah1, bh, acc[1][nt]);
            acc[0][nt] = mfma16(al0, bh, acc[0][nt]);
            acc[1][nt] = mfma16(al1, bh, acc[1][nt]);
            acc[0][nt] = mfma16(ah0, bl, acc[0][nt]);
            acc[1][nt] = mfma16(ah1, bl, acc[1][nt]);
        }
        __syncthreads();
    }
#pragma unroll
    for (int mt = 0; mt < 2; ++mt)
#pragma unroll
        for (int nt = 0; nt < 4; ++nt)
#pragma unroll
            for (int r = 0; r < 4; ++r) {
                int row = m0 + w * 32 + mt * 16 + quad * 4 + r;
                int col = n0 + nt * 16 + l16;
                long ci = coff + (long)row * ldc + col;
                atomicAdd(&Cf[ci], acc[mt][nt][r]);
            }
}

// ---------------- V transpose (bf16 hi/lo): v[b,s,h,d] -> vt[g=b*12+h][d][s] ----------
__global__ __launch_bounds__(256) void vtrans16(const unsigned short* __restrict__ vhi,
                                                const unsigned short* __restrict__ vlo,
                                                unsigned short* __restrict__ vthi,
                                                unsigned short* __restrict__ vtlo) {
    int g = blockIdx.z, b = g / NHn, h = g % NHn;
    int stile = blockIdx.x, tid = threadIdx.x;
    __shared__ unsigned short th[64][66], tl[64][66];
    int sl = tid >> 2, c0 = (tid & 3) * 16;
    long src = (long)(b * Sn + stile * 64 + sl) * Dn + h * 64 + c0;
    *(uint4*)&th[sl][c0] = *(const uint4*)(vhi + src);
    *(uint4*)&th[sl][c0 + 8] = *(const uint4*)(vhi + src + 8);
    *(uint4*)&tl[sl][c0] = *(const uint4*)(vlo + src);
    *(uint4*)&tl[sl][c0 + 8] = *(const uint4*)(vlo + src + 8);
    __syncthreads();
    int dl = tid >> 2, s0 = (tid & 3) * 16;
    unsigned short hh[16] __attribute__((aligned(16)));
    unsigned short ll[16] __attribute__((aligned(16)));
#pragma unroll
    for (int i = 0; i < 16; ++i) {
        hh[i] = th[s0 + i][dl];
        ll[i] = tl[s0 + i][dl];
    }
    long o = (long)(g * 64 + dl) * Sn + stile * 64 + s0;
    *(uint4*)(vthi + o) = ((uint4*)hh)[0];
    *(uint4*)(vthi + o + 8) = ((uint4*)hh)[1];
    *(uint4*)(vtlo + o) = ((uint4*)ll)[0];
    *(uint4*)(vtlo + o + 8) = ((uint4*)ll)[1];
}

// ---------------- MoE stage 1 (per DFF half): eh = relu(h2 @ W1t[e]^T + b1) ----------------
__global__ __launch_bounds__(256) void moe_gemm1(const unsigned short* __restrict__ h2hi,
                                                 const unsigned short* __restrict__ W1t,
                                                 const float* __restrict__ eb1,
                                                 const int* __restrict__ rows,
                                                 const int* __restrict__ meta,
                                                 unsigned short* __restrict__ eh,
                                                 int half) {
    int e = blockIdx.z;
    int cnt = meta[e];
    int mb = blockIdx.y * 128;
    if (mb >= cnt) return;
    int base_e = meta[16 + e];
    int valid = cnt - mb; if (valid > 128) valid = 128;
    int tid = threadIdx.x;
    __shared__ int toks[128];
    if (tid < 128) {
        int idx = mb + tid;
        toks[tid] = rows[base_e + (idx < cnt ? idx : 0)];
    }
    __shared__ unsigned short As[128][40], Bs[128][40];
    int w = tid >> 6, lane = tid & 63, quad = lane >> 4, l16 = lane & 15;
    int wm = w >> 1, wn = w & 1;
    v4f acc[4][4] = {};
    int ar = tid >> 1, ac = (tid & 1) * 16;
    int nb0 = blockIdx.x * 128;
    const unsigned short* Wb = W1t + (long)e * DHALF * Dn;
    __syncthreads();
    for (int kt = 0; kt < Dn / 32; ++kt) {
        int k0 = kt * 32;
        int tok = toks[ar] >> 1;
        const unsigned short* apg = h2hi + (long)tok * Dn + k0 + ac;
        uint4 u0 = ((const uint4*)apg)[0];
        uint4 u1 = ((const uint4*)apg)[1];
        *(uint4*)&As[ar][ac] = u0;
        *(uint4*)&As[ar][ac + 8] = u1;
        const unsigned short* bpg = Wb + (long)(nb0 + ar) * Dn + k0 + ac;
        *(uint4*)&Bs[ar][ac] = ((const uint4*)bpg)[0];
        *(uint4*)&Bs[ar][ac + 8] = ((const uint4*)bpg)[1];
        __syncthreads();
        v8s af[4];
#pragma unroll
        for (int mt = 0; mt < 4; ++mt) af[mt] = *(const v8s*)&As[wm * 64 + mt * 16 + l16][quad * 8];
#pragma unroll
        for (int nt = 0; nt < 4; ++nt) {
            v8s bb = *(const v8s*)&Bs[wn * 64 + nt * 16 + l16][quad * 8];
#pragma unroll
            for (int mt = 0; mt < 4; ++mt) acc[mt][nt] = mfma16(af[mt], bb, acc[mt][nt]);
        }
        __syncthreads();
    }
#pragma unroll
    for (int mt = 0; mt < 4; ++mt)
#pragma unroll
        for (int nt = 0; nt < 4; ++nt)
#pragma unroll
            for (int r = 0; r < 4; ++r) {
                int rl = wm * 64 + mt * 16 + quad * 4 + r;
                if (rl < valid) {
                    int col = nb0 + wn * 64 + nt * 16 + l16;
                    float v = acc[mt][nt][r] + eb1[e * DFFn + half * DHALF + col];
                    v = fmaxf(v, 0.f);
                    eh[(long)(base_e + mb + rl) * DHALF + col] = f2bf(v);
                }
            }
}

// ---------------- MoE stage 2 (per DFF half): buf[tok] += gate*(eh @ W2t[e]^T (+b2)) --------
__global__ __launch_bounds__(256) void moe_gemm2(const unsigned short* __restrict__ eh,
                                                 const unsigned short* __restrict__ W2t,
                                                 const float* __restrict__ eb2,
                                                 const int* __restrict__ rows,
                                                 const int* __restrict__ meta,
                                                 const float* __restrict__ gates,
                                                 float* __restrict__ buf) {
    int e = blockIdx.z;
    int cnt = meta[e];
    int mb = blockIdx.y * 128;
    if (mb >= cnt) return;
    int base_e = meta[16 + e];
    int valid = cnt - mb; if (valid > 128) valid = 128;
    int tid = threadIdx.x;
    __shared__ int toks[128];
    if (tid < 128) {
        int idx = mb + tid;
        toks[tid] = rows[base_e + (idx < cnt ? idx : 0)];
    }
    __shared__ unsigned short As[128][40], Bs[128][40];
    int w = tid >> 6, lane = tid & 63, quad = lane >> 4, l16 = lane & 15;
    int wm = w >> 1, wn = w & 1;
    v4f acc[4][4] = {};
    int ar = tid >> 1, ac = (tid & 1) * 16;
    int nb0 = blockIdx.x * 128;
    const unsigned short* Wb = W2t + (long)e * Dn * DHALF;
    __syncthreads();
    for (int kt = 0; kt < DHALF / 32; ++kt) {
        int k0 = kt * 32;
        long arow = (long)base_e + mb + ar;
        if (arow > NROWS - 1) arow = NROWS - 1;
        const unsigned short* apg = eh + arow * DHALF + k0 + ac;
        *(uint4*)&As[ar][ac] = ((const uint4*)apg)[0];
        *(uint4*)&As[ar][ac + 8] = ((const uint4*)apg)[1];
        const unsigned short* bpg = Wb + (long)(nb0 + ar) * DHALF + k0 + ac;
        *(uint4*)&Bs[ar][ac] = ((const uint4*)bpg)[0];
        *(uint4*)&Bs[ar][ac + 8] = ((const uint4*)bpg)[1];
        __syncthreads();
        v8s af[4];
#pragma unroll
        for (int mt = 0; mt < 4; ++mt) af[mt] = *(const v8s*)&As[wm * 64 + mt * 16 + l16][quad * 8];
#pragma unroll
        for (int nt = 0; nt < 4; ++nt) {
            v8s bb = *(const v8s*)&Bs[wn * 64 + nt * 16 + l16][quad * 8];
#pragma unroll
            for (int mt = 0; mt < 4; ++mt) acc[mt][nt] = mfma16(af[mt], bb, acc[mt][nt]);
        }
        __syncthreads();
    }
#pragma unroll
    for (int mt = 0; mt < 4; ++mt)
#pragma unroll
        for (int nt = 0; nt < 4; ++nt)
#pragma unroll
            for (int r = 0; r < 4; ++r) {
                int rl = wm * 64 + mt * 16 + quad * 4 + r;
                if (rl < valid) {
                    int col = nb0 + wn * 64 + nt * 16 + l16;
                    int code = toks[rl];
                    int tok = code >> 1, slot = code & 1;
                    float g = gates[slot * Tn + tok];
                    float v = acc[mt][nt][r];
                    if (eb2) v += eb2[e * Dn + col];
                    atomicAdd(&buf[(long)tok * Dn + col], v * g);
                }
            }
}

// ---------------- final: out(f32) = x + x2f + buf ----------------
__global__ __launch_bounds__(256) void final_add(const float* __restrict__ x2f,
                                                 const float* __restrict__ xres,
                                                 const float* __restrict__ buf,
                                                 float* __restrict__ out) {
    long i = ((long)blockIdx.x * 256 + threadIdx.x) * 4;
    float4 a = *(const float4*)(x2f + i);
    float4 xr = *(const float4*)(xres + i);
    float4 b = *(const float4*)(buf + i);
    float4 o = {a.x + xr.x + b.x, a.y + xr.y + b.y, a.z + xr.z + b.z, a.w + xr.w + b.w};
    *(float4*)(out + i) = o;
}

extern "C" void kernel_launch(void* const* d_in, const int* in_sizes, int n_in,
                              void* d_out, int out_size, void* d_ws, size_t ws_size,
                              hipStream_t stream) {
    const float* x     = (const float*)d_in[0];
    const float* noise = (const float*)d_in[1];
    const float* wq = (const float*)d_in[2];
    const float* bq = (const float*)d_in[3];
    const float* wk = (const float*)d_in[4];
    const float* bk = (const float*)d_in[5];
    const float* wv = (const float*)d_in[6];
    const float* bv = (const float*)d_in[7];
    const float* wo = (const float*)d_in[8];
    const float* bo = (const float*)d_in[9];
    const float* ln1_s = (const float*)d_in[10];
    const float* ln1_b = (const float*)d_in[11];
    const float* ln2_s = (const float*)d_in[12];
    const float* ln2_b = (const float*)d_in[13];
    const float* r_w = (const float*)d_in[14];
    const float* r_b = (const float*)d_in[15];
    const float* n_w = (const float*)d_in[16];
    const float* n_b = (const float*)d_in[17];
    const float* e_w1 = (const float*)d_in[18];
    const float* e_b1 = (const float*)d_in[19];
    const float* e_w2 = (const float*)d_in[20];
    const float* e_b2 = (const float*)d_in[21];

    char* ws = (char*)d_ws;
    unsigned short* qhi  = (unsigned short*)(ws + 0);        // era B
    unsigned short* qlo  = (unsigned short*)(ws + 6 * MB);
    unsigned short* ohi  = qhi;                              // era C reuse
    unsigned short* olo  = qlo;
    unsigned short* h1hi = (unsigned short*)(ws + 12 * MB);  // era A
    unsigned short* h1lo = (unsigned short*)(ws + 18 * MB);
    unsigned short* phi  = (unsigned short*)(ws + 12 * MB);  // era B (h1 dead)
    unsigned short* eh   = (unsigned short*)(ws + 12 * MB);  // era D (24 MB)
    float* qf32 = (float*)(ws + 24 * MB);                    // era A atomic f32 QKV out
    float* kf32 = (float*)(ws + 36 * MB);
    float* vf32 = (float*)(ws + 48 * MB);
    unsigned short* khi  = (unsigned short*)(ws + 24 * MB);  // era B (qf32 dead)
    unsigned short* klo  = (unsigned short*)(ws + 30 * MB);
    float* of   = (float*)(ws + 36 * MB);                    // era B (kf32 dead)
    float* buf  = of;                                        // era D
    unsigned short* plo  = (unsigned short*)(ws + 48 * MB);  // era B (vf32 dead)
    float* x2f  = (float*)(ws + 48 * MB);                    // era C/D (plo dead)
    unsigned short* vhi  = (unsigned short*)(ws + 60 * MB);  // era A/B
    unsigned short* vlo  = (unsigned short*)(ws + 66 * MB);
    unsigned short* whalf = (unsigned short*)(ws + 60 * MB); // era D (18 MB)
    unsigned short* vthi = (unsigned short*)(ws + 72 * MB);
    unsigned short* vtlo = (unsigned short*)(ws + 78 * MB);
    unsigned short* h2hi  = (unsigned short*)(ws + 78 * MB); // era D (vtlo dead)
    unsigned short* wqkvTh = (unsigned short*)(ws + 84 * MB);          // [2304][768]
    unsigned short* wqkvTl = wqkvTh + (size_t)3 * Dn * Dn;
    unsigned short* woTh = wqkvTl + (size_t)3 * Dn * Dn;
    unsigned short* woTl = woTh + (size_t)Dn * Dn;
    float* rsum = (float*)(ws + 84 * MB);                    // era B/C overlay (wqkvT dead)
    char* misc = (char*)(woTl + (size_t)Dn * Dn);
    float* bqkv = (float*)misc;                          // 2304 f
    float* rwt  = (float*)(misc + 2304 * 4);             // 16*768 f
    float* gates = (float*)(misc + 2304 * 4 + 12288 * 4);
    int* ind  = (int*)((char*)gates + 2 * Tn * 4);
    int* meta = (int*)((char*)ind + 2 * Tn * 4);
    int* rows = (int*)((char*)meta + 256);

    dim3 blk(256);
    // packed QKV weight transpose ([D,D] f32 -> bf16 hi/lo rows of [2304][768])
    transpose_f32<<<dim3(12, 12, 1), blk, 0, stream>>>(wq, Dn, 0, wqkvTh, wqkvTl, Dn, 0);
    transpose_f32<<<dim3(12, 12, 1), blk, 0, stream>>>(wk, Dn, 0,
        wqkvTh + (size_t)Dn * Dn, wqkvTl + (size_t)Dn * Dn, Dn, 0);
    transpose_f32<<<dim3(12, 12, 1), blk, 0, stream>>>(wv, Dn, 0,
        wqkvTh + (size_t)2 * Dn * Dn, wqkvTl + (size_t)2 * Dn * Dn, Dn, 0);
    transpose_f32<<<dim3(12, 12, 1), blk, 0, stream>>>(wo, Dn, 0, woTh, woTl, Dn, 0);
    pack_bias<<<dim3(9), blk, 0, stream>>>(bq, bk, bv, bqkv);
    pack_router<<<dim3(48), blk, 0, stream>>>(r_w, n_w, rwt);
    // LN1 -> split bf16
    ln1_split<<<dim3(Tn), blk, 0, stream>>>(x, ln1_s, ln1_b, h1hi, h1lo);
    // fused QKV: K-split (zdiv=2) pure-bf16 GEMM, atomic f32 into q/k/v buffers
    hipMemsetAsync(qf32, 0, (size_t)Tn * 2304 * 4, stream);
    gemm_bs<<<dim3(18, 32, 2), blk, 0, stream>>>(h1hi, h1lo, Dn, 0, wqkvTh, wqkvTl, Dn, 0,
        bqkv, nullptr, qf32, kf32, vf32, 0, 0, Dn, 2, 0, 1, nullptr, nullptr, nullptr);
    // split to bf16 hi/lo (q pre-scaled by 1/8); ORDER q,k,v (overlay hazards)
    split_conv<<<dim3(3072), blk, 0, stream>>>(qf32, qhi, qlo, 0.125f);
    split_conv<<<dim3(3072), blk, 0, stream>>>(kf32, khi, klo, 1.0f);
    split_conv<<<dim3(3072), blk, 0, stream>>>(vf32, vhi, vlo, 1.0f);
    vtrans16<<<dim3(16, 1, 48), blk, 0, stream>>>(vhi, vlo, vthi, vtlo);
    hipMemsetAsync(rsum, 0, (size_t)48 * Sn * 4, stream);
    hipMemsetAsync(of, 0, (size_t)Tn * Dn * 4, stream);
    // attention in chunks of 6 heads: QK^T+exp+rowsum fused, then PV (K-split atomic)
    for (int b = 0; b < 4; ++b) {
        for (int hg = 0; hg < 2; ++hg) {
            long tb = (long)b * Sn * Dn;
            int hoff = hg * 6 * 64;
            gemm_bs<<<dim3(8, 8, 6), blk, 0, stream>>>(
                qhi + tb + hoff, qlo + tb + hoff, Dn, 64,
                khi + tb + hoff, klo + tb + hoff, Dn, 64,
                nullptr, nullptr, nullptr, nullptr, nullptr,
                1024, (long)1024 * 1024, HDn, 1, 0, 2,
                phi, plo, rsum + (long)(b * 12 + hg * 6) * Sn);
            gemm_pv<<<dim3(1, 8, 96), blk, 0, stream>>>(
                phi, plo, 1024, (long)1024 * 1024,
                vthi + (long)(b * 12 + hg * 6) * 64 * 1024,
                vtlo + (long)(b * 12 + hg * 6) * 64 * 1024, 1024, (long)64 * 1024,
                of + tb + hoff, Dn, 64, Sn, 16);
        }
    }
    // normalize by row-sums + split to bf16, then output projection (K-split atomic)
    scale_split_conv<<<dim3(3072), blk, 0, stream>>>(of, rsum, ohi, olo);
    hipMemsetAsync(x2f, 0, (size_t)Tn * Dn * 4, stream);
    gemm_bs<<<dim3(6, 32, 4), blk, 0, stream>>>(ohi, olo, Dn, 0, woTh, woTl, Dn, 0,
        bo, nullptr, x2f, nullptr, nullptr, Dn, 0, Dn, 4, 1, 0, nullptr, nullptr, nullptr);
    // LN2 + router fused (residual x added on the fly; h2 stored bf16 for MoE)
    ln2_router<<<dim3(Tn), blk, 0, stream>>>(x2f, x, ln2_s, ln2_b, rwt, r_b, n_b, noise,
                                             h2hi, gates, ind);
    hipMemsetAsync(buf, 0, (size_t)Tn * Dn * 4, stream);
    sort_rows<<<dim3(1), dim3(1024), 0, stream>>>(ind, meta, rows);
    // sparse experts, two DFF halves through one 18 MB transposed-weight region
    for (int h = 0; h < 2; ++h) {
        transpose_f32<<<dim3(24, 12, 8), blk, 0, stream>>>(
            e_w1 + (size_t)h * DHALF, DFFn, (long)Dn * DFFn, whalf, nullptr, Dn, (long)DHALF * Dn);
        moe_gemm1<<<dim3(12, 32, 8), blk, 0, stream>>>(h2hi, whalf, e_b1, rows, meta, eh, h);
        transpose_f32<<<dim3(12, 24, 8), blk, 0, stream>>>(
            e_w2 + (size_t)h * DHALF * Dn, Dn, (long)DFFn * Dn, whalf, nullptr, DHALF, (long)Dn * DHALF);
        moe_gemm2<<<dim3(6, 32, 8), blk, 0, stream>>>(eh, whalf, h == 0 ? e_b2 : nullptr,
                                                      rows, meta, gates, buf);
    }
    final_add<<<dim3(Tn * Dn / 1024), blk, 0, stream>>>(x2f, x, buf, (float*)d_out);
}

// Round 3
// 1030.393 us; speedup vs baseline: 1.1965x; 1.1965x over previous
//
#include <hip/hip_runtime.h>

#define DEV static __device__ __forceinline__

typedef __attribute__((ext_vector_type(8))) short v8s;
typedef __attribute__((ext_vector_type(4))) float v4f;

constexpr int Bn = 4, Sn = 1024, Dn = 768, NHn = 12, HDn = 64, En = 8, DFFn = 3072;
constexpr int Tn = Bn * Sn;          // 4096 tokens
constexpr int NROWS = 2 * Tn;        // 8192 gathered expert rows
constexpr int DHALF = DFFn / 2;      // 1536 (MoE processed in two DFF halves)
constexpr size_t MB = 1024 * 1024;

// ---- workspace map (~93.2 MB; lifetime-overlaid regions) ----
// era A (QKV): h1 [12,24) ; QKV epilogue -> q[0,12) k[24,36) v[48,60) ; vtrans -> vt[72,84)
// era B (attn): q[0,12) k[24,36) vt[72,84) | phi[12,24) plo[60,72) | of[36,48) | rsum @84
// era C (proj): ohi/olo[0,12) (q dead) | x2f[48,60) (v dead) | woT @90.75
// era D (MoE): eh[12,36) | whalf[60,78) | h2hi[78,84) | buf[36,48) | x2f[48,60)
// [84,93.2) wqkvTh wqkvTl woTh woTl | bqkv rwt gates ind meta rows ; rsum overlays wqkvTh

DEV float bf2f(unsigned short h) {
    union { unsigned int u; float f; } c; c.u = ((unsigned int)h) << 16; return c.f;
}
DEV unsigned short f2bf(float f) {   // round-to-nearest-even
    union { float f; unsigned int u; } c; c.f = f;
    return (unsigned short)((c.u + 0x7fffu + ((c.u >> 16) & 1u)) >> 16);
}
DEV v4f mfma16(v8s a, v8s b, v4f c) {
    return __builtin_amdgcn_mfma_f32_16x16x32_bf16(a, b, c, 0, 0, 0);
}

// ---------------- transpose fp32 src -> bf16 hi (+ optional lo) ----------------
__global__ __launch_bounds__(256) void transpose_f32(const float* __restrict__ src,
                                                     int src_ld, long src_zs,
                                                     unsigned short* __restrict__ dsthi,
                                                     unsigned short* __restrict__ dstlo,
                                                     int dst_ld, long dst_zs) {
    src += (long)blockIdx.z * src_zs;
    dsthi += (long)blockIdx.z * dst_zs;
    if (dstlo) dstlo += (long)blockIdx.z * dst_zs;
    __shared__ float tile[64][65];
    int tid = threadIdx.x, tx = blockIdx.x, ty = blockIdx.y;
    int r = tid >> 2, c0 = (tid & 3) * 16;
    const float* sp = src + (long)(ty * 64 + r) * src_ld + tx * 64 + c0;
#pragma unroll
    for (int i = 0; i < 4; ++i) {
        float4 f = *(const float4*)(sp + i * 4);
        tile[r][c0 + i * 4 + 0] = f.x;
        tile[r][c0 + i * 4 + 1] = f.y;
        tile[r][c0 + i * 4 + 2] = f.z;
        tile[r][c0 + i * 4 + 3] = f.w;
    }
    __syncthreads();
    int dl = tid >> 2, s0 = (tid & 3) * 16;
    unsigned short hh[16] __attribute__((aligned(16)));
    unsigned short ll[16] __attribute__((aligned(16)));
#pragma unroll
    for (int i = 0; i < 16; ++i) {
        float f = tile[s0 + i][dl];
        unsigned short h0 = f2bf(f);
        hh[i] = h0;
        ll[i] = f2bf(f - bf2f(h0));
    }
    long o = (long)(tx * 64 + dl) * dst_ld + ty * 64 + s0;
    *(uint4*)(dsthi + o) = ((uint4*)hh)[0];
    *(uint4*)(dsthi + o + 8) = ((uint4*)hh)[1];
    if (dstlo) {
        *(uint4*)(dstlo + o) = ((uint4*)ll)[0];
        *(uint4*)(dstlo + o + 8) = ((uint4*)ll)[1];
    }
}

// ---------------- LN1: f32 in -> split bf16 out ----------------
__global__ __launch_bounds__(256) void ln1_split(const float* __restrict__ in_f,
                                                 const float* __restrict__ sc,
                                                 const float* __restrict__ bi,
                                                 unsigned short* __restrict__ hi,
                                                 unsigned short* __restrict__ lo) {
    int row = blockIdx.x, tid = threadIdx.x;
    long base = (long)row * Dn;
    float x[3];
#pragma unroll
    for (int j = 0; j < 3; ++j) x[j] = in_f[base + tid + j * 256];
    __shared__ float red[4];
    float s = x[0] + x[1] + x[2];
    for (int off = 32; off; off >>= 1) s += __shfl_down(s, off, 64);
    if ((tid & 63) == 0) red[tid >> 6] = s;
    __syncthreads();
    float mean = (red[0] + red[1] + red[2] + red[3]) * (1.0f / Dn);
    __syncthreads();
    float ss = 0.f;
#pragma unroll
    for (int j = 0; j < 3; ++j) { float d0 = x[j] - mean; ss += d0 * d0; }
    for (int off = 32; off; off >>= 1) ss += __shfl_down(ss, off, 64);
    if ((tid & 63) == 0) red[tid >> 6] = ss;
    __syncthreads();
    float var = (red[0] + red[1] + red[2] + red[3]) * (1.0f / Dn);
    float rstd = 1.0f / sqrtf(var + 1e-5f);
#pragma unroll
    for (int j = 0; j < 3; ++j) {
        int d = tid + j * 256;
        float y = (x[j] - mean) * rstd * sc[d] + bi[d];
        unsigned short h0 = f2bf(y);
        hi[base + d] = h0;
        lo[base + d] = f2bf(y - bf2f(h0));
    }
}

// ---------------- LN2 fused with router (input = x2f + x residual) ----------------
__global__ __launch_bounds__(256) void ln2_router(const float* __restrict__ in_f,
                                                  const float* __restrict__ xres,
                                                  const float* __restrict__ sc,
                                                  const float* __restrict__ bi,
                                                  const float* __restrict__ rwt,
                                                  const float* __restrict__ rb,
                                                  const float* __restrict__ nb,
                                                  const float* __restrict__ noise,
                                                  unsigned short* __restrict__ h2hi,
                                                  float* __restrict__ gates,
                                                  int* __restrict__ ind) {
    int t = blockIdx.x, tid = threadIdx.x;
    int w = tid >> 6, lane = tid & 63;
    long base = (long)t * Dn;
    float x[3];
#pragma unroll
    for (int j = 0; j < 3; ++j) x[j] = in_f[base + tid + j * 256] + xres[base + tid + j * 256];
    __shared__ float red[4];
    float s = x[0] + x[1] + x[2];
    for (int off = 32; off; off >>= 1) s += __shfl_down(s, off, 64);
    if ((tid & 63) == 0) red[tid >> 6] = s;
    __syncthreads();
    float mean = (red[0] + red[1] + red[2] + red[3]) * (1.0f / Dn);
    __syncthreads();
    float ss = 0.f;
#pragma unroll
    for (int j = 0; j < 3; ++j) { float d0 = x[j] - mean; ss += d0 * d0; }
    for (int off = 32; off; off >>= 1) ss += __shfl_down(ss, off, 64);
    if ((tid & 63) == 0) red[tid >> 6] = ss;
    __syncthreads();
    float var = (red[0] + red[1] + red[2] + red[3]) * (1.0f / Dn);
    float rstd = 1.0f / sqrtf(var + 1e-5f);
    float y[3];
#pragma unroll
    for (int j = 0; j < 3; ++j) {
        int d = tid + j * 256;
        y[j] = (x[j] - mean) * rstd * sc[d] + bi[d];
        h2hi[base + d] = f2bf(y[j]);
    }
    float acc[16];
#pragma unroll
    for (int e = 0; e < 16; ++e) {
        const float* wp = rwt + e * Dn + tid;
        acc[e] = y[0] * wp[0] + y[1] * wp[256] + y[2] * wp[512];
    }
#pragma unroll
    for (int e = 0; e < 16; ++e)
        for (int off = 32; off; off >>= 1) acc[e] += __shfl_down(acc[e], off, 64);
    __shared__ float red2[4][16];
    if (lane == 0)
#pragma unroll
        for (int e = 0; e < 16; ++e) red2[w][e] = acc[e];
    __syncthreads();
    if (tid == 0) {
        float noisy[8];
#pragma unroll
        for (int e = 0; e < 8; ++e) {
            float lg = red2[0][e] + red2[1][e] + red2[2][e] + red2[3][e] + rb[e];
            float nv = red2[0][8 + e] + red2[1][8 + e] + red2[2][8 + e] + red2[3][8 + e] + nb[e];
            float sp = fmaxf(nv, 0.f) + log1pf(expf(-fabsf(nv)));
            noisy[e] = lg + noise[(long)t * En + e] * sp;
        }
        int i0 = 0;
        for (int e = 1; e < 8; ++e) if (noisy[e] > noisy[i0]) i0 = e;
        int i1 = (i0 == 0) ? 1 : 0;
        for (int e = 0; e < 8; ++e) if (e != i0 && noisy[e] > noisy[i1]) i1 = e;
        float mm = fmaxf(noisy[i0], noisy[i1]);
        float e0 = expf(noisy[i0] - mm), e1 = expf(noisy[i1] - mm);
        float inv = 1.0f / (e0 + e1);
        gates[t] = e0 * inv;
        gates[Tn + t] = e1 * inv;
        ind[t] = i0;
        ind[Tn + t] = i1;
    }
}

// ---------------- counting sort of 8192 (tok,slot), parallel prefix ----------------
__global__ __launch_bounds__(1024) void sort_rows(const int* __restrict__ ind,
                                                  int* __restrict__ meta,
                                                  int* __restrict__ rows) {
    __shared__ int wtot[8][17];
    __shared__ int bb[8];
    int tid = threadIdx.x, wv = tid >> 6, ln = tid & 63;
    int codes[8];
    int h[8] = {0, 0, 0, 0, 0, 0, 0, 0};
#pragma unroll
    for (int k = 0; k < 8; ++k) {
        int i = tid * 8 + k;
        int e = ind[(i & 1) * Tn + (i >> 1)];
        codes[k] = e;
        ++h[e];
    }
    int pre[8];
#pragma unroll
    for (int e = 0; e < 8; ++e) {
        int x = h[e];
#pragma unroll
        for (int off = 1; off < 64; off <<= 1) {
            int y = __shfl_up(x, off, 64);
            if (ln >= off) x += y;
        }
        pre[e] = x - h[e];
        if (ln == 63) wtot[e][wv] = x;
    }
    __syncthreads();
    if (tid < 8) {
        int run = 0;
        for (int w2 = 0; w2 < 16; ++w2) {
            int v = wtot[tid][w2];
            wtot[tid][w2] = run;
            run += v;
        }
        wtot[tid][16] = run;
        meta[tid] = run;                 // counts
    }
    __syncthreads();
    if (tid == 0) {
        int b = 0;
        for (int e = 0; e < 8; ++e) {
            bb[e] = b;
            meta[16 + e] = b;
            b += wtot[e][16];
        }
        meta[24] = b;
    }
    __syncthreads();
    int c[8];
#pragma unroll
    for (int e = 0; e < 8; ++e) c[e] = bb[e] + wtot[e][wv] + pre[e];
#pragma unroll
    for (int k = 0; k < 8; ++k) {
        int e = codes[k];
        rows[c[e]] = tid * 8 + k;        // value == t*2+slot
        ++c[e];
    }
}

// ---------------- tiny packers ----------------
__global__ void pack_router(const float* __restrict__ rw, const float* __restrict__ nw,
                            float* __restrict__ rwt) {
    int idx = blockIdx.x * 256 + threadIdx.x;   // [0, 16*768)
    int e = idx / Dn, d = idx - e * Dn;
    rwt[idx] = (e < 8) ? rw[d * En + e] : nw[d * En + (e - 8)];
}

__global__ void pack_bias(const float* __restrict__ bq, const float* __restrict__ bk,
                          const float* __restrict__ bv, float* __restrict__ bqkv) {
    int i = blockIdx.x * 256 + threadIdx.x;     // [0, 2304)
    bqkv[i] = (i < 768) ? bq[i] : (i < 1536 ? bk[i - 768] : bv[i - 1536]);
}

// ---------------- of * (1/rowsum) -> split bf16 (attn normalization) ----------------
__global__ __launch_bounds__(256) void scale_split_conv(const float* __restrict__ of,
                                                        const float* __restrict__ rsum,
                                                        unsigned short* __restrict__ hi,
                                                        unsigned short* __restrict__ lo) {
    long i = ((long)blockIdx.x * 256 + threadIdx.x) * 4;
    long t = i / Dn;
    int d = (int)(i - t * Dn);
    int b = (int)(t >> 10), s = (int)(t & 1023);
    int head = d >> 6;
    float inv = 1.0f / rsum[((long)b * 12 + head) * Sn + s];
    float4 f = *(const float4*)(of + i);
    float vv[4] = {f.x * inv, f.y * inv, f.z * inv, f.w * inv};
    unsigned short hh[4] __attribute__((aligned(8)));
    unsigned short ll[4] __attribute__((aligned(8)));
#pragma unroll
    for (int j = 0; j < 4; ++j) {
        unsigned short h0 = f2bf(vv[j]);
        hh[j] = h0;
        ll[j] = f2bf(vv[j] - bf2f(h0));
    }
    *(uint2*)(hi + i) = *(uint2*)hh;
    *(uint2*)(lo + i) = *(uint2*)ll;
}

// ---------------- pure-bf16 split GEMM, 128x128 tile, 3-product, reg-pipelined ----------
// mode 0: f32 C store (or atomic), bias @ks==0  (o-proj)
// mode 1: QKV: cols [0,768)->q(*0.125), [768,1536)->k, [1536,2304)->v, split bf16 out
// mode 2: attn P: p=exp(acc) -> split bf16 phi/plo [zi][row][col], row-sums atomic to rsum
__global__ __launch_bounds__(256, 2) void gemm_bs(
    const unsigned short* __restrict__ Ahi, const unsigned short* __restrict__ Alo,
    int lda, long za,
    const unsigned short* __restrict__ Bhi, const unsigned short* __restrict__ Blo,
    int ldb, long zb,
    const float* __restrict__ bias,
    float* __restrict__ Cf, int ldc, long zc, int K, int zdiv, int catomic, int mode,
    unsigned short* __restrict__ oqh, unsigned short* __restrict__ oql,
    unsigned short* __restrict__ okh, unsigned short* __restrict__ okl,
    unsigned short* __restrict__ ovh, unsigned short* __restrict__ ovl,
    unsigned short* __restrict__ phi, unsigned short* __restrict__ plo,
    float* __restrict__ rsum) {
    int z = blockIdx.z;
    int zi = z / zdiv, ks = z - zi * zdiv;
    int Klen = K / zdiv, k0base = ks * Klen;
    Ahi += (long)zi * za;
    Alo += (long)zi * za;
    Bhi += (long)zi * zb;
    Blo += (long)zi * zb;
    int n0 = blockIdx.x * 128, m0 = blockIdx.y * 128;
    int tid = threadIdx.x, w = tid >> 6, lane = tid & 63, quad = lane >> 4, l16 = lane & 15;
    int wm = w >> 1, wn = w & 1;
    __shared__ unsigned short Ah[128][40], Al[128][40], Bh[128][40], Bl[128][40];
    v4f acc[4][4] = {};
    int ar = tid >> 1, ac = (tid & 1) * 16;
    const unsigned short* pah = Ahi + (long)(m0 + ar) * lda + k0base + ac;
    const unsigned short* pal = Alo + (long)(m0 + ar) * lda + k0base + ac;
    const unsigned short* pbh = Bhi + (long)(n0 + ar) * ldb + k0base + ac;
    const unsigned short* pbl = Blo + (long)(n0 + ar) * ldb + k0base + ac;
    int nsteps = Klen >> 5;
    uint4 ra0, ra1, rb0, rb1, rc0, rc1, rd0, rd1;
#define LOADK(kt) { int o_ = (kt) << 5; \
    ra0 = *(const uint4*)(pah + o_); ra1 = *(const uint4*)(pah + o_ + 8); \
    rb0 = *(const uint4*)(pal + o_); rb1 = *(const uint4*)(pal + o_ + 8); \
    rc0 = *(const uint4*)(pbh + o_); rc1 = *(const uint4*)(pbh + o_ + 8); \
    rd0 = *(const uint4*)(pbl + o_); rd1 = *(const uint4*)(pbl + o_ + 8); }
    LOADK(0);
    for (int kt = 0; kt < nsteps; ++kt) {
        *(uint4*)&Ah[ar][ac] = ra0;
        *(uint4*)&Ah[ar][ac + 8] = ra1;
        *(uint4*)&Al[ar][ac] = rb0;
        *(uint4*)&Al[ar][ac + 8] = rb1;
        *(uint4*)&Bh[ar][ac] = rc0;
        *(uint4*)&Bh[ar][ac + 8] = rc1;
        *(uint4*)&Bl[ar][ac] = rd0;
        *(uint4*)&Bl[ar][ac + 8] = rd1;
        __syncthreads();
        if (kt + 1 < nsteps) LOADK(kt + 1);   // issue early; hides under MFMA
        v8s afh[4], afl[4];
#pragma unroll
        for (int mt = 0; mt < 4; ++mt) {
            afh[mt] = *(const v8s*)&Ah[wm * 64 + mt * 16 + l16][quad * 8];
            afl[mt] = *(const v8s*)&Al[wm * 64 + mt * 16 + l16][quad * 8];
        }
#pragma unroll
        for (int nt = 0; nt < 4; ++nt) {
            v8s bbh = *(const v8s*)&Bh[wn * 64 + nt * 16 + l16][quad * 8];
            v8s bbl = *(const v8s*)&Bl[wn * 64 + nt * 16 + l16][quad * 8];
#pragma unroll
            for (int mt = 0; mt < 4; ++mt) acc[mt][nt] = mfma16(afh[mt], bbh, acc[mt][nt]);
#pragma unroll
            for (int mt = 0; mt < 4; ++mt) acc[mt][nt] = mfma16(afl[mt], bbh, acc[mt][nt]);
#pragma unroll
            for (int mt = 0; mt < 4; ++mt) acc[mt][nt] = mfma16(afh[mt], bbl, acc[mt][nt]);
        }
        __syncthreads();
    }
#undef LOADK
    if (mode == 2) {
        unsigned short* ph = phi + (long)zi * zc;
        unsigned short* pl = plo + (long)zi * zc;
        float* rs = rsum + (long)zi * Sn;
#pragma unroll
        for (int mt = 0; mt < 4; ++mt)
#pragma unroll
            for (int r = 0; r < 4; ++r) {
                int row = m0 + wm * 64 + mt * 16 + quad * 4 + r;
                float p[4];
#pragma unroll
                for (int nt = 0; nt < 4; ++nt) p[nt] = expf(acc[mt][nt][r]);
                float sum = p[0] + p[1] + p[2] + p[3];
#pragma unroll
                for (int off = 1; off < 16; off <<= 1) sum += __shfl_xor(sum, off, 64);
                if (l16 == 0) atomicAdd(rs + row, sum);
#pragma unroll
                for (int nt = 0; nt < 4; ++nt) {
                    int col = n0 + wn * 64 + nt * 16 + l16;
                    long ci = (long)row * ldc + col;
                    unsigned short h = f2bf(p[nt]);
                    ph[ci] = h;
                    pl[ci] = f2bf(p[nt] - bf2f(h));
                }
            }
    } else if (mode == 1) {
#pragma unroll
        for (int mt = 0; mt < 4; ++mt)
#pragma unroll
            for (int nt = 0; nt < 4; ++nt)
#pragma unroll
                for (int r = 0; r < 4; ++r) {
                    int row = m0 + wm * 64 + mt * 16 + quad * 4 + r;
                    int col = n0 + wn * 64 + nt * 16 + l16;
                    float v = acc[mt][nt][r] + bias[col];
                    int seg = (col >= 1536) ? 2 : (col >= 768 ? 1 : 0);
                    int c = col - seg * 768;
                    if (seg == 0) v *= 0.125f;   // fold 1/sqrt(HD) into q
                    long ci = (long)row * Dn + c;
                    unsigned short* dh = (seg == 0) ? oqh : (seg == 1 ? okh : ovh);
                    unsigned short* dl = (seg == 0) ? oql : (seg == 1 ? okl : ovl);
                    unsigned short h0 = f2bf(v);
                    dh[ci] = h0;
                    dl[ci] = f2bf(v - bf2f(h0));
                }
    } else {
        long coff = (long)zi * zc;
#pragma unroll
        for (int mt = 0; mt < 4; ++mt)
#pragma unroll
            for (int nt = 0; nt < 4; ++nt)
#pragma unroll
                for (int r = 0; r < 4; ++r) {
                    int row = m0 + wm * 64 + mt * 16 + quad * 4 + r;
                    int col = n0 + wn * 64 + nt * 16 + l16;
                    float v = acc[mt][nt][r];
                    if (ks == 0 && bias) v += bias[col];
                    long ci = coff + (long)row * ldc + col;
                    if (catomic) atomicAdd(&Cf[ci], v);
                    else Cf[ci] = v;
                }
    }
}

// ---------------- PV GEMM: split bf16 P x split V, 128x64 tile, K-split atomic, pipelined ----
__global__ __launch_bounds__(256, 2) void gemm_pv(
    const unsigned short* __restrict__ Ahi, const unsigned short* __restrict__ Alo,
    int lda, long za,
    const unsigned short* __restrict__ Bhi, const unsigned short* __restrict__ Blo,
    int ldb, long zb,
    float* __restrict__ Cf, int ldc, long zc, int K, int zdiv) {
    int z = blockIdx.z;
    int zi = z / zdiv, ks = z - zi * zdiv;
    int Klen = K / zdiv, k0base = ks * Klen;
    Ahi += (long)zi * za;
    Alo += (long)zi * za;
    Bhi += (long)zi * zb;
    Blo += (long)zi * zb;
    long coff = (long)zi * zc;
    int n0 = blockIdx.x * 64, m0 = blockIdx.y * 128;
    int tid = threadIdx.x, w = tid >> 6, lane = tid & 63, quad = lane >> 4, l16 = lane & 15;
    __shared__ unsigned short Ah[128][40], Al[128][40], Bh[64][40], Bl[64][40];
    v4f acc[2][4] = {};
    int ar = tid >> 1, ac = (tid & 1) * 16;
    int br = tid >> 2, bc = (tid & 3) * 8;
    const unsigned short* pah = Ahi + (long)(m0 + ar) * lda + k0base + ac;
    const unsigned short* pal = Alo + (long)(m0 + ar) * lda + k0base + ac;
    const unsigned short* pbh = Bhi + (long)(n0 + br) * ldb + k0base + bc;
    const unsigned short* pbl = Blo + (long)(n0 + br) * ldb + k0base + bc;
    int nsteps = Klen >> 5;
    uint4 ra0, ra1, rb0, rb1, rc0, rd0;
#define LOADK(kt) { int o_ = (kt) << 5; \
    ra0 = *(const uint4*)(pah + o_); ra1 = *(const uint4*)(pah + o_ + 8); \
    rb0 = *(const uint4*)(pal + o_); rb1 = *(const uint4*)(pal + o_ + 8); \
    rc0 = *(const uint4*)(pbh + o_); rd0 = *(const uint4*)(pbl + o_); }
    LOADK(0);
    for (int kt = 0; kt < nsteps; ++kt) {
        *(uint4*)&Ah[ar][ac] = ra0;
        *(uint4*)&Ah[ar][ac + 8] = ra1;
        *(uint4*)&Al[ar][ac] = rb0;
        *(uint4*)&Al[ar][ac + 8] = rb1;
        *(uint4*)&Bh[br][bc] = rc0;
        *(uint4*)&Bl[br][bc] = rd0;
        __syncthreads();
        if (kt + 1 < nsteps) LOADK(kt + 1);
        v8s ah0 = *(const v8s*)&Ah[w * 32 + l16][quad * 8];
        v8s ah1 = *(const v8s*)&Ah[w * 32 + 16 + l16][quad * 8];
        v8s al0 = *(const v8s*)&Al[w * 32 + l16][quad * 8];
        v8s al1 = *(const v8s*)&Al[w * 32 + 16 + l16][quad * 8];
#pragma unroll
        for (int nt = 0; nt < 4; ++nt) {
            v8s bh = *(const v8s*)&Bh[nt * 16 + l16][quad * 8];
            v8s bl = *(const v8s*)&Bl[nt * 16 + l16][quad * 8];
            acc[0][nt] = mfma16(ah0, bh, acc[0][nt]);
            acc[1][nt] = mfma16(ah1, bh, acc[1][nt]);
            acc[0][nt] = mfma16(al0, bh, acc[0][nt]);
            acc[1][nt] = mfma16(al1, bh, acc[1][nt]);
            acc[0][nt] = mfma16(ah0, bl, acc[0][nt]);
            acc[1][nt] = mfma16(ah1, bl, acc[1][nt]);
        }
        __syncthreads();
    }
#undef LOADK
#pragma unroll
    for (int mt = 0; mt < 2; ++mt)
#pragma unroll
        for (int nt = 0; nt < 4; ++nt)
#pragma unroll
            for (int r = 0; r < 4; ++r) {
                int row = m0 + w * 32 + mt * 16 + quad * 4 + r;
                int col = n0 + nt * 16 + l16;
                long ci = coff + (long)row * ldc + col;
                atomicAdd(&Cf[ci], acc[mt][nt][r]);
            }
}

// ---------------- V transpose (bf16 hi/lo): v[b,s,h,d] -> vt[g=b*12+h][d][s] ----------
__global__ __launch_bounds__(256) void vtrans16(const unsigned short* __restrict__ vhi,
                                                const unsigned short* __restrict__ vlo,
                                                unsigned short* __restrict__ vthi,
                                                unsigned short* __restrict__ vtlo) {
    int g = blockIdx.z, b = g / NHn, h = g % NHn;
    int stile = blockIdx.x, tid = threadIdx.x;
    __shared__ unsigned short th[64][66], tl[64][66];
    int sl = tid >> 2, c0 = (tid & 3) * 16;
    long src = (long)(b * Sn + stile * 64 + sl) * Dn + h * 64 + c0;
    *(uint4*)&th[sl][c0] = *(const uint4*)(vhi + src);
    *(uint4*)&th[sl][c0 + 8] = *(const uint4*)(vhi + src + 8);
    *(uint4*)&tl[sl][c0] = *(const uint4*)(vlo + src);
    *(uint4*)&tl[sl][c0 + 8] = *(const uint4*)(vlo + src + 8);
    __syncthreads();
    int dl = tid >> 2, s0 = (tid & 3) * 16;
    unsigned short hh[16] __attribute__((aligned(16)));
    unsigned short ll[16] __attribute__((aligned(16)));
#pragma unroll
    for (int i = 0; i < 16; ++i) {
        hh[i] = th[s0 + i][dl];
        ll[i] = tl[s0 + i][dl];
    }
    long o = (long)(g * 64 + dl) * Sn + stile * 64 + s0;
    *(uint4*)(vthi + o) = ((uint4*)hh)[0];
    *(uint4*)(vthi + o + 8) = ((uint4*)hh)[1];
    *(uint4*)(vtlo + o) = ((uint4*)ll)[0];
    *(uint4*)(vtlo + o + 8) = ((uint4*)ll)[1];
}

// ---------------- MoE stage 1 (per DFF half): eh = relu(h2 @ W1t[e]^T + b1), pipelined ----
__global__ __launch_bounds__(256, 2) void moe_gemm1(const unsigned short* __restrict__ h2hi,
                                                    const unsigned short* __restrict__ W1t,
                                                    const float* __restrict__ eb1,
                                                    const int* __restrict__ rows,
                                                    const int* __restrict__ meta,
                                                    unsigned short* __restrict__ eh,
                                                    int half) {
    int e = blockIdx.z;
    int cnt = meta[e];
    int mb = blockIdx.y * 128;
    if (mb >= cnt) return;
    int base_e = meta[16 + e];
    int valid = cnt - mb; if (valid > 128) valid = 128;
    int tid = threadIdx.x;
    __shared__ int toks[128];
    if (tid < 128) {
        int idx = mb + tid;
        toks[tid] = rows[base_e + (idx < cnt ? idx : 0)];
    }
    __shared__ unsigned short As[128][40], Bs[128][40];
    int w = tid >> 6, lane = tid & 63, quad = lane >> 4, l16 = lane & 15;
    int wm = w >> 1, wn = w & 1;
    v4f acc[4][4] = {};
    int ar = tid >> 1, ac = (tid & 1) * 16;
    int nb0 = blockIdx.x * 128;
    const unsigned short* Wb = W1t + (long)e * DHALF * Dn;
    __syncthreads();
    const unsigned short* apg = h2hi + (long)(toks[ar] >> 1) * Dn + ac;
    const unsigned short* bpg = Wb + (long)(nb0 + ar) * Dn + ac;
    uint4 a0, a1, b0, b1;
#define LOADK(kt) { int o_ = (kt) * 32; \
    a0 = *(const uint4*)(apg + o_); a1 = *(const uint4*)(apg + o_ + 8); \
    b0 = *(const uint4*)(bpg + o_); b1 = *(const uint4*)(bpg + o_ + 8); }
    LOADK(0);
    for (int kt = 0; kt < Dn / 32; ++kt) {
        *(uint4*)&As[ar][ac] = a0;
        *(uint4*)&As[ar][ac + 8] = a1;
        *(uint4*)&Bs[ar][ac] = b0;
        *(uint4*)&Bs[ar][ac + 8] = b1;
        __syncthreads();
        if (kt + 1 < Dn / 32) LOADK(kt + 1);
        v8s af[4];
#pragma unroll
        for (int mt = 0; mt < 4; ++mt) af[mt] = *(const v8s*)&As[wm * 64 + mt * 16 + l16][quad * 8];
#pragma unroll
        for (int nt = 0; nt < 4; ++nt) {
            v8s bb = *(const v8s*)&Bs[wn * 64 + nt * 16 + l16][quad * 8];
#pragma unroll
            for (int mt = 0; mt < 4; ++mt) acc[mt][nt] = mfma16(af[mt], bb, acc[mt][nt]);
        }
        __syncthreads();
    }
#undef LOADK
#pragma unroll
    for (int mt = 0; mt < 4; ++mt)
#pragma unroll
        for (int nt = 0; nt < 4; ++nt)
#pragma unroll
            for (int r = 0; r < 4; ++r) {
                int rl = wm * 64 + mt * 16 + quad * 4 + r;
                if (rl < valid) {
                    int col = nb0 + wn * 64 + nt * 16 + l16;
                    float v = acc[mt][nt][r] + eb1[e * DFFn + half * DHALF + col];
                    v = fmaxf(v, 0.f);
                    eh[(long)(base_e + mb + rl) * DHALF + col] = f2bf(v);
                }
            }
}

// ---------------- MoE stage 2 (per DFF half): buf[tok] += gate*(eh @ W2t[e]^T (+b2)) ------
__global__ __launch_bounds__(256, 2) void moe_gemm2(const unsigned short* __restrict__ eh,
                                                    const unsigned short* __restrict__ W2t,
                                                    const float* __restrict__ eb2,
                                                    const int* __restrict__ rows,
                                                    const int* __restrict__ meta,
                                                    const float* __restrict__ gates,
                                                    float* __restrict__ buf) {
    int e = blockIdx.z;
    int cnt = meta[e];
    int mb = blockIdx.y * 128;
    if (mb >= cnt) return;
    int base_e = meta[16 + e];
    int valid = cnt - mb; if (valid > 128) valid = 128;
    int tid = threadIdx.x;
    __shared__ int toks[128];
    if (tid < 128) {
        int idx = mb + tid;
        toks[tid] = rows[base_e + (idx < cnt ? idx : 0)];
    }
    __shared__ unsigned short As[128][40], Bs[128][40];
    int w = tid >> 6, lane = tid & 63, quad = lane >> 4, l16 = lane & 15;
    int wm = w >> 1, wn = w & 1;
    v4f acc[4][4] = {};
    int ar = tid >> 1, ac = (tid & 1) * 16;
    int nb0 = blockIdx.x * 128;
    const unsigned short* Wb = W2t + (long)e * Dn * DHALF;
    long arow = (long)base_e + mb + ar;
    if (arow > NROWS - 1) arow = NROWS - 1;
    const unsigned short* apg = eh + arow * DHALF + ac;
    const unsigned short* bpg = Wb + (long)(nb0 + ar) * DHALF + ac;
    __syncthreads();
    uint4 a0, a1, b0, b1;
#define LOADK(kt) { int o_ = (kt) * 32; \
    a0 = *(const uint4*)(apg + o_); a1 = *(const uint4*)(apg + o_ + 8); \
    b0 = *(const uint4*)(bpg + o_); b1 = *(const uint4*)(bpg + o_ + 8); }
    LOADK(0);
    for (int kt = 0; kt < DHALF / 32; ++kt) {
        *(uint4*)&As[ar][ac] = a0;
        *(uint4*)&As[ar][ac + 8] = a1;
        *(uint4*)&Bs[ar][ac] = b0;
        *(uint4*)&Bs[ar][ac + 8] = b1;
        __syncthreads();
        if (kt + 1 < DHALF / 32) LOADK(kt + 1);
        v8s af[4];
#pragma unroll
        for (int mt = 0; mt < 4; ++mt) af[mt] = *(const v8s*)&As[wm * 64 + mt * 16 + l16][quad * 8];
#pragma unroll
        for (int nt = 0; nt < 4; ++nt) {
            v8s bb = *(const v8s*)&Bs[wn * 64 + nt * 16 + l16][quad * 8];
#pragma unroll
            for (int mt = 0; mt < 4; ++mt) acc[mt][nt] = mfma16(af[mt], bb, acc[mt][nt]);
        }
        __syncthreads();
    }
#undef LOADK
#pragma unroll
    for (int mt = 0; mt < 4; ++mt)
#pragma unroll
        for (int nt = 0; nt < 4; ++nt)
#pragma unroll
            for (int r = 0; r < 4; ++r) {
                int rl = wm * 64 + mt * 16 + quad * 4 + r;
                if (rl < valid) {
                    int col = nb0 + wn * 64 + nt * 16 + l16;
                    int code = toks[rl];
                    int tok = code >> 1, slot = code & 1;
                    float g = gates[slot * Tn + tok];
                    float v = acc[mt][nt][r];
                    if (eb2) v += eb2[e * Dn + col];
                    atomicAdd(&buf[(long)tok * Dn + col], v * g);
                }
            }
}

// ---------------- final: out(f32) = x + x2f + buf ----------------
__global__ __launch_bounds__(256) void final_add(const float* __restrict__ x2f,
                                                 const float* __restrict__ xres,
                                                 const float* __restrict__ buf,
                                                 float* __restrict__ out) {
    long i = ((long)blockIdx.x * 256 + threadIdx.x) * 4;
    float4 a = *(const float4*)(x2f + i);
    float4 xr = *(const float4*)(xres + i);
    float4 b = *(const float4*)(buf + i);
    float4 o = {a.x + xr.x + b.x, a.y + xr.y + b.y, a.z + xr.z + b.z, a.w + xr.w + b.w};
    *(float4*)(out + i) = o;
}

extern "C" void kernel_launch(void* const* d_in, const int* in_sizes, int n_in,
                              void* d_out, int out_size, void* d_ws, size_t ws_size,
                              hipStream_t stream) {
    const float* x     = (const float*)d_in[0];
    const float* noise = (const float*)d_in[1];
    const float* wq = (const float*)d_in[2];
    const float* bq = (const float*)d_in[3];
    const float* wk = (const float*)d_in[4];
    const float* bk = (const float*)d_in[5];
    const float* wv = (const float*)d_in[6];
    const float* bv = (const float*)d_in[7];
    const float* wo = (const float*)d_in[8];
    const float* bo = (const float*)d_in[9];
    const float* ln1_s = (const float*)d_in[10];
    const float* ln1_b = (const float*)d_in[11];
    const float* ln2_s = (const float*)d_in[12];
    const float* ln2_b = (const float*)d_in[13];
    const float* r_w = (const float*)d_in[14];
    const float* r_b = (const float*)d_in[15];
    const float* n_w = (const float*)d_in[16];
    const float* n_b = (const float*)d_in[17];
    const float* e_w1 = (const float*)d_in[18];
    const float* e_b1 = (const float*)d_in[19];
    const float* e_w2 = (const float*)d_in[20];
    const float* e_b2 = (const float*)d_in[21];

    char* ws = (char*)d_ws;
    unsigned short* qhi  = (unsigned short*)(ws + 0);
    unsigned short* qlo  = (unsigned short*)(ws + 6 * MB);
    unsigned short* ohi  = qhi;                              // era C reuse
    unsigned short* olo  = qlo;
    unsigned short* h1hi = (unsigned short*)(ws + 12 * MB);  // era A
    unsigned short* h1lo = (unsigned short*)(ws + 18 * MB);
    unsigned short* phi  = (unsigned short*)(ws + 12 * MB);  // era B (h1 dead)
    unsigned short* eh   = (unsigned short*)(ws + 12 * MB);  // era D (24 MB)
    unsigned short* khi  = (unsigned short*)(ws + 24 * MB);
    unsigned short* klo  = (unsigned short*)(ws + 30 * MB);
    float* of   = (float*)(ws + 36 * MB);                    // era B PV accum
    float* buf  = of;                                        // era D
    unsigned short* vhi  = (unsigned short*)(ws + 48 * MB);  // era A
    unsigned short* vlo  = (unsigned short*)(ws + 54 * MB);
    float* x2f  = (float*)(ws + 48 * MB);                    // era C/D (v dead)
    unsigned short* plo  = (unsigned short*)(ws + 60 * MB);  // era B
    unsigned short* whalf = (unsigned short*)(ws + 60 * MB); // era D (18 MB)
    unsigned short* vthi = (unsigned short*)(ws + 72 * MB);
    unsigned short* vtlo = (unsigned short*)(ws + 78 * MB);
    unsigned short* h2hi  = (unsigned short*)(ws + 78 * MB); // era D (vtlo dead)
    unsigned short* wqkvTh = (unsigned short*)(ws + 84 * MB);          // [2304][768]
    unsigned short* wqkvTl = wqkvTh + (size_t)3 * Dn * Dn;
    unsigned short* woTh = wqkvTl + (size_t)3 * Dn * Dn;
    unsigned short* woTl = woTh + (size_t)Dn * Dn;
    float* rsum = (float*)(ws + 84 * MB);                    // era B/C overlay (wqkvT dead)
    char* misc = (char*)(woTl + (size_t)Dn * Dn);
    float* bqkv = (float*)misc;                          // 2304 f
    float* rwt  = (float*)(misc + 2304 * 4);             // 16*768 f
    float* gates = (float*)(misc + 2304 * 4 + 12288 * 4);
    int* ind  = (int*)((char*)gates + 2 * Tn * 4);
    int* meta = (int*)((char*)ind + 2 * Tn * 4);
    int* rows = (int*)((char*)meta + 256);

    dim3 blk(256);
    // packed QKV weight transpose ([D,D] f32 -> bf16 hi/lo rows of [2304][768])
    transpose_f32<<<dim3(12, 12, 1), blk, 0, stream>>>(wq, Dn, 0, wqkvTh, wqkvTl, Dn, 0);
    transpose_f32<<<dim3(12, 12, 1), blk, 0, stream>>>(wk, Dn, 0,
        wqkvTh + (size_t)Dn * Dn, wqkvTl + (size_t)Dn * Dn, Dn, 0);
    transpose_f32<<<dim3(12, 12, 1), blk, 0, stream>>>(wv, Dn, 0,
        wqkvTh + (size_t)2 * Dn * Dn, wqkvTl + (size_t)2 * Dn * Dn, Dn, 0);
    transpose_f32<<<dim3(12, 12, 1), blk, 0, stream>>>(wo, Dn, 0, woTh, woTl, Dn, 0);
    pack_bias<<<dim3(9), blk, 0, stream>>>(bq, bk, bv, bqkv);
    pack_router<<<dim3(48), blk, 0, stream>>>(r_w, n_w, rwt);
    // LN1 -> split bf16
    ln1_split<<<dim3(Tn), blk, 0, stream>>>(x, ln1_s, ln1_b, h1hi, h1lo);
    // fused QKV: pipelined split GEMM, direct split-bf16 epilogue (q pre-scaled 1/8)
    gemm_bs<<<dim3(18, 32, 1), blk, 0, stream>>>(h1hi, h1lo, Dn, 0, wqkvTh, wqkvTl, Dn, 0,
        bqkv, nullptr, 0, 0, Dn, 1, 0, 1,
        qhi, qlo, khi, klo, vhi, vlo, nullptr, nullptr, nullptr);
    vtrans16<<<dim3(16, 1, 48), blk, 0, stream>>>(vhi, vlo, vthi, vtlo);
    hipMemsetAsync(rsum, 0, (size_t)48 * Sn * 4, stream);
    hipMemsetAsync(of, 0, (size_t)Tn * Dn * 4, stream);
    // attention in chunks of 6 heads: QK^T+exp+rowsum fused, then PV (K-split atomic)
    for (int b = 0; b < 4; ++b) {
        for (int hg = 0; hg < 2; ++hg) {
            long tb = (long)b * Sn * Dn;
            int hoff = hg * 6 * 64;
            gemm_bs<<<dim3(8, 8, 6), blk, 0, stream>>>(
                qhi + tb + hoff, qlo + tb + hoff, Dn, 64,
                khi + tb + hoff, klo + tb + hoff, Dn, 64,
                nullptr, nullptr, 1024, (long)1024 * 1024, HDn, 1, 0, 2,
                nullptr, nullptr, nullptr, nullptr, nullptr, nullptr,
                phi, plo, rsum + (long)(b * 12 + hg * 6) * Sn);
            gemm_pv<<<dim3(1, 8, 48), blk, 0, stream>>>(
                phi, plo, 1024, (long)1024 * 1024,
                vthi + (long)(b * 12 + hg * 6) * 64 * 1024,
                vtlo + (long)(b * 12 + hg * 6) * 64 * 1024, 1024, (long)64 * 1024,
                of + tb + hoff, Dn, 64, Sn, 8);
        }
    }
    // normalize by row-sums + split to bf16, then output projection (direct store)
    scale_split_conv<<<dim3(3072), blk, 0, stream>>>(of, rsum, ohi, olo);
    gemm_bs<<<dim3(6, 32, 1), blk, 0, stream>>>(ohi, olo, Dn, 0, woTh, woTl, Dn, 0,
        bo, x2f, Dn, 0, Dn, 1, 0, 0,
        nullptr, nullptr, nullptr, nullptr, nullptr, nullptr, nullptr, nullptr, nullptr);
    // LN2 + router fused (residual x added on the fly; h2 stored bf16 for MoE)
    ln2_router<<<dim3(Tn), blk, 0, stream>>>(x2f, x, ln2_s, ln2_b, rwt, r_b, n_b, noise,
                                             h2hi, gates, ind);
    hipMemsetAsync(buf, 0, (size_t)Tn * Dn * 4, stream);
    sort_rows<<<dim3(1), dim3(1024), 0, stream>>>(ind, meta, rows);
    // sparse experts, two DFF halves through one 18 MB transposed-weight region
    for (int h = 0; h < 2; ++h) {
        transpose_f32<<<dim3(24, 12, 8), blk, 0, stream>>>(
            e_w1 + (size_t)h * DHALF, DFFn, (long)Dn * DFFn, whalf, nullptr, Dn, (long)DHALF * Dn);
        moe_gemm1<<<dim3(12, 32, 8), blk, 0, stream>>>(h2hi, whalf, e_b1, rows, meta, eh, h);
        transpose_f32<<<dim3(12, 24, 8), blk, 0, stream>>>(
            e_w2 + (size_t)h * DHALF * Dn, Dn, (long)DFFn * Dn, whalf, nullptr, DHALF, (long)Dn * DHALF);
        moe_gemm2<<<dim3(6, 32, 8), blk, 0, stream>>>(eh, whalf, h == 0 ? e_b2 : nullptr,
                                                      rows, meta, gates, buf);
    }
    final_add<<<dim3(Tn * Dn / 1024), blk, 0, stream>>>(x2f, x, buf, (float*)d_out);
}

// Round 4
// 838.491 us; speedup vs baseline: 1.4704x; 1.2289x over previous
//
#include <hip/hip_runtime.h>

#define DEV static __device__ __forceinline__

typedef __attribute__((ext_vector_type(8))) short v8s;
typedef __attribute__((ext_vector_type(4))) float v4f;

constexpr int Bn = 4, Sn = 1024, Dn = 768, NHn = 12, HDn = 64, En = 8, DFFn = 3072;
constexpr int Tn = Bn * Sn;          // 4096 tokens
constexpr int NROWS = 2 * Tn;        // 8192 gathered expert rows
constexpr int DHALF = DFFn / 2;      // 1536 (MoE processed in two DFF halves)
constexpr int KS2 = 4;               // moe_gemm2 K-split factor
constexpr size_t MB = 1024 * 1024;

// ---- workspace map (~93.2 MB; lifetime-overlaid regions) ----
// era A (QKV): h1 [12,24) ; QKV epilogue -> q[0,12) k[24,36) v[48,60) ; vtrans -> vt[72,84)
// era B (flash attn): reads q[0,12) k[24,36) vt[72,84); writes O over q region [0,12)
// era C (proj): ohi/olo[0,12) | x2f[48,60) (v dead) | woT @90.75
// era D (MoE): eh[12,36) | whalf[60,78) | h2hi[78,84) | buf[36,48) | x2f[48,60)
// [84,93.2) wqkvTh wqkvTl woTh woTl | bqkv rwt gates ind meta rows

DEV float bf2f(unsigned short h) {
    union { unsigned int u; float f; } c; c.u = ((unsigned int)h) << 16; return c.f;
}
DEV unsigned short f2bf(float f) {   // round-to-nearest-even
    union { float f; unsigned int u; } c; c.f = f;
    return (unsigned short)((c.u + 0x7fffu + ((c.u >> 16) & 1u)) >> 16);
}
DEV v4f mfma16(v8s a, v8s b, v4f c) {
    return __builtin_amdgcn_mfma_f32_16x16x32_bf16(a, b, c, 0, 0, 0);
}

// ---------------- transpose fp32 src -> bf16 hi (+ optional lo) ----------------
__global__ __launch_bounds__(256) void transpose_f32(const float* __restrict__ src,
                                                     int src_ld, long src_zs,
                                                     unsigned short* __restrict__ dsthi,
                                                     unsigned short* __restrict__ dstlo,
                                                     int dst_ld, long dst_zs) {
    src += (long)blockIdx.z * src_zs;
    dsthi += (long)blockIdx.z * dst_zs;
    if (dstlo) dstlo += (long)blockIdx.z * dst_zs;
    __shared__ float tile[64][65];
    int tid = threadIdx.x, tx = blockIdx.x, ty = blockIdx.y;
    int r = tid >> 2, c0 = (tid & 3) * 16;
    const float* sp = src + (long)(ty * 64 + r) * src_ld + tx * 64 + c0;
#pragma unroll
    for (int i = 0; i < 4; ++i) {
        float4 f = *(const float4*)(sp + i * 4);
        tile[r][c0 + i * 4 + 0] = f.x;
        tile[r][c0 + i * 4 + 1] = f.y;
        tile[r][c0 + i * 4 + 2] = f.z;
        tile[r][c0 + i * 4 + 3] = f.w;
    }
    __syncthreads();
    int dl = tid >> 2, s0 = (tid & 3) * 16;
    unsigned short hh[16] __attribute__((aligned(16)));
    unsigned short ll[16] __attribute__((aligned(16)));
#pragma unroll
    for (int i = 0; i < 16; ++i) {
        float f = tile[s0 + i][dl];
        unsigned short h0 = f2bf(f);
        hh[i] = h0;
        ll[i] = f2bf(f - bf2f(h0));
    }
    long o = (long)(tx * 64 + dl) * dst_ld + ty * 64 + s0;
    *(uint4*)(dsthi + o) = ((uint4*)hh)[0];
    *(uint4*)(dsthi + o + 8) = ((uint4*)hh)[1];
    if (dstlo) {
        *(uint4*)(dstlo + o) = ((uint4*)ll)[0];
        *(uint4*)(dstlo + o + 8) = ((uint4*)ll)[1];
    }
}

// ---------------- LN1: f32 in -> split bf16 out ----------------
__global__ __launch_bounds__(256) void ln1_split(const float* __restrict__ in_f,
                                                 const float* __restrict__ sc,
                                                 const float* __restrict__ bi,
                                                 unsigned short* __restrict__ hi,
                                                 unsigned short* __restrict__ lo) {
    int row = blockIdx.x, tid = threadIdx.x;
    long base = (long)row * Dn;
    float x[3];
#pragma unroll
    for (int j = 0; j < 3; ++j) x[j] = in_f[base + tid + j * 256];
    __shared__ float red[4];
    float s = x[0] + x[1] + x[2];
    for (int off = 32; off; off >>= 1) s += __shfl_down(s, off, 64);
    if ((tid & 63) == 0) red[tid >> 6] = s;
    __syncthreads();
    float mean = (red[0] + red[1] + red[2] + red[3]) * (1.0f / Dn);
    __syncthreads();
    float ss = 0.f;
#pragma unroll
    for (int j = 0; j < 3; ++j) { float d0 = x[j] - mean; ss += d0 * d0; }
    for (int off = 32; off; off >>= 1) ss += __shfl_down(ss, off, 64);
    if ((tid & 63) == 0) red[tid >> 6] = ss;
    __syncthreads();
    float var = (red[0] + red[1] + red[2] + red[3]) * (1.0f / Dn);
    float rstd = 1.0f / sqrtf(var + 1e-5f);
#pragma unroll
    for (int j = 0; j < 3; ++j) {
        int d = tid + j * 256;
        float y = (x[j] - mean) * rstd * sc[d] + bi[d];
        unsigned short h0 = f2bf(y);
        hi[base + d] = h0;
        lo[base + d] = f2bf(y - bf2f(h0));
    }
}

// ---------------- LN2 fused with router (input = x2f + x residual) ----------------
__global__ __launch_bounds__(256) void ln2_router(const float* __restrict__ in_f,
                                                  const float* __restrict__ xres,
                                                  const float* __restrict__ sc,
                                                  const float* __restrict__ bi,
                                                  const float* __restrict__ rwt,
                                                  const float* __restrict__ rb,
                                                  const float* __restrict__ nb,
                                                  const float* __restrict__ noise,
                                                  unsigned short* __restrict__ h2hi,
                                                  float* __restrict__ gates,
                                                  int* __restrict__ ind) {
    int t = blockIdx.x, tid = threadIdx.x;
    int w = tid >> 6, lane = tid & 63;
    long base = (long)t * Dn;
    float x[3];
#pragma unroll
    for (int j = 0; j < 3; ++j) x[j] = in_f[base + tid + j * 256] + xres[base + tid + j * 256];
    __shared__ float red[4];
    float s = x[0] + x[1] + x[2];
    for (int off = 32; off; off >>= 1) s += __shfl_down(s, off, 64);
    if ((tid & 63) == 0) red[tid >> 6] = s;
    __syncthreads();
    float mean = (red[0] + red[1] + red[2] + red[3]) * (1.0f / Dn);
    __syncthreads();
    float ss = 0.f;
#pragma unroll
    for (int j = 0; j < 3; ++j) { float d0 = x[j] - mean; ss += d0 * d0; }
    for (int off = 32; off; off >>= 1) ss += __shfl_down(ss, off, 64);
    if ((tid & 63) == 0) red[tid >> 6] = ss;
    __syncthreads();
    float var = (red[0] + red[1] + red[2] + red[3]) * (1.0f / Dn);
    float rstd = 1.0f / sqrtf(var + 1e-5f);
    float y[3];
#pragma unroll
    for (int j = 0; j < 3; ++j) {
        int d = tid + j * 256;
        y[j] = (x[j] - mean) * rstd * sc[d] + bi[d];
        h2hi[base + d] = f2bf(y[j]);
    }
    float acc[16];
#pragma unroll
    for (int e = 0; e < 16; ++e) {
        const float* wp = rwt + e * Dn + tid;
        acc[e] = y[0] * wp[0] + y[1] * wp[256] + y[2] * wp[512];
    }
#pragma unroll
    for (int e = 0; e < 16; ++e)
        for (int off = 32; off; off >>= 1) acc[e] += __shfl_down(acc[e], off, 64);
    __shared__ float red2[4][16];
    if (lane == 0)
#pragma unroll
        for (int e = 0; e < 16; ++e) red2[w][e] = acc[e];
    __syncthreads();
    if (tid == 0) {
        float noisy[8];
#pragma unroll
        for (int e = 0; e < 8; ++e) {
            float lg = red2[0][e] + red2[1][e] + red2[2][e] + red2[3][e] + rb[e];
            float nv = red2[0][8 + e] + red2[1][8 + e] + red2[2][8 + e] + red2[3][8 + e] + nb[e];
            float sp = fmaxf(nv, 0.f) + log1pf(expf(-fabsf(nv)));
            noisy[e] = lg + noise[(long)t * En + e] * sp;
        }
        int i0 = 0;
        for (int e = 1; e < 8; ++e) if (noisy[e] > noisy[i0]) i0 = e;
        int i1 = (i0 == 0) ? 1 : 0;
        for (int e = 0; e < 8; ++e) if (e != i0 && noisy[e] > noisy[i1]) i1 = e;
        float mm = fmaxf(noisy[i0], noisy[i1]);
        float e0 = expf(noisy[i0] - mm), e1 = expf(noisy[i1] - mm);
        float inv = 1.0f / (e0 + e1);
        gates[t] = e0 * inv;
        gates[Tn + t] = e1 * inv;
        ind[t] = i0;
        ind[Tn + t] = i1;
    }
}

// ---------------- counting sort of 8192 (tok,slot), parallel prefix ----------------
__global__ __launch_bounds__(1024) void sort_rows(const int* __restrict__ ind,
                                                  int* __restrict__ meta,
                                                  int* __restrict__ rows) {
    __shared__ int wtot[8][17];
    __shared__ int bb[8];
    int tid = threadIdx.x, wv = tid >> 6, ln = tid & 63;
    int codes[8];
    int h[8] = {0, 0, 0, 0, 0, 0, 0, 0};
#pragma unroll
    for (int k = 0; k < 8; ++k) {
        int i = tid * 8 + k;
        int e = ind[(i & 1) * Tn + (i >> 1)];
        codes[k] = e;
        ++h[e];
    }
    int pre[8];
#pragma unroll
    for (int e = 0; e < 8; ++e) {
        int x = h[e];
#pragma unroll
        for (int off = 1; off < 64; off <<= 1) {
            int y = __shfl_up(x, off, 64);
            if (ln >= off) x += y;
        }
        pre[e] = x - h[e];
        if (ln == 63) wtot[e][wv] = x;
    }
    __syncthreads();
    if (tid < 8) {
        int run = 0;
        for (int w2 = 0; w2 < 16; ++w2) {
            int v = wtot[tid][w2];
            wtot[tid][w2] = run;
            run += v;
        }
        wtot[tid][16] = run;
        meta[tid] = run;                 // counts
    }
    __syncthreads();
    if (tid == 0) {
        int b = 0;
        for (int e = 0; e < 8; ++e) {
            bb[e] = b;
            meta[16 + e] = b;
            b += wtot[e][16];
        }
        meta[24] = b;
    }
    __syncthreads();
    int c[8];
#pragma unroll
    for (int e = 0; e < 8; ++e) c[e] = bb[e] + wtot[e][wv] + pre[e];
#pragma unroll
    for (int k = 0; k < 8; ++k) {
        int e = codes[k];
        rows[c[e]] = tid * 8 + k;        // value == t*2+slot
        ++c[e];
    }
}

// ---------------- tiny packers ----------------
__global__ void pack_router(const float* __restrict__ rw, const float* __restrict__ nw,
                            float* __restrict__ rwt) {
    int idx = blockIdx.x * 256 + threadIdx.x;   // [0, 16*768)
    int e = idx / Dn, d = idx - e * Dn;
    rwt[idx] = (e < 8) ? rw[d * En + e] : nw[d * En + (e - 8)];
}

__global__ void pack_bias(const float* __restrict__ bq, const float* __restrict__ bk,
                          const float* __restrict__ bv, float* __restrict__ bqkv) {
    int i = blockIdx.x * 256 + threadIdx.x;     // [0, 2304)
    bqkv[i] = (i < 768) ? bq[i] : (i < 1536 ? bk[i - 768] : bv[i - 1536]);
}

// ---------------- pure-bf16 split GEMM, 128x128 tile, 3-product, reg-pipelined ----------
// mode 0: f32 C store (or atomic), bias @ks==0  (o-proj)
// mode 1: QKV: cols [0,768)->q(*0.125), [768,1536)->k, [1536,2304)->v, split bf16 out
__global__ __launch_bounds__(256, 2) void gemm_bs(
    const unsigned short* __restrict__ Ahi, const unsigned short* __restrict__ Alo,
    int lda, long za,
    const unsigned short* __restrict__ Bhi, const unsigned short* __restrict__ Blo,
    int ldb, long zb,
    const float* __restrict__ bias,
    float* __restrict__ Cf, int ldc, long zc, int K, int zdiv, int catomic, int mode,
    unsigned short* __restrict__ oqh, unsigned short* __restrict__ oql,
    unsigned short* __restrict__ okh, unsigned short* __restrict__ okl,
    unsigned short* __restrict__ ovh, unsigned short* __restrict__ ovl) {
    int z = blockIdx.z;
    int zi = z / zdiv, ks = z - zi * zdiv;
    int Klen = K / zdiv, k0base = ks * Klen;
    Ahi += (long)zi * za;
    Alo += (long)zi * za;
    Bhi += (long)zi * zb;
    Blo += (long)zi * zb;
    int n0 = blockIdx.x * 128, m0 = blockIdx.y * 128;
    int tid = threadIdx.x, w = tid >> 6, lane = tid & 63, quad = lane >> 4, l16 = lane & 15;
    int wm = w >> 1, wn = w & 1;
    __shared__ unsigned short Ah[128][40], Al[128][40], Bh[128][40], Bl[128][40];
    v4f acc[4][4] = {};
    int ar = tid >> 1, ac = (tid & 1) * 16;
    const unsigned short* pah = Ahi + (long)(m0 + ar) * lda + k0base + ac;
    const unsigned short* pal = Alo + (long)(m0 + ar) * lda + k0base + ac;
    const unsigned short* pbh = Bhi + (long)(n0 + ar) * ldb + k0base + ac;
    const unsigned short* pbl = Blo + (long)(n0 + ar) * ldb + k0base + ac;
    int nsteps = Klen >> 5;
    uint4 ra0, ra1, rb0, rb1, rc0, rc1, rd0, rd1;
#define LOADK(kt) { int o_ = (kt) << 5; \
    ra0 = *(const uint4*)(pah + o_); ra1 = *(const uint4*)(pah + o_ + 8); \
    rb0 = *(const uint4*)(pal + o_); rb1 = *(const uint4*)(pal + o_ + 8); \
    rc0 = *(const uint4*)(pbh + o_); rc1 = *(const uint4*)(pbh + o_ + 8); \
    rd0 = *(const uint4*)(pbl + o_); rd1 = *(const uint4*)(pbl + o_ + 8); }
    LOADK(0);
    for (int kt = 0; kt < nsteps; ++kt) {
        *(uint4*)&Ah[ar][ac] = ra0;
        *(uint4*)&Ah[ar][ac + 8] = ra1;
        *(uint4*)&Al[ar][ac] = rb0;
        *(uint4*)&Al[ar][ac + 8] = rb1;
        *(uint4*)&Bh[ar][ac] = rc0;
        *(uint4*)&Bh[ar][ac + 8] = rc1;
        *(uint4*)&Bl[ar][ac] = rd0;
        *(uint4*)&Bl[ar][ac + 8] = rd1;
        __syncthreads();
        if (kt + 1 < nsteps) LOADK(kt + 1);   // issue early; hides under MFMA
        v8s afh[4], afl[4];
#pragma unroll
        for (int mt = 0; mt < 4; ++mt) {
            afh[mt] = *(const v8s*)&Ah[wm * 64 + mt * 16 + l16][quad * 8];
            afl[mt] = *(const v8s*)&Al[wm * 64 + mt * 16 + l16][quad * 8];
        }
#pragma unroll
        for (int nt = 0; nt < 4; ++nt) {
            v8s bbh = *(const v8s*)&Bh[wn * 64 + nt * 16 + l16][quad * 8];
            v8s bbl = *(const v8s*)&Bl[wn * 64 + nt * 16 + l16][quad * 8];
#pragma unroll
            for (int mt = 0; mt < 4; ++mt) acc[mt][nt] = mfma16(afh[mt], bbh, acc[mt][nt]);
#pragma unroll
            for (int mt = 0; mt < 4; ++mt) acc[mt][nt] = mfma16(afl[mt], bbh, acc[mt][nt]);
#pragma unroll
            for (int mt = 0; mt < 4; ++mt) acc[mt][nt] = mfma16(afh[mt], bbl, acc[mt][nt]);
        }
        __syncthreads();
    }
#undef LOADK
    if (mode == 1) {
#pragma unroll
        for (int mt = 0; mt < 4; ++mt)
#pragma unroll
            for (int nt = 0; nt < 4; ++nt)
#pragma unroll
                for (int r = 0; r < 4; ++r) {
                    int row = m0 + wm * 64 + mt * 16 + quad * 4 + r;
                    int col = n0 + wn * 64 + nt * 16 + l16;
                    float v = acc[mt][nt][r] + bias[col];
                    int seg = (col >= 1536) ? 2 : (col >= 768 ? 1 : 0);
                    int c = col - seg * 768;
                    if (seg == 0) v *= 0.125f;   // fold 1/sqrt(HD) into q
                    long ci = (long)row * Dn + c;
                    unsigned short* dh = (seg == 0) ? oqh : (seg == 1 ? okh : ovh);
                    unsigned short* dl = (seg == 0) ? oql : (seg == 1 ? okl : ovl);
                    unsigned short h0 = f2bf(v);
                    dh[ci] = h0;
                    dl[ci] = f2bf(v - bf2f(h0));
                }
    } else {
        long coff = (long)zi * zc;
#pragma unroll
        for (int mt = 0; mt < 4; ++mt)
#pragma unroll
            for (int nt = 0; nt < 4; ++nt)
#pragma unroll
                for (int r = 0; r < 4; ++r) {
                    int row = m0 + wm * 64 + mt * 16 + quad * 4 + r;
                    int col = n0 + wn * 64 + nt * 16 + l16;
                    float v = acc[mt][nt][r];
                    if (ks == 0 && bias) v += bias[col];
                    long ci = coff + (long)row * ldc + col;
                    if (catomic) atomicAdd(&Cf[ci], v);
                    else Cf[ci] = v;
                }
    }
}

// ---------------- flash attention: one block = (q-tile 128) x (b,h) ----------------
// Q pre-scaled by 1/8. No max-shift (|s| small). O normalized in-reg, written as
// split bf16 over the (block-exclusive, consumed) Q region.
__global__ __launch_bounds__(256) void flash_attn(
    const unsigned short* __restrict__ qhi, const unsigned short* __restrict__ qlo,
    const unsigned short* __restrict__ khi, const unsigned short* __restrict__ klo,
    const unsigned short* __restrict__ vthi, const unsigned short* __restrict__ vtlo,
    unsigned short* __restrict__ ohi, unsigned short* __restrict__ olo) {
    int g = blockIdx.y, b = g / NHn, h = g - b * NHn;
    int m0 = blockIdx.x * 128;
    int tid = threadIdx.x, w = tid >> 6, lane = tid & 63, quad = lane >> 4, l16 = lane & 15;
    __shared__ unsigned short Kh[2][64][40], Kl[2][64][40];
    __shared__ unsigned short Vh[2][64][40], Vl[2][64][40];
    __shared__ unsigned short Ph[4][2][32][40];   // per-wave P (hi only)
    // Q fragments in registers (rows m0+w*32+mt*16+l16, d = kk*32+quad*8+..)
    v8s qh[2][2], ql[2][2];
    long qrow0 = (long)b * Sn + m0 + w * 32;
#pragma unroll
    for (int mt = 0; mt < 2; ++mt)
#pragma unroll
        for (int kk = 0; kk < 2; ++kk) {
            long off = (qrow0 + mt * 16 + l16) * Dn + h * 64 + kk * 32 + quad * 8;
            qh[mt][kk] = *(const v8s*)(qhi + off);
            ql[mt][kk] = *(const v8s*)(qlo + off);
        }
    v4f accO[2][4] = {};
    float rs[2][4] = {};
    // staging thread mapping: srow in [0,32), su selects (kk, 8-col chunk)
    int srow = tid >> 3, su = tid & 7, skk = su >> 2, scu = (su & 3) * 8;
    const unsigned short* kb_h = khi + ((long)b * Sn + srow) * Dn + h * 64 + skk * 32 + scu;
    const unsigned short* kb_l = klo + ((long)b * Sn + srow) * Dn + h * 64 + skk * 32 + scu;
    const unsigned short* vb_h = vthi + ((long)g * 64 + srow) * Sn + skk * 32 + scu;
    const unsigned short* vb_l = vtlo + ((long)g * 64 + srow) * Sn + skk * 32 + scu;
    uint4 pkh0, pkh1, pkl0, pkl1, pvh0, pvh1, pvl0, pvl1;
#define LOADT(t) { long ko = (long)(t) * 64 * Dn; int vo = (t) * 64; \
    pkh0 = *(const uint4*)(kb_h + ko); pkh1 = *(const uint4*)(kb_h + ko + (long)32 * Dn); \
    pkl0 = *(const uint4*)(kb_l + ko); pkl1 = *(const uint4*)(kb_l + ko + (long)32 * Dn); \
    pvh0 = *(const uint4*)(vb_h + vo); pvh1 = *(const uint4*)(vb_h + vo + 32 * Sn); \
    pvl0 = *(const uint4*)(vb_l + vo); pvl1 = *(const uint4*)(vb_l + vo + 32 * Sn); }
    LOADT(0);
    for (int t = 0; t < 16; ++t) {
        __syncthreads();                 // prev iter's K/V reads done
        *(uint4*)&Kh[skk][srow][scu] = pkh0;
        *(uint4*)&Kh[skk][srow + 32][scu] = pkh1;
        *(uint4*)&Kl[skk][srow][scu] = pkl0;
        *(uint4*)&Kl[skk][srow + 32][scu] = pkl1;
        *(uint4*)&Vh[skk][srow][scu] = pvh0;
        *(uint4*)&Vh[skk][srow + 32][scu] = pvh1;
        *(uint4*)&Vl[skk][srow][scu] = pvl0;
        *(uint4*)&Vl[skk][srow + 32][scu] = pvl1;
        __syncthreads();
        if (t < 15) LOADT(t + 1);        // latency hides under compute
        // ---- S = Q K^T (3-product split) ----
        v4f accS[2][4] = {};
#pragma unroll
        for (int nt = 0; nt < 4; ++nt)
#pragma unroll
            for (int kk = 0; kk < 2; ++kk) {
                v8s bh = *(const v8s*)&Kh[kk][nt * 16 + l16][quad * 8];
                v8s bl = *(const v8s*)&Kl[kk][nt * 16 + l16][quad * 8];
#pragma unroll
                for (int mt = 0; mt < 2; ++mt) {
                    accS[mt][nt] = mfma16(qh[mt][kk], bh, accS[mt][nt]);
                    accS[mt][nt] = mfma16(ql[mt][kk], bh, accS[mt][nt]);
                    accS[mt][nt] = mfma16(qh[mt][kk], bl, accS[mt][nt]);
                }
            }
        // ---- P = exp(S) -> bf16 in wave-private LDS; rowsum of quantized P ----
#pragma unroll
        for (int mt = 0; mt < 2; ++mt)
#pragma unroll
            for (int r = 0; r < 4; ++r) {
                int prow = mt * 16 + quad * 4 + r;
                float psum = 0.f;
#pragma unroll
                for (int nt = 0; nt < 4; ++nt) {
                    float p = __expf(accS[mt][nt][r]);
                    unsigned short hh = f2bf(p);
                    psum += bf2f(hh);    // normalize exactly what PV consumes
                    Ph[w][nt >> 1][prow][(nt & 1) * 16 + l16] = hh;
                }
                rs[mt][r] += psum;
            }
        // ---- O += P V (P-hi x split-V) ----
#pragma unroll
        for (int kk = 0; kk < 2; ++kk) {
            v8s pa0 = *(const v8s*)&Ph[w][kk][l16][quad * 8];
            v8s pa1 = *(const v8s*)&Ph[w][kk][16 + l16][quad * 8];
#pragma unroll
            for (int nt = 0; nt < 4; ++nt) {
                v8s vh = *(const v8s*)&Vh[kk][nt * 16 + l16][quad * 8];
                v8s vl = *(const v8s*)&Vl[kk][nt * 16 + l16][quad * 8];
                accO[0][nt] = mfma16(pa0, vh, accO[0][nt]);
                accO[1][nt] = mfma16(pa1, vh, accO[1][nt]);
                accO[0][nt] = mfma16(pa0, vl, accO[0][nt]);
                accO[1][nt] = mfma16(pa1, vl, accO[1][nt]);
            }
        }
    }
#undef LOADT
    // ---- epilogue: finish rowsums (16-lane reduce), normalize, write split bf16 ----
#pragma unroll
    for (int mt = 0; mt < 2; ++mt)
#pragma unroll
        for (int r = 0; r < 4; ++r) {
            float s = rs[mt][r];
#pragma unroll
            for (int off = 1; off < 16; off <<= 1) s += __shfl_xor(s, off, 64);
            float inv = 1.0f / s;
            long orow = qrow0 + mt * 16 + quad * 4 + r;
#pragma unroll
            for (int nt = 0; nt < 4; ++nt) {
                float v = accO[mt][nt][r] * inv;
                unsigned short hh = f2bf(v);
                long oi = orow * Dn + h * 64 + nt * 16 + l16;
                ohi[oi] = hh;
                olo[oi] = f2bf(v - bf2f(hh));
            }
        }
}

// ---------------- V transpose (bf16 hi/lo): v[b,s,h,d] -> vt[g=b*12+h][d][s] ----------
__global__ __launch_bounds__(256) void vtrans16(const unsigned short* __restrict__ vhi,
                                                const unsigned short* __restrict__ vlo,
                                                unsigned short* __restrict__ vthi,
                                                unsigned short* __restrict__ vtlo) {
    int g = blockIdx.z, b = g / NHn, h = g % NHn;
    int stile = blockIdx.x, tid = threadIdx.x;
    __shared__ unsigned short th[64][66], tl[64][66];
    int sl = tid >> 2, c0 = (tid & 3) * 16;
    long src = (long)(b * Sn + stile * 64 + sl) * Dn + h * 64 + c0;
    *(uint4*)&th[sl][c0] = *(const uint4*)(vhi + src);
    *(uint4*)&th[sl][c0 + 8] = *(const uint4*)(vhi + src + 8);
    *(uint4*)&tl[sl][c0] = *(const uint4*)(vlo + src);
    *(uint4*)&tl[sl][c0 + 8] = *(const uint4*)(vlo + src + 8);
    __syncthreads();
    int dl = tid >> 2, s0 = (tid & 3) * 16;
    unsigned short hh[16] __attribute__((aligned(16)));
    unsigned short ll[16] __attribute__((aligned(16)));
#pragma unroll
    for (int i = 0; i < 16; ++i) {
        hh[i] = th[s0 + i][dl];
        ll[i] = tl[s0 + i][dl];
    }
    long o = (long)(g * 64 + dl) * Sn + stile * 64 + s0;
    *(uint4*)(vthi + o) = ((uint4*)hh)[0];
    *(uint4*)(vthi + o + 8) = ((uint4*)hh)[1];
    *(uint4*)(vtlo + o) = ((uint4*)ll)[0];
    *(uint4*)(vtlo + o + 8) = ((uint4*)ll)[1];
}

// ---------------- MoE stage 1 (per DFF half): eh = relu(h2 @ W1t[e]^T + b1), pipelined ----
__global__ __launch_bounds__(256, 2) void moe_gemm1(const unsigned short* __restrict__ h2hi,
                                                    const unsigned short* __restrict__ W1t,
                                                    const float* __restrict__ eb1,
                                                    const int* __restrict__ rows,
                                                    const int* __restrict__ meta,
                                                    unsigned short* __restrict__ eh,
                                                    int half) {
    int e = blockIdx.z;
    int cnt = meta[e];
    int mb = blockIdx.y * 128;
    if (mb >= cnt) return;
    int base_e = meta[16 + e];
    int valid = cnt - mb; if (valid > 128) valid = 128;
    int tid = threadIdx.x;
    __shared__ int toks[128];
    if (tid < 128) {
        int idx = mb + tid;
        toks[tid] = rows[base_e + (idx < cnt ? idx : 0)];
    }
    __shared__ unsigned short As[128][40], Bs[128][40];
    int w = tid >> 6, lane = tid & 63, quad = lane >> 4, l16 = lane & 15;
    int wm = w >> 1, wn = w & 1;
    v4f acc[4][4] = {};
    int ar = tid >> 1, ac = (tid & 1) * 16;
    int nb0 = blockIdx.x * 128;
    const unsigned short* Wb = W1t + (long)e * DHALF * Dn;
    __syncthreads();
    const unsigned short* apg = h2hi + (long)(toks[ar] >> 1) * Dn + ac;
    const unsigned short* bpg = Wb + (long)(nb0 + ar) * Dn + ac;
    uint4 a0, a1, b0, b1;
#define LOADK(kt) { int o_ = (kt) * 32; \
    a0 = *(const uint4*)(apg + o_); a1 = *(const uint4*)(apg + o_ + 8); \
    b0 = *(const uint4*)(bpg + o_); b1 = *(const uint4*)(bpg + o_ + 8); }
    LOADK(0);
    for (int kt = 0; kt < Dn / 32; ++kt) {
        *(uint4*)&As[ar][ac] = a0;
        *(uint4*)&As[ar][ac + 8] = a1;
        *(uint4*)&Bs[ar][ac] = b0;
        *(uint4*)&Bs[ar][ac + 8] = b1;
        __syncthreads();
        if (kt + 1 < Dn / 32) LOADK(kt + 1);
        v8s af[4];
#pragma unroll
        for (int mt = 0; mt < 4; ++mt) af[mt] = *(const v8s*)&As[wm * 64 + mt * 16 + l16][quad * 8];
#pragma unroll
        for (int nt = 0; nt < 4; ++nt) {
            v8s bb = *(const v8s*)&Bs[wn * 64 + nt * 16 + l16][quad * 8];
#pragma unroll
            for (int mt = 0; mt < 4; ++mt) acc[mt][nt] = mfma16(af[mt], bb, acc[mt][nt]);
        }
        __syncthreads();
    }
#undef LOADK
#pragma unroll
    for (int mt = 0; mt < 4; ++mt)
#pragma unroll
        for (int nt = 0; nt < 4; ++nt)
#pragma unroll
            for (int r = 0; r < 4; ++r) {
                int rl = wm * 64 + mt * 16 + quad * 4 + r;
                if (rl < valid) {
                    int col = nb0 + wn * 64 + nt * 16 + l16;
                    float v = acc[mt][nt][r] + eb1[e * DFFn + half * DHALF + col];
                    v = fmaxf(v, 0.f);
                    eh[(long)(base_e + mb + rl) * DHALF + col] = f2bf(v);
                }
            }
}

// ---------------- MoE stage 2 (per DFF half, K-split x4): buf += gate*(eh @ W2t^T) -----
__global__ __launch_bounds__(256, 2) void moe_gemm2(const unsigned short* __restrict__ eh,
                                                    const unsigned short* __restrict__ W2t,
                                                    const float* __restrict__ eb2,
                                                    const int* __restrict__ rows,
                                                    const int* __restrict__ meta,
                                                    const float* __restrict__ gates,
                                                    float* __restrict__ buf) {
    int z = blockIdx.z;
    int e = z >> 2, ks = z & (KS2 - 1);
    int k0b = ks * (DHALF / KS2);
    int cnt = meta[e];
    int mb = blockIdx.y * 128;
    if (mb >= cnt) return;
    int base_e = meta[16 + e];
    int valid = cnt - mb; if (valid > 128) valid = 128;
    int tid = threadIdx.x;
    __shared__ int toks[128];
    if (tid < 128) {
        int idx = mb + tid;
        toks[tid] = rows[base_e + (idx < cnt ? idx : 0)];
    }
    __shared__ unsigned short As[128][40], Bs[128][40];
    int w = tid >> 6, lane = tid & 63, quad = lane >> 4, l16 = lane & 15;
    int wm = w >> 1, wn = w & 1;
    v4f acc[4][4] = {};
    int ar = tid >> 1, ac = (tid & 1) * 16;
    int nb0 = blockIdx.x * 128;
    const unsigned short* Wb = W2t + (long)e * Dn * DHALF;
    long arow = (long)base_e + mb + ar;
    if (arow > NROWS - 1) arow = NROWS - 1;
    const unsigned short* apg = eh + arow * DHALF + k0b + ac;
    const unsigned short* bpg = Wb + (long)(nb0 + ar) * DHALF + k0b + ac;
    __syncthreads();
    uint4 a0, a1, b0, b1;
#define LOADK(kt) { int o_ = (kt) * 32; \
    a0 = *(const uint4*)(apg + o_); a1 = *(const uint4*)(apg + o_ + 8); \
    b0 = *(const uint4*)(bpg + o_); b1 = *(const uint4*)(bpg + o_ + 8); }
    LOADK(0);
    constexpr int NK = (DHALF / KS2) / 32;   // 12
    for (int kt = 0; kt < NK; ++kt) {
        *(uint4*)&As[ar][ac] = a0;
        *(uint4*)&As[ar][ac + 8] = a1;
        *(uint4*)&Bs[ar][ac] = b0;
        *(uint4*)&Bs[ar][ac + 8] = b1;
        __syncthreads();
        if (kt + 1 < NK) LOADK(kt + 1);
        v8s af[4];
#pragma unroll
        for (int mt = 0; mt < 4; ++mt) af[mt] = *(const v8s*)&As[wm * 64 + mt * 16 + l16][quad * 8];
#pragma unroll
        for (int nt = 0; nt < 4; ++nt) {
            v8s bb = *(const v8s*)&Bs[wn * 64 + nt * 16 + l16][quad * 8];
#pragma unroll
            for (int mt = 0; mt < 4; ++mt) acc[mt][nt] = mfma16(af[mt], bb, acc[mt][nt]);
        }
        __syncthreads();
    }
#undef LOADK
#pragma unroll
    for (int mt = 0; mt < 4; ++mt)
#pragma unroll
        for (int nt = 0; nt < 4; ++nt)
#pragma unroll
            for (int r = 0; r < 4; ++r) {
                int rl = wm * 64 + mt * 16 + quad * 4 + r;
                if (rl < valid) {
                    int col = nb0 + wn * 64 + nt * 16 + l16;
                    int code = toks[rl];
                    int tok = code >> 1, slot = code & 1;
                    float g = gates[slot * Tn + tok];
                    float v = acc[mt][nt][r];
                    if (eb2 && ks == 0) v += eb2[e * Dn + col];
                    atomicAdd(&buf[(long)tok * Dn + col], v * g);
                }
            }
}

// ---------------- final: out(f32) = x + x2f + buf ----------------
__global__ __launch_bounds__(256) void final_add(const float* __restrict__ x2f,
                                                 const float* __restrict__ xres,
                                                 const float* __restrict__ buf,
                                                 float* __restrict__ out) {
    long i = ((long)blockIdx.x * 256 + threadIdx.x) * 4;
    float4 a = *(const float4*)(x2f + i);
    float4 xr = *(const float4*)(xres + i);
    float4 b = *(const float4*)(buf + i);
    float4 o = {a.x + xr.x + b.x, a.y + xr.y + b.y, a.z + xr.z + b.z, a.w + xr.w + b.w};
    *(float4*)(out + i) = o;
}

extern "C" void kernel_launch(void* const* d_in, const int* in_sizes, int n_in,
                              void* d_out, int out_size, void* d_ws, size_t ws_size,
                              hipStream_t stream) {
    const float* x     = (const float*)d_in[0];
    const float* noise = (const float*)d_in[1];
    const float* wq = (const float*)d_in[2];
    const float* bq = (const float*)d_in[3];
    const float* wk = (const float*)d_in[4];
    const float* bk = (const float*)d_in[5];
    const float* wv = (const float*)d_in[6];
    const float* bv = (const float*)d_in[7];
    const float* wo = (const float*)d_in[8];
    const float* bo = (const float*)d_in[9];
    const float* ln1_s = (const float*)d_in[10];
    const float* ln1_b = (const float*)d_in[11];
    const float* ln2_s = (const float*)d_in[12];
    const float* ln2_b = (const float*)d_in[13];
    const float* r_w = (const float*)d_in[14];
    const float* r_b = (const float*)d_in[15];
    const float* n_w = (const float*)d_in[16];
    const float* n_b = (const float*)d_in[17];
    const float* e_w1 = (const float*)d_in[18];
    const float* e_b1 = (const float*)d_in[19];
    const float* e_w2 = (const float*)d_in[20];
    const float* e_b2 = (const float*)d_in[21];

    char* ws = (char*)d_ws;
    unsigned short* qhi  = (unsigned short*)(ws + 0);
    unsigned short* qlo  = (unsigned short*)(ws + 6 * MB);
    unsigned short* ohi  = qhi;                              // flash writes O over Q
    unsigned short* olo  = qlo;
    unsigned short* h1hi = (unsigned short*)(ws + 12 * MB);  // era A
    unsigned short* h1lo = (unsigned short*)(ws + 18 * MB);
    unsigned short* eh   = (unsigned short*)(ws + 12 * MB);  // era D (24 MB)
    unsigned short* khi  = (unsigned short*)(ws + 24 * MB);
    unsigned short* klo  = (unsigned short*)(ws + 30 * MB);
    float* buf  = (float*)(ws + 36 * MB);                    // era D MoE accum
    unsigned short* vhi  = (unsigned short*)(ws + 48 * MB);  // era A
    unsigned short* vlo  = (unsigned short*)(ws + 54 * MB);
    float* x2f  = (float*)(ws + 48 * MB);                    // era C/D (v dead)
    unsigned short* whalf = (unsigned short*)(ws + 60 * MB); // era D (18 MB)
    unsigned short* vthi = (unsigned short*)(ws + 72 * MB);
    unsigned short* vtlo = (unsigned short*)(ws + 78 * MB);
    unsigned short* h2hi  = (unsigned short*)(ws + 78 * MB); // era D (vtlo dead)
    unsigned short* wqkvTh = (unsigned short*)(ws + 84 * MB);          // [2304][768]
    unsigned short* wqkvTl = wqkvTh + (size_t)3 * Dn * Dn;
    unsigned short* woTh = wqkvTl + (size_t)3 * Dn * Dn;
    unsigned short* woTl = woTh + (size_t)Dn * Dn;
    char* misc = (char*)(woTl + (size_t)Dn * Dn);
    float* bqkv = (float*)misc;                          // 2304 f
    float* rwt  = (float*)(misc + 2304 * 4);             // 16*768 f
    float* gates = (float*)(misc + 2304 * 4 + 12288 * 4);
    int* ind  = (int*)((char*)gates + 2 * Tn * 4);
    int* meta = (int*)((char*)ind + 2 * Tn * 4);
    int* rows = (int*)((char*)meta + 256);

    dim3 blk(256);
    // packed QKV weight transpose ([D,D] f32 -> bf16 hi/lo rows of [2304][768])
    transpose_f32<<<dim3(12, 12, 1), blk, 0, stream>>>(wq, Dn, 0, wqkvTh, wqkvTl, Dn, 0);
    transpose_f32<<<dim3(12, 12, 1), blk, 0, stream>>>(wk, Dn, 0,
        wqkvTh + (size_t)Dn * Dn, wqkvTl + (size_t)Dn * Dn, Dn, 0);
    transpose_f32<<<dim3(12, 12, 1), blk, 0, stream>>>(wv, Dn, 0,
        wqkvTh + (size_t)2 * Dn * Dn, wqkvTl + (size_t)2 * Dn * Dn, Dn, 0);
    transpose_f32<<<dim3(12, 12, 1), blk, 0, stream>>>(wo, Dn, 0, woTh, woTl, Dn, 0);
    pack_bias<<<dim3(9), blk, 0, stream>>>(bq, bk, bv, bqkv);
    pack_router<<<dim3(48), blk, 0, stream>>>(r_w, n_w, rwt);
    // LN1 -> split bf16
    ln1_split<<<dim3(Tn), blk, 0, stream>>>(x, ln1_s, ln1_b, h1hi, h1lo);
    // fused QKV: pipelined split GEMM, direct split-bf16 epilogue (q pre-scaled 1/8)
    gemm_bs<<<dim3(18, 32, 1), blk, 0, stream>>>(h1hi, h1lo, Dn, 0, wqkvTh, wqkvTl, Dn, 0,
        bqkv, nullptr, 0, 0, Dn, 1, 0, 1, qhi, qlo, khi, klo, vhi, vlo);
    vtrans16<<<dim3(16, 1, 48), blk, 0, stream>>>(vhi, vlo, vthi, vtlo);
    // flash attention: 1 launch; writes split-bf16 O over the Q region
    flash_attn<<<dim3(8, 48), blk, 0, stream>>>(qhi, qlo, khi, klo, vthi, vtlo, ohi, olo);
    // output projection (direct store) -> x2f
    gemm_bs<<<dim3(6, 32, 1), blk, 0, stream>>>(ohi, olo, Dn, 0, woTh, woTl, Dn, 0,
        bo, x2f, Dn, 0, Dn, 1, 0, 0, nullptr, nullptr, nullptr, nullptr, nullptr, nullptr);
    // LN2 + router fused (residual x added on the fly; h2 stored bf16 for MoE)
    ln2_router<<<dim3(Tn), blk, 0, stream>>>(x2f, x, ln2_s, ln2_b, rwt, r_b, n_b, noise,
                                             h2hi, gates, ind);
    hipMemsetAsync(buf, 0, (size_t)Tn * Dn * 4, stream);
    sort_rows<<<dim3(1), dim3(1024), 0, stream>>>(ind, meta, rows);
    // sparse experts, two DFF halves through one 18 MB transposed-weight region
    for (int h = 0; h < 2; ++h) {
        transpose_f32<<<dim3(24, 12, 8), blk, 0, stream>>>(
            e_w1 + (size_t)h * DHALF, DFFn, (long)Dn * DFFn, whalf, nullptr, Dn, (long)DHALF * Dn);
        moe_gemm1<<<dim3(12, 32, 8), blk, 0, stream>>>(h2hi, whalf, e_b1, rows, meta, eh, h);
        transpose_f32<<<dim3(12, 24, 8), blk, 0, stream>>>(
            e_w2 + (size_t)h * DHALF * Dn, Dn, (long)DFFn * Dn, whalf, nullptr, DHALF, (long)Dn * DHALF);
        moe_gemm2<<<dim3(6, 32, 8 * KS2), blk, 0, stream>>>(eh, whalf, h == 0 ? e_b2 : nullptr,
                                                            rows, meta, gates, buf);
    }
    final_add<<<dim3(Tn * Dn / 1024), blk, 0, stream>>>(x2f, x, buf, (float*)d_out);
}

// Round 5
// 700.652 us; speedup vs baseline: 1.7596x; 1.1967x over previous
//
#include <hip/hip_runtime.h>

#define DEV static __device__ __forceinline__

typedef __attribute__((ext_vector_type(8))) short v8s;
typedef __attribute__((ext_vector_type(4))) float v4f;

constexpr int Bn = 4, Sn = 1024, Dn = 768, NHn = 12, HDn = 64, En = 8, DFFn = 3072;
constexpr int Tn = Bn * Sn;          // 4096 tokens
constexpr int NROWS = 2 * Tn;        // 8192 gathered expert rows
constexpr int DHALF = DFFn / 2;      // 1536 (MoE processed in two DFF halves)
constexpr size_t MB = 1024 * 1024;

// ---- workspace map (~93.2 MB; lifetime-overlaid regions) ----
// era A (QKV): h1 [12,24) ; QKV epilogue -> q[0,12) k[24,36) v[48,60) ; vtrans -> vt[72,84)
// era B (flash attn): reads q[0,12) k[24,36) vt[72,84); writes O over q region [0,12)
// era C (proj): ohi/olo[0,12) | x2f[48,60) (v dead) | woT @90.75
// era D (MoE): eh[12,36) | whalf[60,78) | h2hi[78,84) | eo0[36,48) eo1[0,12) | x2f[48,60)
// [84,93.2) wqkvTh wqkvTl woTh woTl | bqkv rwt gates ind meta rows pos

DEV float bf2f(unsigned short h) {
    union { unsigned int u; float f; } c; c.u = ((unsigned int)h) << 16; return c.f;
}
DEV unsigned short f2bf(float f) {   // round-to-nearest-even
    union { float f; unsigned int u; } c; c.f = f;
    return (unsigned short)((c.u + 0x7fffu + ((c.u >> 16) & 1u)) >> 16);
}
DEV v4f mfma16(v8s a, v8s b, v4f c) {
    return __builtin_amdgcn_mfma_f32_16x16x32_bf16(a, b, c, 0, 0, 0);
}

// ---------------- transpose fp32 src -> bf16 hi (+ optional lo) ----------------
__global__ __launch_bounds__(256) void transpose_f32(const float* __restrict__ src,
                                                     int src_ld, long src_zs,
                                                     unsigned short* __restrict__ dsthi,
                                                     unsigned short* __restrict__ dstlo,
                                                     int dst_ld, long dst_zs) {
    src += (long)blockIdx.z * src_zs;
    dsthi += (long)blockIdx.z * dst_zs;
    if (dstlo) dstlo += (long)blockIdx.z * dst_zs;
    __shared__ float tile[64][65];
    int tid = threadIdx.x, tx = blockIdx.x, ty = blockIdx.y;
    int r = tid >> 2, c0 = (tid & 3) * 16;
    const float* sp = src + (long)(ty * 64 + r) * src_ld + tx * 64 + c0;
#pragma unroll
    for (int i = 0; i < 4; ++i) {
        float4 f = *(const float4*)(sp + i * 4);
        tile[r][c0 + i * 4 + 0] = f.x;
        tile[r][c0 + i * 4 + 1] = f.y;
        tile[r][c0 + i * 4 + 2] = f.z;
        tile[r][c0 + i * 4 + 3] = f.w;
    }
    __syncthreads();
    int dl = tid >> 2, s0 = (tid & 3) * 16;
    unsigned short hh[16] __attribute__((aligned(16)));
    unsigned short ll[16] __attribute__((aligned(16)));
#pragma unroll
    for (int i = 0; i < 16; ++i) {
        float f = tile[s0 + i][dl];
        unsigned short h0 = f2bf(f);
        hh[i] = h0;
        ll[i] = f2bf(f - bf2f(h0));
    }
    long o = (long)(tx * 64 + dl) * dst_ld + ty * 64 + s0;
    *(uint4*)(dsthi + o) = ((uint4*)hh)[0];
    *(uint4*)(dsthi + o + 8) = ((uint4*)hh)[1];
    if (dstlo) {
        *(uint4*)(dstlo + o) = ((uint4*)ll)[0];
        *(uint4*)(dstlo + o + 8) = ((uint4*)ll)[1];
    }
}

// ---------------- LN1: f32 in -> split bf16 out ----------------
__global__ __launch_bounds__(256) void ln1_split(const float* __restrict__ in_f,
                                                 const float* __restrict__ sc,
                                                 const float* __restrict__ bi,
                                                 unsigned short* __restrict__ hi,
                                                 unsigned short* __restrict__ lo) {
    int row = blockIdx.x, tid = threadIdx.x;
    long base = (long)row * Dn;
    float x[3];
#pragma unroll
    for (int j = 0; j < 3; ++j) x[j] = in_f[base + tid + j * 256];
    __shared__ float red[4];
    float s = x[0] + x[1] + x[2];
    for (int off = 32; off; off >>= 1) s += __shfl_down(s, off, 64);
    if ((tid & 63) == 0) red[tid >> 6] = s;
    __syncthreads();
    float mean = (red[0] + red[1] + red[2] + red[3]) * (1.0f / Dn);
    __syncthreads();
    float ss = 0.f;
#pragma unroll
    for (int j = 0; j < 3; ++j) { float d0 = x[j] - mean; ss += d0 * d0; }
    for (int off = 32; off; off >>= 1) ss += __shfl_down(ss, off, 64);
    if ((tid & 63) == 0) red[tid >> 6] = ss;
    __syncthreads();
    float var = (red[0] + red[1] + red[2] + red[3]) * (1.0f / Dn);
    float rstd = 1.0f / sqrtf(var + 1e-5f);
#pragma unroll
    for (int j = 0; j < 3; ++j) {
        int d = tid + j * 256;
        float y = (x[j] - mean) * rstd * sc[d] + bi[d];
        unsigned short h0 = f2bf(y);
        hi[base + d] = h0;
        lo[base + d] = f2bf(y - bf2f(h0));
    }
}

// ---------------- LN2 fused with router (input = x2f + x residual) ----------------
__global__ __launch_bounds__(256) void ln2_router(const float* __restrict__ in_f,
                                                  const float* __restrict__ xres,
                                                  const float* __restrict__ sc,
                                                  const float* __restrict__ bi,
                                                  const float* __restrict__ rwt,
                                                  const float* __restrict__ rb,
                                                  const float* __restrict__ nb,
                                                  const float* __restrict__ noise,
                                                  unsigned short* __restrict__ h2hi,
                                                  float* __restrict__ gates,
                                                  int* __restrict__ ind) {
    int t = blockIdx.x, tid = threadIdx.x;
    int w = tid >> 6, lane = tid & 63;
    long base = (long)t * Dn;
    float x[3];
#pragma unroll
    for (int j = 0; j < 3; ++j) x[j] = in_f[base + tid + j * 256] + xres[base + tid + j * 256];
    __shared__ float red[4];
    float s = x[0] + x[1] + x[2];
    for (int off = 32; off; off >>= 1) s += __shfl_down(s, off, 64);
    if ((tid & 63) == 0) red[tid >> 6] = s;
    __syncthreads();
    float mean = (red[0] + red[1] + red[2] + red[3]) * (1.0f / Dn);
    __syncthreads();
    float ss = 0.f;
#pragma unroll
    for (int j = 0; j < 3; ++j) { float d0 = x[j] - mean; ss += d0 * d0; }
    for (int off = 32; off; off >>= 1) ss += __shfl_down(ss, off, 64);
    if ((tid & 63) == 0) red[tid >> 6] = ss;
    __syncthreads();
    float var = (red[0] + red[1] + red[2] + red[3]) * (1.0f / Dn);
    float rstd = 1.0f / sqrtf(var + 1e-5f);
    float y[3];
#pragma unroll
    for (int j = 0; j < 3; ++j) {
        int d = tid + j * 256;
        y[j] = (x[j] - mean) * rstd * sc[d] + bi[d];
        h2hi[base + d] = f2bf(y[j]);
    }
    float acc[16];
#pragma unroll
    for (int e = 0; e < 16; ++e) {
        const float* wp = rwt + e * Dn + tid;
        acc[e] = y[0] * wp[0] + y[1] * wp[256] + y[2] * wp[512];
    }
#pragma unroll
    for (int e = 0; e < 16; ++e)
        for (int off = 32; off; off >>= 1) acc[e] += __shfl_down(acc[e], off, 64);
    __shared__ float red2[4][16];
    if (lane == 0)
#pragma unroll
        for (int e = 0; e < 16; ++e) red2[w][e] = acc[e];
    __syncthreads();
    if (tid == 0) {
        float noisy[8];
#pragma unroll
        for (int e = 0; e < 8; ++e) {
            float lg = red2[0][e] + red2[1][e] + red2[2][e] + red2[3][e] + rb[e];
            float nv = red2[0][8 + e] + red2[1][8 + e] + red2[2][8 + e] + red2[3][8 + e] + nb[e];
            float sp = fmaxf(nv, 0.f) + log1pf(expf(-fabsf(nv)));
            noisy[e] = lg + noise[(long)t * En + e] * sp;
        }
        int i0 = 0;
        for (int e = 1; e < 8; ++e) if (noisy[e] > noisy[i0]) i0 = e;
        int i1 = (i0 == 0) ? 1 : 0;
        for (int e = 0; e < 8; ++e) if (e != i0 && noisy[e] > noisy[i1]) i1 = e;
        float mm = fmaxf(noisy[i0], noisy[i1]);
        float e0 = expf(noisy[i0] - mm), e1 = expf(noisy[i1] - mm);
        float inv = 1.0f / (e0 + e1);
        gates[t] = e0 * inv;
        gates[Tn + t] = e1 * inv;
        ind[t] = i0;
        ind[Tn + t] = i1;
    }
}

// ------ counting sort of 8192 (tok,slot), parallel prefix; also inverse perm pos ------
__global__ __launch_bounds__(1024) void sort_rows(const int* __restrict__ ind,
                                                  int* __restrict__ meta,
                                                  int* __restrict__ rows,
                                                  int* __restrict__ pos) {
    __shared__ int wtot[8][17];
    __shared__ int bb[8];
    int tid = threadIdx.x, wv = tid >> 6, ln = tid & 63;
    int codes[8];
    int h[8] = {0, 0, 0, 0, 0, 0, 0, 0};
#pragma unroll
    for (int k = 0; k < 8; ++k) {
        int i = tid * 8 + k;
        int e = ind[(i & 1) * Tn + (i >> 1)];
        codes[k] = e;
        ++h[e];
    }
    int pre[8];
#pragma unroll
    for (int e = 0; e < 8; ++e) {
        int x = h[e];
#pragma unroll
        for (int off = 1; off < 64; off <<= 1) {
            int y = __shfl_up(x, off, 64);
            if (ln >= off) x += y;
        }
        pre[e] = x - h[e];
        if (ln == 63) wtot[e][wv] = x;
    }
    __syncthreads();
    if (tid < 8) {
        int run = 0;
        for (int w2 = 0; w2 < 16; ++w2) {
            int v = wtot[tid][w2];
            wtot[tid][w2] = run;
            run += v;
        }
        wtot[tid][16] = run;
        meta[tid] = run;                 // counts
    }
    __syncthreads();
    if (tid == 0) {
        int b = 0;
        for (int e = 0; e < 8; ++e) {
            bb[e] = b;
            meta[16 + e] = b;
            b += wtot[e][16];
        }
        meta[24] = b;
    }
    __syncthreads();
    int c[8];
#pragma unroll
    for (int e = 0; e < 8; ++e) c[e] = bb[e] + wtot[e][wv] + pre[e];
#pragma unroll
    for (int k = 0; k < 8; ++k) {
        int e = codes[k];
        int code = tid * 8 + k;          // value == t*2+slot
        rows[c[e]] = code;
        pos[code] = c[e];
        ++c[e];
    }
}

// ---------------- tiny packers ----------------
__global__ void pack_router(const float* __restrict__ rw, const float* __restrict__ nw,
                            float* __restrict__ rwt) {
    int idx = blockIdx.x * 256 + threadIdx.x;   // [0, 16*768)
    int e = idx / Dn, d = idx - e * Dn;
    rwt[idx] = (e < 8) ? rw[d * En + e] : nw[d * En + (e - 8)];
}

__global__ void pack_bias(const float* __restrict__ bq, const float* __restrict__ bk,
                          const float* __restrict__ bv, float* __restrict__ bqkv) {
    int i = blockIdx.x * 256 + threadIdx.x;     // [0, 2304)
    bqkv[i] = (i < 768) ? bq[i] : (i < 1536 ? bk[i - 768] : bv[i - 1536]);
}

// ---------------- pure-bf16 split GEMM, 128x128 tile, 3-product, reg-pipelined ----------
// mode 0: f32 C store (or atomic), bias @ks==0  (o-proj)
// mode 1: QKV: cols [0,768)->q(*0.125), [768,1536)->k, [1536,2304)->v, split bf16 out
__global__ __launch_bounds__(256, 2) void gemm_bs(
    const unsigned short* __restrict__ Ahi, const unsigned short* __restrict__ Alo,
    int lda, long za,
    const unsigned short* __restrict__ Bhi, const unsigned short* __restrict__ Blo,
    int ldb, long zb,
    const float* __restrict__ bias,
    float* __restrict__ Cf, int ldc, long zc, int K, int zdiv, int catomic, int mode,
    unsigned short* __restrict__ oqh, unsigned short* __restrict__ oql,
    unsigned short* __restrict__ okh, unsigned short* __restrict__ okl,
    unsigned short* __restrict__ ovh, unsigned short* __restrict__ ovl) {
    int z = blockIdx.z;
    int zi = z / zdiv, ks = z - zi * zdiv;
    int Klen = K / zdiv, k0base = ks * Klen;
    Ahi += (long)zi * za;
    Alo += (long)zi * za;
    Bhi += (long)zi * zb;
    Blo += (long)zi * zb;
    int n0 = blockIdx.x * 128, m0 = blockIdx.y * 128;
    int tid = threadIdx.x, w = tid >> 6, lane = tid & 63, quad = lane >> 4, l16 = lane & 15;
    int wm = w >> 1, wn = w & 1;
    __shared__ unsigned short Ah[128][40], Al[128][40], Bh[128][40], Bl[128][40];
    v4f acc[4][4] = {};
    int ar = tid >> 1, ac = (tid & 1) * 16;
    const unsigned short* pah = Ahi + (long)(m0 + ar) * lda + k0base + ac;
    const unsigned short* pal = Alo + (long)(m0 + ar) * lda + k0base + ac;
    const unsigned short* pbh = Bhi + (long)(n0 + ar) * ldb + k0base + ac;
    const unsigned short* pbl = Blo + (long)(n0 + ar) * ldb + k0base + ac;
    int nsteps = Klen >> 5;
    uint4 ra0, ra1, rb0, rb1, rc0, rc1, rd0, rd1;
#define LOADK(kt) { int o_ = (kt) << 5; \
    ra0 = *(const uint4*)(pah + o_); ra1 = *(const uint4*)(pah + o_ + 8); \
    rb0 = *(const uint4*)(pal + o_); rb1 = *(const uint4*)(pal + o_ + 8); \
    rc0 = *(const uint4*)(pbh + o_); rc1 = *(const uint4*)(pbh + o_ + 8); \
    rd0 = *(const uint4*)(pbl + o_); rd1 = *(const uint4*)(pbl + o_ + 8); }
    LOADK(0);
    for (int kt = 0; kt < nsteps; ++kt) {
        *(uint4*)&Ah[ar][ac] = ra0;
        *(uint4*)&Ah[ar][ac + 8] = ra1;
        *(uint4*)&Al[ar][ac] = rb0;
        *(uint4*)&Al[ar][ac + 8] = rb1;
        *(uint4*)&Bh[ar][ac] = rc0;
        *(uint4*)&Bh[ar][ac + 8] = rc1;
        *(uint4*)&Bl[ar][ac] = rd0;
        *(uint4*)&Bl[ar][ac + 8] = rd1;
        __syncthreads();
        if (kt + 1 < nsteps) LOADK(kt + 1);   // issue early; hides under MFMA
        v8s afh[4], afl[4];
#pragma unroll
        for (int mt = 0; mt < 4; ++mt) {
            afh[mt] = *(const v8s*)&Ah[wm * 64 + mt * 16 + l16][quad * 8];
            afl[mt] = *(const v8s*)&Al[wm * 64 + mt * 16 + l16][quad * 8];
        }
#pragma unroll
        for (int nt = 0; nt < 4; ++nt) {
            v8s bbh = *(const v8s*)&Bh[wn * 64 + nt * 16 + l16][quad * 8];
            v8s bbl = *(const v8s*)&Bl[wn * 64 + nt * 16 + l16][quad * 8];
#pragma unroll
            for (int mt = 0; mt < 4; ++mt) acc[mt][nt] = mfma16(afh[mt], bbh, acc[mt][nt]);
#pragma unroll
            for (int mt = 0; mt < 4; ++mt) acc[mt][nt] = mfma16(afl[mt], bbh, acc[mt][nt]);
#pragma unroll
            for (int mt = 0; mt < 4; ++mt) acc[mt][nt] = mfma16(afh[mt], bbl, acc[mt][nt]);
        }
        __syncthreads();
    }
#undef LOADK
    if (mode == 1) {
#pragma unroll
        for (int mt = 0; mt < 4; ++mt)
#pragma unroll
            for (int nt = 0; nt < 4; ++nt)
#pragma unroll
                for (int r = 0; r < 4; ++r) {
                    int row = m0 + wm * 64 + mt * 16 + quad * 4 + r;
                    int col = n0 + wn * 64 + nt * 16 + l16;
                    float v = acc[mt][nt][r] + bias[col];
                    int seg = (col >= 1536) ? 2 : (col >= 768 ? 1 : 0);
                    int c = col - seg * 768;
                    if (seg == 0) v *= 0.125f;   // fold 1/sqrt(HD) into q
                    long ci = (long)row * Dn + c;
                    unsigned short* dh = (seg == 0) ? oqh : (seg == 1 ? okh : ovh);
                    unsigned short* dl = (seg == 0) ? oql : (seg == 1 ? okl : ovl);
                    unsigned short h0 = f2bf(v);
                    dh[ci] = h0;
                    dl[ci] = f2bf(v - bf2f(h0));
                }
    } else {
        long coff = (long)zi * zc;
#pragma unroll
        for (int mt = 0; mt < 4; ++mt)
#pragma unroll
            for (int nt = 0; nt < 4; ++nt)
#pragma unroll
                for (int r = 0; r < 4; ++r) {
                    int row = m0 + wm * 64 + mt * 16 + quad * 4 + r;
                    int col = n0 + wn * 64 + nt * 16 + l16;
                    float v = acc[mt][nt][r];
                    if (ks == 0 && bias) v += bias[col];
                    long ci = coff + (long)row * ldc + col;
                    if (catomic) atomicAdd(&Cf[ci], v);
                    else Cf[ci] = v;
                }
    }
}

// ---------------- flash attention: one block = (q-tile 128) x (b,h) ----------------
// Q pre-scaled by 1/8. No max-shift (|s| small). O normalized in-reg, written as
// split bf16 over the (block-exclusive, consumed) Q region.
__global__ __launch_bounds__(256) void flash_attn(
    const unsigned short* __restrict__ qhi, const unsigned short* __restrict__ qlo,
    const unsigned short* __restrict__ khi, const unsigned short* __restrict__ klo,
    const unsigned short* __restrict__ vthi, const unsigned short* __restrict__ vtlo,
    unsigned short* __restrict__ ohi, unsigned short* __restrict__ olo) {
    int g = blockIdx.y, b = g / NHn, h = g - b * NHn;
    int m0 = blockIdx.x * 128;
    int tid = threadIdx.x, w = tid >> 6, lane = tid & 63, quad = lane >> 4, l16 = lane & 15;
    __shared__ unsigned short Kh[2][64][40], Kl[2][64][40];
    __shared__ unsigned short Vh[2][64][40], Vl[2][64][40];
    __shared__ unsigned short Ph[4][2][32][40];   // per-wave P (hi only)
    // Q fragments in registers (rows m0+w*32+mt*16+l16, d = kk*32+quad*8+..)
    v8s qh[2][2], ql[2][2];
    long qrow0 = (long)b * Sn + m0 + w * 32;
#pragma unroll
    for (int mt = 0; mt < 2; ++mt)
#pragma unroll
        for (int kk = 0; kk < 2; ++kk) {
            long off = (qrow0 + mt * 16 + l16) * Dn + h * 64 + kk * 32 + quad * 8;
            qh[mt][kk] = *(const v8s*)(qhi + off);
            ql[mt][kk] = *(const v8s*)(qlo + off);
        }
    v4f accO[2][4] = {};
    float rs[2][4] = {};
    // staging thread mapping: srow in [0,32), su selects (kk, 8-col chunk)
    int srow = tid >> 3, su = tid & 7, skk = su >> 2, scu = (su & 3) * 8;
    const unsigned short* kb_h = khi + ((long)b * Sn + srow) * Dn + h * 64 + skk * 32 + scu;
    const unsigned short* kb_l = klo + ((long)b * Sn + srow) * Dn + h * 64 + skk * 32 + scu;
    const unsigned short* vb_h = vthi + ((long)g * 64 + srow) * Sn + skk * 32 + scu;
    const unsigned short* vb_l = vtlo + ((long)g * 64 + srow) * Sn + skk * 32 + scu;
    uint4 pkh0, pkh1, pkl0, pkl1, pvh0, pvh1, pvl0, pvl1;
#define LOADT(t) { long ko = (long)(t) * 64 * Dn; int vo = (t) * 64; \
    pkh0 = *(const uint4*)(kb_h + ko); pkh1 = *(const uint4*)(kb_h + ko + (long)32 * Dn); \
    pkl0 = *(const uint4*)(kb_l + ko); pkl1 = *(const uint4*)(kb_l + ko + (long)32 * Dn); \
    pvh0 = *(const uint4*)(vb_h + vo); pvh1 = *(const uint4*)(vb_h + vo + 32 * Sn); \
    pvl0 = *(const uint4*)(vb_l + vo); pvl1 = *(const uint4*)(vb_l + vo + 32 * Sn); }
    LOADT(0);
    for (int t = 0; t < 16; ++t) {
        __syncthreads();                 // prev iter's K/V reads done
        *(uint4*)&Kh[skk][srow][scu] = pkh0;
        *(uint4*)&Kh[skk][srow + 32][scu] = pkh1;
        *(uint4*)&Kl[skk][srow][scu] = pkl0;
        *(uint4*)&Kl[skk][srow + 32][scu] = pkl1;
        *(uint4*)&Vh[skk][srow][scu] = pvh0;
        *(uint4*)&Vh[skk][srow + 32][scu] = pvh1;
        *(uint4*)&Vl[skk][srow][scu] = pvl0;
        *(uint4*)&Vl[skk][srow + 32][scu] = pvl1;
        __syncthreads();
        if (t < 15) LOADT(t + 1);        // latency hides under compute
        // ---- S = Q K^T (3-product split) ----
        v4f accS[2][4] = {};
#pragma unroll
        for (int nt = 0; nt < 4; ++nt)
#pragma unroll
            for (int kk = 0; kk < 2; ++kk) {
                v8s bh = *(const v8s*)&Kh[kk][nt * 16 + l16][quad * 8];
                v8s bl = *(const v8s*)&Kl[kk][nt * 16 + l16][quad * 8];
#pragma unroll
                for (int mt = 0; mt < 2; ++mt) {
                    accS[mt][nt] = mfma16(qh[mt][kk], bh, accS[mt][nt]);
                    accS[mt][nt] = mfma16(ql[mt][kk], bh, accS[mt][nt]);
                    accS[mt][nt] = mfma16(qh[mt][kk], bl, accS[mt][nt]);
                }
            }
        // ---- P = exp(S) -> bf16 in wave-private LDS; rowsum of quantized P ----
#pragma unroll
        for (int mt = 0; mt < 2; ++mt)
#pragma unroll
            for (int r = 0; r < 4; ++r) {
                int prow = mt * 16 + quad * 4 + r;
                float psum = 0.f;
#pragma unroll
                for (int nt = 0; nt < 4; ++nt) {
                    float p = __expf(accS[mt][nt][r]);
                    unsigned short hh = f2bf(p);
                    psum += bf2f(hh);    // normalize exactly what PV consumes
                    Ph[w][nt >> 1][prow][(nt & 1) * 16 + l16] = hh;
                }
                rs[mt][r] += psum;
            }
        // ---- O += P V (P-hi x split-V) ----
#pragma unroll
        for (int kk = 0; kk < 2; ++kk) {
            v8s pa0 = *(const v8s*)&Ph[w][kk][l16][quad * 8];
            v8s pa1 = *(const v8s*)&Ph[w][kk][16 + l16][quad * 8];
#pragma unroll
            for (int nt = 0; nt < 4; ++nt) {
                v8s vh = *(const v8s*)&Vh[kk][nt * 16 + l16][quad * 8];
                v8s vl = *(const v8s*)&Vl[kk][nt * 16 + l16][quad * 8];
                accO[0][nt] = mfma16(pa0, vh, accO[0][nt]);
                accO[1][nt] = mfma16(pa1, vh, accO[1][nt]);
                accO[0][nt] = mfma16(pa0, vl, accO[0][nt]);
                accO[1][nt] = mfma16(pa1, vl, accO[1][nt]);
            }
        }
    }
#undef LOADT
    // ---- epilogue: finish rowsums (16-lane reduce), normalize, write split bf16 ----
#pragma unroll
    for (int mt = 0; mt < 2; ++mt)
#pragma unroll
        for (int r = 0; r < 4; ++r) {
            float s = rs[mt][r];
#pragma unroll
            for (int off = 1; off < 16; off <<= 1) s += __shfl_xor(s, off, 64);
            float inv = 1.0f / s;
            long orow = qrow0 + mt * 16 + quad * 4 + r;
#pragma unroll
            for (int nt = 0; nt < 4; ++nt) {
                float v = accO[mt][nt][r] * inv;
                unsigned short hh = f2bf(v);
                long oi = orow * Dn + h * 64 + nt * 16 + l16;
                ohi[oi] = hh;
                olo[oi] = f2bf(v - bf2f(hh));
            }
        }
}

// ---------------- V transpose (bf16 hi/lo): v[b,s,h,d] -> vt[g=b*12+h][d][s] ----------
__global__ __launch_bounds__(256) void vtrans16(const unsigned short* __restrict__ vhi,
                                                const unsigned short* __restrict__ vlo,
                                                unsigned short* __restrict__ vthi,
                                                unsigned short* __restrict__ vtlo) {
    int g = blockIdx.z, b = g / NHn, h = g % NHn;
    int stile = blockIdx.x, tid = threadIdx.x;
    __shared__ unsigned short th[64][66], tl[64][66];
    int sl = tid >> 2, c0 = (tid & 3) * 16;
    long src = (long)(b * Sn + stile * 64 + sl) * Dn + h * 64 + c0;
    *(uint4*)&th[sl][c0] = *(const uint4*)(vhi + src);
    *(uint4*)&th[sl][c0 + 8] = *(const uint4*)(vhi + src + 8);
    *(uint4*)&tl[sl][c0] = *(const uint4*)(vlo + src);
    *(uint4*)&tl[sl][c0 + 8] = *(const uint4*)(vlo + src + 8);
    __syncthreads();
    int dl = tid >> 2, s0 = (tid & 3) * 16;
    unsigned short hh[16] __attribute__((aligned(16)));
    unsigned short ll[16] __attribute__((aligned(16)));
#pragma unroll
    for (int i = 0; i < 16; ++i) {
        hh[i] = th[s0 + i][dl];
        ll[i] = tl[s0 + i][dl];
    }
    long o = (long)(g * 64 + dl) * Sn + stile * 64 + s0;
    *(uint4*)(vthi + o) = ((uint4*)hh)[0];
    *(uint4*)(vthi + o + 8) = ((uint4*)hh)[1];
    *(uint4*)(vtlo + o) = ((uint4*)ll)[0];
    *(uint4*)(vtlo + o + 8) = ((uint4*)ll)[1];
}

// ---------------- MoE stage 1 (per DFF half): eh = relu(h2 @ W1t[e]^T + b1), pipelined ----
__global__ __launch_bounds__(256, 2) void moe_gemm1(const unsigned short* __restrict__ h2hi,
                                                    const unsigned short* __restrict__ W1t,
                                                    const float* __restrict__ eb1,
                                                    const int* __restrict__ rows,
                                                    const int* __restrict__ meta,
                                                    unsigned short* __restrict__ eh,
                                                    int half) {
    int e = blockIdx.z;
    int cnt = meta[e];
    int mb = blockIdx.y * 128;
    if (mb >= cnt) return;
    int base_e = meta[16 + e];
    int valid = cnt - mb; if (valid > 128) valid = 128;
    int tid = threadIdx.x;
    __shared__ int toks[128];
    if (tid < 128) {
        int idx = mb + tid;
        toks[tid] = rows[base_e + (idx < cnt ? idx : 0)];
    }
    __shared__ unsigned short As[128][40], Bs[128][40];
    int w = tid >> 6, lane = tid & 63, quad = lane >> 4, l16 = lane & 15;
    int wm = w >> 1, wn = w & 1;
    v4f acc[4][4] = {};
    int ar = tid >> 1, ac = (tid & 1) * 16;
    int nb0 = blockIdx.x * 128;
    const unsigned short* Wb = W1t + (long)e * DHALF * Dn;
    __syncthreads();
    const unsigned short* apg = h2hi + (long)(toks[ar] >> 1) * Dn + ac;
    const unsigned short* bpg = Wb + (long)(nb0 + ar) * Dn + ac;
    uint4 a0, a1, b0, b1;
#define LOADK(kt) { int o_ = (kt) * 32; \
    a0 = *(const uint4*)(apg + o_); a1 = *(const uint4*)(apg + o_ + 8); \
    b0 = *(const uint4*)(bpg + o_); b1 = *(const uint4*)(bpg + o_ + 8); }
    LOADK(0);
    for (int kt = 0; kt < Dn / 32; ++kt) {
        *(uint4*)&As[ar][ac] = a0;
        *(uint4*)&As[ar][ac + 8] = a1;
        *(uint4*)&Bs[ar][ac] = b0;
        *(uint4*)&Bs[ar][ac + 8] = b1;
        __syncthreads();
        if (kt + 1 < Dn / 32) LOADK(kt + 1);
        v8s af[4];
#pragma unroll
        for (int mt = 0; mt < 4; ++mt) af[mt] = *(const v8s*)&As[wm * 64 + mt * 16 + l16][quad * 8];
#pragma unroll
        for (int nt = 0; nt < 4; ++nt) {
            v8s bb = *(const v8s*)&Bs[wn * 64 + nt * 16 + l16][quad * 8];
#pragma unroll
            for (int mt = 0; mt < 4; ++mt) acc[mt][nt] = mfma16(af[mt], bb, acc[mt][nt]);
        }
        __syncthreads();
    }
#undef LOADK
#pragma unroll
    for (int mt = 0; mt < 4; ++mt)
#pragma unroll
        for (int nt = 0; nt < 4; ++nt)
#pragma unroll
            for (int r = 0; r < 4; ++r) {
                int rl = wm * 64 + mt * 16 + quad * 4 + r;
                if (rl < valid) {
                    int col = nb0 + wn * 64 + nt * 16 + l16;
                    float v = acc[mt][nt][r] + eb1[e * DFFn + half * DHALF + col];
                    v = fmaxf(v, 0.f);
                    eh[(long)(base_e + mb + rl) * DHALF + col] = f2bf(v);
                }
            }
}

// -------- MoE stage 2 (per DFF half, K-split x2 into eo0/eo1, NO atomics) --------
// ks=0 -> eo0, ks=1 -> eo1 (bf16 [NROWS][Dn]); half0 stores, half1 read-add-stores.
__global__ __launch_bounds__(256, 2) void moe_gemm2(const unsigned short* __restrict__ eh,
                                                    const unsigned short* __restrict__ W2t,
                                                    const float* __restrict__ eb2,
                                                    const int* __restrict__ meta,
                                                    unsigned short* __restrict__ eo0,
                                                    unsigned short* __restrict__ eo1,
                                                    int accum) {
    int z = blockIdx.z;
    int e = z >> 1, ks = z & 1;
    int k0b = ks * (DHALF / 2);
    int cnt = meta[e];
    int mb = blockIdx.y * 128;
    if (mb >= cnt) return;
    int base_e = meta[16 + e];
    int valid = cnt - mb; if (valid > 128) valid = 128;
    int tid = threadIdx.x;
    __shared__ unsigned short As[128][40], Bs[128][40];
    int w = tid >> 6, lane = tid & 63, quad = lane >> 4, l16 = lane & 15;
    int wm = w >> 1, wn = w & 1;
    v4f acc[4][4] = {};
    int ar = tid >> 1, ac = (tid & 1) * 16;
    int nb0 = blockIdx.x * 128;
    const unsigned short* Wb = W2t + (long)e * Dn * DHALF;
    long arow = (long)base_e + mb + ar;
    if (arow > NROWS - 1) arow = NROWS - 1;
    const unsigned short* apg = eh + arow * DHALF + k0b + ac;
    const unsigned short* bpg = Wb + (long)(nb0 + ar) * DHALF + k0b + ac;
    uint4 a0, a1, b0, b1;
#define LOADK(kt) { int o_ = (kt) * 32; \
    a0 = *(const uint4*)(apg + o_); a1 = *(const uint4*)(apg + o_ + 8); \
    b0 = *(const uint4*)(bpg + o_); b1 = *(const uint4*)(bpg + o_ + 8); }
    LOADK(0);
    constexpr int NK = (DHALF / 2) / 32;   // 24
    for (int kt = 0; kt < NK; ++kt) {
        *(uint4*)&As[ar][ac] = a0;
        *(uint4*)&As[ar][ac + 8] = a1;
        *(uint4*)&Bs[ar][ac] = b0;
        *(uint4*)&Bs[ar][ac + 8] = b1;
        __syncthreads();
        if (kt + 1 < NK) LOADK(kt + 1);
        v8s af[4];
#pragma unroll
        for (int mt = 0; mt < 4; ++mt) af[mt] = *(const v8s*)&As[wm * 64 + mt * 16 + l16][quad * 8];
#pragma unroll
        for (int nt = 0; nt < 4; ++nt) {
            v8s bb = *(const v8s*)&Bs[wn * 64 + nt * 16 + l16][quad * 8];
#pragma unroll
            for (int mt = 0; mt < 4; ++mt) acc[mt][nt] = mfma16(af[mt], bb, acc[mt][nt]);
        }
        __syncthreads();
    }
#undef LOADK
    unsigned short* eo = ks ? eo1 : eo0;
#pragma unroll
    for (int mt = 0; mt < 4; ++mt)
#pragma unroll
        for (int nt = 0; nt < 4; ++nt)
#pragma unroll
            for (int r = 0; r < 4; ++r) {
                int rl = wm * 64 + mt * 16 + quad * 4 + r;
                if (rl < valid) {
                    int col = nb0 + wn * 64 + nt * 16 + l16;
                    long idx = (long)(base_e + mb + rl) * Dn + col;
                    float v = acc[mt][nt][r];
                    if (eb2 && ks == 0) v += eb2[e * Dn + col];
                    if (accum) v += bf2f(eo[idx]);
                    eo[idx] = f2bf(v);
                }
            }
}

// ---------------- final: out = x + x2f + g0*(eo0+eo1)[pos0] + g1*(eo0+eo1)[pos1] --------
__global__ __launch_bounds__(256) void final_add(const float* __restrict__ x2f,
                                                 const float* __restrict__ xres,
                                                 const unsigned short* __restrict__ eo0,
                                                 const unsigned short* __restrict__ eo1,
                                                 const float* __restrict__ gates,
                                                 const int* __restrict__ pos,
                                                 float* __restrict__ out) {
    int t = blockIdx.x, tid = threadIdx.x;
    int p0 = pos[2 * t], p1 = pos[2 * t + 1];
    float g0 = gates[t], g1 = gates[Tn + t];
    long b0 = (long)p0 * Dn, b1 = (long)p1 * Dn;
    long xb = (long)t * Dn;
#pragma unroll
    for (int j = 0; j < 3; ++j) {
        int d = tid + j * 256;
        float m0 = bf2f(eo0[b0 + d]) + bf2f(eo1[b0 + d]);
        float m1 = bf2f(eo0[b1 + d]) + bf2f(eo1[b1 + d]);
        out[xb + d] = x2f[xb + d] + xres[xb + d] + g0 * m0 + g1 * m1;
    }
}

extern "C" void kernel_launch(void* const* d_in, const int* in_sizes, int n_in,
                              void* d_out, int out_size, void* d_ws, size_t ws_size,
                              hipStream_t stream) {
    const float* x     = (const float*)d_in[0];
    const float* noise = (const float*)d_in[1];
    const float* wq = (const float*)d_in[2];
    const float* bq = (const float*)d_in[3];
    const float* wk = (const float*)d_in[4];
    const float* bk = (const float*)d_in[5];
    const float* wv = (const float*)d_in[6];
    const float* bv = (const float*)d_in[7];
    const float* wo = (const float*)d_in[8];
    const float* bo = (const float*)d_in[9];
    const float* ln1_s = (const float*)d_in[10];
    const float* ln1_b = (const float*)d_in[11];
    const float* ln2_s = (const float*)d_in[12];
    const float* ln2_b = (const float*)d_in[13];
    const float* r_w = (const float*)d_in[14];
    const float* r_b = (const float*)d_in[15];
    const float* n_w = (const float*)d_in[16];
    const float* n_b = (const float*)d_in[17];
    const float* e_w1 = (const float*)d_in[18];
    const float* e_b1 = (const float*)d_in[19];
    const float* e_w2 = (const float*)d_in[20];
    const float* e_b2 = (const float*)d_in[21];

    char* ws = (char*)d_ws;
    unsigned short* qhi  = (unsigned short*)(ws + 0);
    unsigned short* qlo  = (unsigned short*)(ws + 6 * MB);
    unsigned short* ohi  = qhi;                              // flash writes O over Q
    unsigned short* olo  = qlo;
    unsigned short* eo1  = (unsigned short*)(ws + 0);        // era D (o dead)
    unsigned short* h1hi = (unsigned short*)(ws + 12 * MB);  // era A
    unsigned short* h1lo = (unsigned short*)(ws + 18 * MB);
    unsigned short* eh   = (unsigned short*)(ws + 12 * MB);  // era D (24 MB)
    unsigned short* khi  = (unsigned short*)(ws + 24 * MB);
    unsigned short* klo  = (unsigned short*)(ws + 30 * MB);
    unsigned short* eo0  = (unsigned short*)(ws + 36 * MB);  // era D (12 MB bf16)
    unsigned short* vhi  = (unsigned short*)(ws + 48 * MB);  // era A
    unsigned short* vlo  = (unsigned short*)(ws + 54 * MB);
    float* x2f  = (float*)(ws + 48 * MB);                    // era C/D (v dead)
    unsigned short* whalf = (unsigned short*)(ws + 60 * MB); // era D (18 MB)
    unsigned short* vthi = (unsigned short*)(ws + 72 * MB);
    unsigned short* vtlo = (unsigned short*)(ws + 78 * MB);
    unsigned short* h2hi  = (unsigned short*)(ws + 78 * MB); // era D (vtlo dead)
    unsigned short* wqkvTh = (unsigned short*)(ws + 84 * MB);          // [2304][768]
    unsigned short* wqkvTl = wqkvTh + (size_t)3 * Dn * Dn;
    unsigned short* woTh = wqkvTl + (size_t)3 * Dn * Dn;
    unsigned short* woTl = woTh + (size_t)Dn * Dn;
    char* misc = (char*)(woTl + (size_t)Dn * Dn);
    float* bqkv = (float*)misc;                          // 2304 f
    float* rwt  = (float*)(misc + 2304 * 4);             // 16*768 f
    float* gates = (float*)(misc + 2304 * 4 + 12288 * 4);
    int* ind  = (int*)((char*)gates + 2 * Tn * 4);
    int* meta = (int*)((char*)ind + 2 * Tn * 4);
    int* rows = (int*)((char*)meta + 256);
    int* pos  = rows + NROWS;

    dim3 blk(256);
    // packed QKV weight transpose ([D,D] f32 -> bf16 hi/lo rows of [2304][768])
    transpose_f32<<<dim3(12, 12, 1), blk, 0, stream>>>(wq, Dn, 0, wqkvTh, wqkvTl, Dn, 0);
    transpose_f32<<<dim3(12, 12, 1), blk, 0, stream>>>(wk, Dn, 0,
        wqkvTh + (size_t)Dn * Dn, wqkvTl + (size_t)Dn * Dn, Dn, 0);
    transpose_f32<<<dim3(12, 12, 1), blk, 0, stream>>>(wv, Dn, 0,
        wqkvTh + (size_t)2 * Dn * Dn, wqkvTl + (size_t)2 * Dn * Dn, Dn, 0);
    transpose_f32<<<dim3(12, 12, 1), blk, 0, stream>>>(wo, Dn, 0, woTh, woTl, Dn, 0);
    pack_bias<<<dim3(9), blk, 0, stream>>>(bq, bk, bv, bqkv);
    pack_router<<<dim3(48), blk, 0, stream>>>(r_w, n_w, rwt);
    // LN1 -> split bf16
    ln1_split<<<dim3(Tn), blk, 0, stream>>>(x, ln1_s, ln1_b, h1hi, h1lo);
    // fused QKV: pipelined split GEMM, direct split-bf16 epilogue (q pre-scaled 1/8)
    gemm_bs<<<dim3(18, 32, 1), blk, 0, stream>>>(h1hi, h1lo, Dn, 0, wqkvTh, wqkvTl, Dn, 0,
        bqkv, nullptr, 0, 0, Dn, 1, 0, 1, qhi, qlo, khi, klo, vhi, vlo);
    vtrans16<<<dim3(16, 1, 48), blk, 0, stream>>>(vhi, vlo, vthi, vtlo);
    // flash attention: 1 launch; writes split-bf16 O over the Q region
    flash_attn<<<dim3(8, 48), blk, 0, stream>>>(qhi, qlo, khi, klo, vthi, vtlo, ohi, olo);
    // output projection (direct store) -> x2f
    gemm_bs<<<dim3(6, 32, 1), blk, 0, stream>>>(ohi, olo, Dn, 0, woTh, woTl, Dn, 0,
        bo, x2f, Dn, 0, Dn, 1, 0, 0, nullptr, nullptr, nullptr, nullptr, nullptr, nullptr);
    // LN2 + router fused (residual x added on the fly; h2 stored bf16 for MoE)
    ln2_router<<<dim3(Tn), blk, 0, stream>>>(x2f, x, ln2_s, ln2_b, rwt, r_b, n_b, noise,
                                             h2hi, gates, ind);
    sort_rows<<<dim3(1), dim3(1024), 0, stream>>>(ind, meta, rows, pos);
    // sparse experts, two DFF halves through one 18 MB transposed-weight region
    for (int h = 0; h < 2; ++h) {
        transpose_f32<<<dim3(24, 12, 8), blk, 0, stream>>>(
            e_w1 + (size_t)h * DHALF, DFFn, (long)Dn * DFFn, whalf, nullptr, Dn, (long)DHALF * Dn);
        moe_gemm1<<<dim3(12, 32, 8), blk, 0, stream>>>(h2hi, whalf, e_b1, rows, meta, eh, h);
        transpose_f32<<<dim3(12, 24, 8), blk, 0, stream>>>(
            e_w2 + (size_t)h * DHALF * Dn, Dn, (long)DFFn * Dn, whalf, nullptr, DHALF, (long)Dn * DHALF);
        moe_gemm2<<<dim3(6, 32, 16), blk, 0, stream>>>(eh, whalf, h == 0 ? e_b2 : nullptr,
                                                       meta, eo0, eo1, h);
    }
    final_add<<<dim3(Tn), blk, 0, stream>>>(x2f, x, eo0, eo1, gates, pos, (float*)d_out);
}

// Round 6
// 655.813 us; speedup vs baseline: 1.8799x; 1.0684x over previous
//
#include <hip/hip_runtime.h>

#define DEV static __device__ __forceinline__

typedef __attribute__((ext_vector_type(8))) short v8s;
typedef __attribute__((ext_vector_type(4))) float v4f;

constexpr int Bn = 4, Sn = 1024, Dn = 768, NHn = 12, HDn = 64, En = 8, DFFn = 3072;
constexpr int Tn = Bn * Sn;          // 4096 tokens
constexpr int NROWS = 2 * Tn;        // 8192 gathered expert rows
constexpr int DHALF = DFFn / 2;      // 1536 (MoE processed in two DFF halves)
constexpr int YT = 72;               // flat tile-grid upper bound (64 + 7 + slack)
constexpr size_t MB = 1024 * 1024;

// ---- workspace map (~93.2 MB; lifetime-overlaid regions) ----
// era A (QKV): h1 [12,24) ; QKV epilogue -> q[0,12) k[24,36) v[48,60) ; vtrans -> vt[72,84)
// era B (flash attn): reads q[0,12) k[24,36) vt[72,84); writes O over q region [0,12)
// era C (proj): ohi/olo[0,12) | x2f[48,60) (v dead) | woT @90.75
// era D (MoE): eh[12,36) | whalf[60,78) | h2hi[78,84) | eo0[36,48) eo1[0,12) | x2f[48,60)
// [84,93.2) wqkvTh wqkvTl woTh woTl | bqkv rwt gates ind meta rows pos

DEV float bf2f(unsigned short h) {
    union { unsigned int u; float f; } c; c.u = ((unsigned int)h) << 16; return c.f;
}
DEV unsigned short f2bf(float f) {   // round-to-nearest-even
    union { float f; unsigned int u; } c; c.f = f;
    return (unsigned short)((c.u + 0x7fffu + ((c.u >> 16) & 1u)) >> 16);
}
DEV v4f mfma16(v8s a, v8s b, v4f c) {
    return __builtin_amdgcn_mfma_f32_16x16x32_bf16(a, b, c, 0, 0, 0);
}

// ---------------- transpose fp32 src -> bf16 hi (+ optional lo) ----------------
__global__ __launch_bounds__(256) void transpose_f32(const float* __restrict__ src,
                                                     int src_ld, long src_zs,
                                                     unsigned short* __restrict__ dsthi,
                                                     unsigned short* __restrict__ dstlo,
                                                     int dst_ld, long dst_zs) {
    src += (long)blockIdx.z * src_zs;
    dsthi += (long)blockIdx.z * dst_zs;
    if (dstlo) dstlo += (long)blockIdx.z * dst_zs;
    __shared__ float tile[64][65];
    int tid = threadIdx.x, tx = blockIdx.x, ty = blockIdx.y;
    int r = tid >> 2, c0 = (tid & 3) * 16;
    const float* sp = src + (long)(ty * 64 + r) * src_ld + tx * 64 + c0;
#pragma unroll
    for (int i = 0; i < 4; ++i) {
        float4 f = *(const float4*)(sp + i * 4);
        tile[r][c0 + i * 4 + 0] = f.x;
        tile[r][c0 + i * 4 + 1] = f.y;
        tile[r][c0 + i * 4 + 2] = f.z;
        tile[r][c0 + i * 4 + 3] = f.w;
    }
    __syncthreads();
    int dl = tid >> 2, s0 = (tid & 3) * 16;
    unsigned short hh[16] __attribute__((aligned(16)));
    unsigned short ll[16] __attribute__((aligned(16)));
#pragma unroll
    for (int i = 0; i < 16; ++i) {
        float f = tile[s0 + i][dl];
        unsigned short h0 = f2bf(f);
        hh[i] = h0;
        ll[i] = f2bf(f - bf2f(h0));
    }
    long o = (long)(tx * 64 + dl) * dst_ld + ty * 64 + s0;
    *(uint4*)(dsthi + o) = ((uint4*)hh)[0];
    *(uint4*)(dsthi + o + 8) = ((uint4*)hh)[1];
    if (dstlo) {
        *(uint4*)(dstlo + o) = ((uint4*)ll)[0];
        *(uint4*)(dstlo + o + 8) = ((uint4*)ll)[1];
    }
}

// ---------------- LN1: f32 in -> split bf16 out ----------------
__global__ __launch_bounds__(256) void ln1_split(const float* __restrict__ in_f,
                                                 const float* __restrict__ sc,
                                                 const float* __restrict__ bi,
                                                 unsigned short* __restrict__ hi,
                                                 unsigned short* __restrict__ lo) {
    int row = blockIdx.x, tid = threadIdx.x;
    long base = (long)row * Dn;
    float x[3];
#pragma unroll
    for (int j = 0; j < 3; ++j) x[j] = in_f[base + tid + j * 256];
    __shared__ float red[4];
    float s = x[0] + x[1] + x[2];
    for (int off = 32; off; off >>= 1) s += __shfl_down(s, off, 64);
    if ((tid & 63) == 0) red[tid >> 6] = s;
    __syncthreads();
    float mean = (red[0] + red[1] + red[2] + red[3]) * (1.0f / Dn);
    __syncthreads();
    float ss = 0.f;
#pragma unroll
    for (int j = 0; j < 3; ++j) { float d0 = x[j] - mean; ss += d0 * d0; }
    for (int off = 32; off; off >>= 1) ss += __shfl_down(ss, off, 64);
    if ((tid & 63) == 0) red[tid >> 6] = ss;
    __syncthreads();
    float var = (red[0] + red[1] + red[2] + red[3]) * (1.0f / Dn);
    float rstd = 1.0f / sqrtf(var + 1e-5f);
#pragma unroll
    for (int j = 0; j < 3; ++j) {
        int d = tid + j * 256;
        float y = (x[j] - mean) * rstd * sc[d] + bi[d];
        unsigned short h0 = f2bf(y);
        hi[base + d] = h0;
        lo[base + d] = f2bf(y - bf2f(h0));
    }
}

// ---------------- LN2 fused with router (input = x2f + x residual) ----------------
__global__ __launch_bounds__(256) void ln2_router(const float* __restrict__ in_f,
                                                  const float* __restrict__ xres,
                                                  const float* __restrict__ sc,
                                                  const float* __restrict__ bi,
                                                  const float* __restrict__ rwt,
                                                  const float* __restrict__ rb,
                                                  const float* __restrict__ nb,
                                                  const float* __restrict__ noise,
                                                  unsigned short* __restrict__ h2hi,
                                                  float* __restrict__ gates,
                                                  int* __restrict__ ind) {
    int t = blockIdx.x, tid = threadIdx.x;
    int w = tid >> 6, lane = tid & 63;
    long base = (long)t * Dn;
    float x[3];
#pragma unroll
    for (int j = 0; j < 3; ++j) x[j] = in_f[base + tid + j * 256] + xres[base + tid + j * 256];
    __shared__ float red[4];
    float s = x[0] + x[1] + x[2];
    for (int off = 32; off; off >>= 1) s += __shfl_down(s, off, 64);
    if ((tid & 63) == 0) red[tid >> 6] = s;
    __syncthreads();
    float mean = (red[0] + red[1] + red[2] + red[3]) * (1.0f / Dn);
    __syncthreads();
    float ss = 0.f;
#pragma unroll
    for (int j = 0; j < 3; ++j) { float d0 = x[j] - mean; ss += d0 * d0; }
    for (int off = 32; off; off >>= 1) ss += __shfl_down(ss, off, 64);
    if ((tid & 63) == 0) red[tid >> 6] = ss;
    __syncthreads();
    float var = (red[0] + red[1] + red[2] + red[3]) * (1.0f / Dn);
    float rstd = 1.0f / sqrtf(var + 1e-5f);
    float y[3];
#pragma unroll
    for (int j = 0; j < 3; ++j) {
        int d = tid + j * 256;
        y[j] = (x[j] - mean) * rstd * sc[d] + bi[d];
        h2hi[base + d] = f2bf(y[j]);
    }
    float acc[16];
#pragma unroll
    for (int e = 0; e < 16; ++e) {
        const float* wp = rwt + e * Dn + tid;
        acc[e] = y[0] * wp[0] + y[1] * wp[256] + y[2] * wp[512];
    }
#pragma unroll
    for (int e = 0; e < 16; ++e)
        for (int off = 32; off; off >>= 1) acc[e] += __shfl_down(acc[e], off, 64);
    __shared__ float red2[4][16];
    if (lane == 0)
#pragma unroll
        for (int e = 0; e < 16; ++e) red2[w][e] = acc[e];
    __syncthreads();
    if (tid == 0) {
        float noisy[8];
#pragma unroll
        for (int e = 0; e < 8; ++e) {
            float lg = red2[0][e] + red2[1][e] + red2[2][e] + red2[3][e] + rb[e];
            float nv = red2[0][8 + e] + red2[1][8 + e] + red2[2][8 + e] + red2[3][8 + e] + nb[e];
            float sp = fmaxf(nv, 0.f) + log1pf(expf(-fabsf(nv)));
            noisy[e] = lg + noise[(long)t * En + e] * sp;
        }
        int i0 = 0;
        for (int e = 1; e < 8; ++e) if (noisy[e] > noisy[i0]) i0 = e;
        int i1 = (i0 == 0) ? 1 : 0;
        for (int e = 0; e < 8; ++e) if (e != i0 && noisy[e] > noisy[i1]) i1 = e;
        float mm = fmaxf(noisy[i0], noisy[i1]);
        float e0 = expf(noisy[i0] - mm), e1 = expf(noisy[i1] - mm);
        float inv = 1.0f / (e0 + e1);
        gates[t] = e0 * inv;
        gates[Tn + t] = e1 * inv;
        ind[t] = i0;
        ind[Tn + t] = i1;
    }
}

// ------ counting sort of 8192 (tok,slot); also inverse perm pos and tile prefixes ------
__global__ __launch_bounds__(1024) void sort_rows(const int* __restrict__ ind,
                                                  int* __restrict__ meta,
                                                  int* __restrict__ rows,
                                                  int* __restrict__ pos) {
    __shared__ int wtot[8][17];
    __shared__ int bb[8];
    int tid = threadIdx.x, wv = tid >> 6, ln = tid & 63;
    int codes[8];
    int h[8] = {0, 0, 0, 0, 0, 0, 0, 0};
#pragma unroll
    for (int k = 0; k < 8; ++k) {
        int i = tid * 8 + k;
        int e = ind[(i & 1) * Tn + (i >> 1)];
        codes[k] = e;
        ++h[e];
    }
    int pre[8];
#pragma unroll
    for (int e = 0; e < 8; ++e) {
        int x = h[e];
#pragma unroll
        for (int off = 1; off < 64; off <<= 1) {
            int y = __shfl_up(x, off, 64);
            if (ln >= off) x += y;
        }
        pre[e] = x - h[e];
        if (ln == 63) wtot[e][wv] = x;
    }
    __syncthreads();
    if (tid < 8) {
        int run = 0;
        for (int w2 = 0; w2 < 16; ++w2) {
            int v = wtot[tid][w2];
            wtot[tid][w2] = run;
            run += v;
        }
        wtot[tid][16] = run;
        meta[tid] = run;                 // counts
    }
    __syncthreads();
    if (tid == 0) {
        int b = 0, ct = 0;
        for (int e = 0; e < 8; ++e) {
            bb[e] = b;
            meta[16 + e] = b;
            b += wtot[e][16];
            meta[32 + e] = ct;           // tile prefix (128-row tiles)
            ct += (wtot[e][16] + 127) >> 7;
        }
        meta[24] = b;
        meta[40] = ct;                   // total tiles
    }
    __syncthreads();
    int c[8];
#pragma unroll
    for (int e = 0; e < 8; ++e) c[e] = bb[e] + wtot[e][wv] + pre[e];
#pragma unroll
    for (int k = 0; k < 8; ++k) {
        int e = codes[k];
        int code = tid * 8 + k;          // value == t*2+slot
        rows[c[e]] = code;
        pos[code] = c[e];
        ++c[e];
    }
}

// ---------------- tiny packers ----------------
__global__ void pack_router(const float* __restrict__ rw, const float* __restrict__ nw,
                            float* __restrict__ rwt) {
    int idx = blockIdx.x * 256 + threadIdx.x;   // [0, 16*768)
    int e = idx / Dn, d = idx - e * Dn;
    rwt[idx] = (e < 8) ? rw[d * En + e] : nw[d * En + (e - 8)];
}

__global__ void pack_bias(const float* __restrict__ bq, const float* __restrict__ bk,
                          const float* __restrict__ bv, float* __restrict__ bqkv) {
    int i = blockIdx.x * 256 + threadIdx.x;     // [0, 2304)
    bqkv[i] = (i < 768) ? bq[i] : (i < 1536 ? bk[i - 768] : bv[i - 1536]);
}

// ---------------- pure-bf16 split GEMM, 128x128 tile, 3-product, reg-pipelined ----------
// mode 0: f32 C store (or atomic), bias @ks==0  (o-proj)
// mode 1: QKV: cols [0,768)->q(*0.125), [768,1536)->k, [1536,2304)->v, split bf16 out
__global__ __launch_bounds__(256, 2) void gemm_bs(
    const unsigned short* __restrict__ Ahi, const unsigned short* __restrict__ Alo,
    int lda, long za,
    const unsigned short* __restrict__ Bhi, const unsigned short* __restrict__ Blo,
    int ldb, long zb,
    const float* __restrict__ bias,
    float* __restrict__ Cf, int ldc, long zc, int K, int zdiv, int catomic, int mode,
    unsigned short* __restrict__ oqh, unsigned short* __restrict__ oql,
    unsigned short* __restrict__ okh, unsigned short* __restrict__ okl,
    unsigned short* __restrict__ ovh, unsigned short* __restrict__ ovl) {
    int z = blockIdx.z;
    int zi = z / zdiv, ks = z - zi * zdiv;
    int Klen = K / zdiv, k0base = ks * Klen;
    Ahi += (long)zi * za;
    Alo += (long)zi * za;
    Bhi += (long)zi * zb;
    Blo += (long)zi * zb;
    int n0 = blockIdx.x * 128, m0 = blockIdx.y * 128;
    int tid = threadIdx.x, w = tid >> 6, lane = tid & 63, quad = lane >> 4, l16 = lane & 15;
    int wm = w >> 1, wn = w & 1;
    __shared__ unsigned short Ah[128][40], Al[128][40], Bh[128][40], Bl[128][40];
    v4f acc[4][4] = {};
    int ar = tid >> 1, ac = (tid & 1) * 16;
    const unsigned short* pah = Ahi + (long)(m0 + ar) * lda + k0base + ac;
    const unsigned short* pal = Alo + (long)(m0 + ar) * lda + k0base + ac;
    const unsigned short* pbh = Bhi + (long)(n0 + ar) * ldb + k0base + ac;
    const unsigned short* pbl = Blo + (long)(n0 + ar) * ldb + k0base + ac;
    int nsteps = Klen >> 5;
    uint4 ra0, ra1, rb0, rb1, rc0, rc1, rd0, rd1;
#define LOADK(kt) { int o_ = (kt) << 5; \
    ra0 = *(const uint4*)(pah + o_); ra1 = *(const uint4*)(pah + o_ + 8); \
    rb0 = *(const uint4*)(pal + o_); rb1 = *(const uint4*)(pal + o_ + 8); \
    rc0 = *(const uint4*)(pbh + o_); rc1 = *(const uint4*)(pbh + o_ + 8); \
    rd0 = *(const uint4*)(pbl + o_); rd1 = *(const uint4*)(pbl + o_ + 8); }
    LOADK(0);
    for (int kt = 0; kt < nsteps; ++kt) {
        *(uint4*)&Ah[ar][ac] = ra0;
        *(uint4*)&Ah[ar][ac + 8] = ra1;
        *(uint4*)&Al[ar][ac] = rb0;
        *(uint4*)&Al[ar][ac + 8] = rb1;
        *(uint4*)&Bh[ar][ac] = rc0;
        *(uint4*)&Bh[ar][ac + 8] = rc1;
        *(uint4*)&Bl[ar][ac] = rd0;
        *(uint4*)&Bl[ar][ac + 8] = rd1;
        __syncthreads();
        if (kt + 1 < nsteps) LOADK(kt + 1);   // issue early; hides under MFMA
        v8s afh[4], afl[4];
#pragma unroll
        for (int mt = 0; mt < 4; ++mt) {
            afh[mt] = *(const v8s*)&Ah[wm * 64 + mt * 16 + l16][quad * 8];
            afl[mt] = *(const v8s*)&Al[wm * 64 + mt * 16 + l16][quad * 8];
        }
#pragma unroll
        for (int nt = 0; nt < 4; ++nt) {
            v8s bbh = *(const v8s*)&Bh[wn * 64 + nt * 16 + l16][quad * 8];
            v8s bbl = *(const v8s*)&Bl[wn * 64 + nt * 16 + l16][quad * 8];
#pragma unroll
            for (int mt = 0; mt < 4; ++mt) acc[mt][nt] = mfma16(afh[mt], bbh, acc[mt][nt]);
#pragma unroll
            for (int mt = 0; mt < 4; ++mt) acc[mt][nt] = mfma16(afl[mt], bbh, acc[mt][nt]);
#pragma unroll
            for (int mt = 0; mt < 4; ++mt) acc[mt][nt] = mfma16(afh[mt], bbl, acc[mt][nt]);
        }
        __syncthreads();
    }
#undef LOADK
    if (mode == 1) {
#pragma unroll
        for (int mt = 0; mt < 4; ++mt)
#pragma unroll
            for (int nt = 0; nt < 4; ++nt)
#pragma unroll
                for (int r = 0; r < 4; ++r) {
                    int row = m0 + wm * 64 + mt * 16 + quad * 4 + r;
                    int col = n0 + wn * 64 + nt * 16 + l16;
                    float v = acc[mt][nt][r] + bias[col];
                    int seg = (col >= 1536) ? 2 : (col >= 768 ? 1 : 0);
                    int c = col - seg * 768;
                    if (seg == 0) v *= 0.125f;   // fold 1/sqrt(HD) into q
                    long ci = (long)row * Dn + c;
                    unsigned short* dh = (seg == 0) ? oqh : (seg == 1 ? okh : ovh);
                    unsigned short* dl = (seg == 0) ? oql : (seg == 1 ? okl : ovl);
                    unsigned short h0 = f2bf(v);
                    dh[ci] = h0;
                    dl[ci] = f2bf(v - bf2f(h0));
                }
    } else {
        long coff = (long)zi * zc;
#pragma unroll
        for (int mt = 0; mt < 4; ++mt)
#pragma unroll
            for (int nt = 0; nt < 4; ++nt)
#pragma unroll
                for (int r = 0; r < 4; ++r) {
                    int row = m0 + wm * 64 + mt * 16 + quad * 4 + r;
                    int col = n0 + wn * 64 + nt * 16 + l16;
                    float v = acc[mt][nt][r];
                    if (ks == 0 && bias) v += bias[col];
                    long ci = coff + (long)row * ldc + col;
                    if (catomic) atomicAdd(&Cf[ci], v);
                    else Cf[ci] = v;
                }
    }
}

// ---------------- flash attention: one block = (q-tile 128) x (b,h) ----------------
// Q pre-scaled by 1/8. No max-shift (|s| small). O normalized in-reg, written as
// split bf16 over the (block-exclusive, consumed) Q region.
__global__ __launch_bounds__(256) void flash_attn(
    const unsigned short* __restrict__ qhi, const unsigned short* __restrict__ qlo,
    const unsigned short* __restrict__ khi, const unsigned short* __restrict__ klo,
    const unsigned short* __restrict__ vthi, const unsigned short* __restrict__ vtlo,
    unsigned short* __restrict__ ohi, unsigned short* __restrict__ olo) {
    int g = blockIdx.y, b = g / NHn, h = g - b * NHn;
    int m0 = blockIdx.x * 128;
    int tid = threadIdx.x, w = tid >> 6, lane = tid & 63, quad = lane >> 4, l16 = lane & 15;
    __shared__ unsigned short Kh[2][64][40], Kl[2][64][40];
    __shared__ unsigned short Vh[2][64][40], Vl[2][64][40];
    __shared__ unsigned short Ph[4][2][32][40];   // per-wave P (hi only)
    // Q fragments in registers (rows m0+w*32+mt*16+l16, d = kk*32+quad*8+..)
    v8s qh[2][2], ql[2][2];
    long qrow0 = (long)b * Sn + m0 + w * 32;
#pragma unroll
    for (int mt = 0; mt < 2; ++mt)
#pragma unroll
        for (int kk = 0; kk < 2; ++kk) {
            long off = (qrow0 + mt * 16 + l16) * Dn + h * 64 + kk * 32 + quad * 8;
            qh[mt][kk] = *(const v8s*)(qhi + off);
            ql[mt][kk] = *(const v8s*)(qlo + off);
        }
    v4f accO[2][4] = {};
    float rs[2][4] = {};
    // staging thread mapping: srow in [0,32), su selects (kk, 8-col chunk)
    int srow = tid >> 3, su = tid & 7, skk = su >> 2, scu = (su & 3) * 8;
    const unsigned short* kb_h = khi + ((long)b * Sn + srow) * Dn + h * 64 + skk * 32 + scu;
    const unsigned short* kb_l = klo + ((long)b * Sn + srow) * Dn + h * 64 + skk * 32 + scu;
    const unsigned short* vb_h = vthi + ((long)g * 64 + srow) * Sn + skk * 32 + scu;
    const unsigned short* vb_l = vtlo + ((long)g * 64 + srow) * Sn + skk * 32 + scu;
    uint4 pkh0, pkh1, pkl0, pkl1, pvh0, pvh1, pvl0, pvl1;
#define LOADT(t) { long ko = (long)(t) * 64 * Dn; int vo = (t) * 64; \
    pkh0 = *(const uint4*)(kb_h + ko); pkh1 = *(const uint4*)(kb_h + ko + (long)32 * Dn); \
    pkl0 = *(const uint4*)(kb_l + ko); pkl1 = *(const uint4*)(kb_l + ko + (long)32 * Dn); \
    pvh0 = *(const uint4*)(vb_h + vo); pvh1 = *(const uint4*)(vb_h + vo + 32 * Sn); \
    pvl0 = *(const uint4*)(vb_l + vo); pvl1 = *(const uint4*)(vb_l + vo + 32 * Sn); }
    LOADT(0);
    for (int t = 0; t < 16; ++t) {
        __syncthreads();                 // prev iter's K/V reads done
        *(uint4*)&Kh[skk][srow][scu] = pkh0;
        *(uint4*)&Kh[skk][srow + 32][scu] = pkh1;
        *(uint4*)&Kl[skk][srow][scu] = pkl0;
        *(uint4*)&Kl[skk][srow + 32][scu] = pkl1;
        *(uint4*)&Vh[skk][srow][scu] = pvh0;
        *(uint4*)&Vh[skk][srow + 32][scu] = pvh1;
        *(uint4*)&Vl[skk][srow][scu] = pvl0;
        *(uint4*)&Vl[skk][srow + 32][scu] = pvl1;
        __syncthreads();
        if (t < 15) LOADT(t + 1);        // latency hides under compute
        // ---- S = Q K^T (3-product split) ----
        v4f accS[2][4] = {};
#pragma unroll
        for (int nt = 0; nt < 4; ++nt)
#pragma unroll
            for (int kk = 0; kk < 2; ++kk) {
                v8s bh = *(const v8s*)&Kh[kk][nt * 16 + l16][quad * 8];
                v8s bl = *(const v8s*)&Kl[kk][nt * 16 + l16][quad * 8];
#pragma unroll
                for (int mt = 0; mt < 2; ++mt) {
                    accS[mt][nt] = mfma16(qh[mt][kk], bh, accS[mt][nt]);
                    accS[mt][nt] = mfma16(ql[mt][kk], bh, accS[mt][nt]);
                    accS[mt][nt] = mfma16(qh[mt][kk], bl, accS[mt][nt]);
                }
            }
        // ---- P = exp(S) -> bf16 in wave-private LDS; rowsum of quantized P ----
#pragma unroll
        for (int mt = 0; mt < 2; ++mt)
#pragma unroll
            for (int r = 0; r < 4; ++r) {
                int prow = mt * 16 + quad * 4 + r;
                float psum = 0.f;
#pragma unroll
                for (int nt = 0; nt < 4; ++nt) {
                    float p = __expf(accS[mt][nt][r]);
                    unsigned short hh = f2bf(p);
                    psum += bf2f(hh);    // normalize exactly what PV consumes
                    Ph[w][nt >> 1][prow][(nt & 1) * 16 + l16] = hh;
                }
                rs[mt][r] += psum;
            }
        // ---- O += P V (P-hi x split-V) ----
#pragma unroll
        for (int kk = 0; kk < 2; ++kk) {
            v8s pa0 = *(const v8s*)&Ph[w][kk][l16][quad * 8];
            v8s pa1 = *(const v8s*)&Ph[w][kk][16 + l16][quad * 8];
#pragma unroll
            for (int nt = 0; nt < 4; ++nt) {
                v8s vh = *(const v8s*)&Vh[kk][nt * 16 + l16][quad * 8];
                v8s vl = *(const v8s*)&Vl[kk][nt * 16 + l16][quad * 8];
                accO[0][nt] = mfma16(pa0, vh, accO[0][nt]);
                accO[1][nt] = mfma16(pa1, vh, accO[1][nt]);
                accO[0][nt] = mfma16(pa0, vl, accO[0][nt]);
                accO[1][nt] = mfma16(pa1, vl, accO[1][nt]);
            }
        }
    }
#undef LOADT
    // ---- epilogue: finish rowsums (16-lane reduce), normalize, write split bf16 ----
#pragma unroll
    for (int mt = 0; mt < 2; ++mt)
#pragma unroll
        for (int r = 0; r < 4; ++r) {
            float s = rs[mt][r];
#pragma unroll
            for (int off = 1; off < 16; off <<= 1) s += __shfl_xor(s, off, 64);
            float inv = 1.0f / s;
            long orow = qrow0 + mt * 16 + quad * 4 + r;
#pragma unroll
            for (int nt = 0; nt < 4; ++nt) {
                float v = accO[mt][nt][r] * inv;
                unsigned short hh = f2bf(v);
                long oi = orow * Dn + h * 64 + nt * 16 + l16;
                ohi[oi] = hh;
                olo[oi] = f2bf(v - bf2f(hh));
            }
        }
}

// ---------------- V transpose (bf16 hi/lo): v[b,s,h,d] -> vt[g=b*12+h][d][s] ----------
__global__ __launch_bounds__(256) void vtrans16(const unsigned short* __restrict__ vhi,
                                                const unsigned short* __restrict__ vlo,
                                                unsigned short* __restrict__ vthi,
                                                unsigned short* __restrict__ vtlo) {
    int g = blockIdx.z, b = g / NHn, h = g % NHn;
    int stile = blockIdx.x, tid = threadIdx.x;
    __shared__ unsigned short th[64][66], tl[64][66];
    int sl = tid >> 2, c0 = (tid & 3) * 16;
    long src = (long)(b * Sn + stile * 64 + sl) * Dn + h * 64 + c0;
    *(uint4*)&th[sl][c0] = *(const uint4*)(vhi + src);
    *(uint4*)&th[sl][c0 + 8] = *(const uint4*)(vhi + src + 8);
    *(uint4*)&tl[sl][c0] = *(const uint4*)(vlo + src);
    *(uint4*)&tl[sl][c0 + 8] = *(const uint4*)(vlo + src + 8);
    __syncthreads();
    int dl = tid >> 2, s0 = (tid & 3) * 16;
    unsigned short hh[16] __attribute__((aligned(16)));
    unsigned short ll[16] __attribute__((aligned(16)));
#pragma unroll
    for (int i = 0; i < 16; ++i) {
        hh[i] = th[s0 + i][dl];
        ll[i] = tl[s0 + i][dl];
    }
    long o = (long)(g * 64 + dl) * Sn + stile * 64 + s0;
    *(uint4*)(vthi + o) = ((uint4*)hh)[0];
    *(uint4*)(vthi + o + 8) = ((uint4*)hh)[1];
    *(uint4*)(vtlo + o) = ((uint4*)ll)[0];
    *(uint4*)(vtlo + o + 8) = ((uint4*)ll)[1];
}

// ---- MoE stage 1 (per DFF half): eh = relu(h2 @ W1t[e]^T + b1), flat grid + XCD swizzle ----
__global__ __launch_bounds__(256, 2) void moe_gemm1(const unsigned short* __restrict__ h2hi,
                                                    const unsigned short* __restrict__ W1t,
                                                    const float* __restrict__ eb1,
                                                    const int* __restrict__ rows,
                                                    const int* __restrict__ meta,
                                                    unsigned short* __restrict__ eh,
                                                    int half) {
    // flat (x=12 n-tiles, y=YT tiles) with XCD chunk swizzle
    int l = blockIdx.x + 12 * blockIdx.y;
    constexpr int L1 = 12 * YT;                       // 864, %8==0
    int nl = (l & 7) * (L1 >> 3) + (l >> 3);
    int vy = nl / 12, vx = nl - vy * 12;
    if (vy >= meta[40]) return;
    int e = 0;
#pragma unroll
    for (int i = 1; i < 8; ++i) if (meta[32 + i] <= vy) e = i;
    int mb = (vy - meta[32 + e]) * 128;
    int cnt = meta[e];
    int base_e = meta[16 + e];
    int valid = cnt - mb; if (valid > 128) valid = 128;
    int tid = threadIdx.x;
    __shared__ int toks[128];
    if (tid < 128) {
        int idx = mb + tid;
        toks[tid] = rows[base_e + (idx < cnt ? idx : 0)];
    }
    __shared__ unsigned short As[128][40], Bs[128][40];
    int w = tid >> 6, lane = tid & 63, quad = lane >> 4, l16 = lane & 15;
    int wm = w >> 1, wn = w & 1;
    v4f acc[4][4] = {};
    int ar = tid >> 1, ac = (tid & 1) * 16;
    int nb0 = vx * 128;
    const unsigned short* Wb = W1t + (long)e * DHALF * Dn;
    __syncthreads();
    const unsigned short* apg = h2hi + (long)(toks[ar] >> 1) * Dn + ac;
    const unsigned short* bpg = Wb + (long)(nb0 + ar) * Dn + ac;
    uint4 a0, a1, b0, b1;
#define LOADK(kt) { int o_ = (kt) * 32; \
    a0 = *(const uint4*)(apg + o_); a1 = *(const uint4*)(apg + o_ + 8); \
    b0 = *(const uint4*)(bpg + o_); b1 = *(const uint4*)(bpg + o_ + 8); }
    LOADK(0);
    for (int kt = 0; kt < Dn / 32; ++kt) {
        *(uint4*)&As[ar][ac] = a0;
        *(uint4*)&As[ar][ac + 8] = a1;
        *(uint4*)&Bs[ar][ac] = b0;
        *(uint4*)&Bs[ar][ac + 8] = b1;
        __syncthreads();
        if (kt + 1 < Dn / 32) LOADK(kt + 1);
        v8s af[4];
#pragma unroll
        for (int mt = 0; mt < 4; ++mt) af[mt] = *(const v8s*)&As[wm * 64 + mt * 16 + l16][quad * 8];
#pragma unroll
        for (int nt = 0; nt < 4; ++nt) {
            v8s bb = *(const v8s*)&Bs[wn * 64 + nt * 16 + l16][quad * 8];
#pragma unroll
            for (int mt = 0; mt < 4; ++mt) acc[mt][nt] = mfma16(af[mt], bb, acc[mt][nt]);
        }
        __syncthreads();
    }
#undef LOADK
#pragma unroll
    for (int mt = 0; mt < 4; ++mt)
#pragma unroll
        for (int nt = 0; nt < 4; ++nt)
#pragma unroll
            for (int r = 0; r < 4; ++r) {
                int rl = wm * 64 + mt * 16 + quad * 4 + r;
                if (rl < valid) {
                    int col = nb0 + wn * 64 + nt * 16 + l16;
                    float v = acc[mt][nt][r] + eb1[e * DFFn + half * DHALF + col];
                    v = fmaxf(v, 0.f);
                    eh[(long)(base_e + mb + rl) * DHALF + col] = f2bf(v);
                }
            }
}

// -- MoE stage 2 (per DFF half, K-split x2 into eo0/eo1, NO atomics), flat grid + swizzle --
// ks=blockIdx.z -> eo0/eo1 (bf16 [NROWS][Dn]); half0 stores, half1 read-add-stores.
__global__ __launch_bounds__(256, 2) void moe_gemm2(const unsigned short* __restrict__ eh,
                                                    const unsigned short* __restrict__ W2t,
                                                    const float* __restrict__ eb2,
                                                    const int* __restrict__ meta,
                                                    unsigned short* __restrict__ eo0,
                                                    unsigned short* __restrict__ eo1,
                                                    int accum) {
    int ks = blockIdx.z;
    int k0b = ks * (DHALF / 2);
    int l = blockIdx.x + 6 * blockIdx.y;
    constexpr int L2 = 6 * YT;                        // 432, %8==0
    int nl = (l & 7) * (L2 >> 3) + (l >> 3);
    int vy = nl / 6, vx = nl - vy * 6;
    if (vy >= meta[40]) return;
    int e = 0;
#pragma unroll
    for (int i = 1; i < 8; ++i) if (meta[32 + i] <= vy) e = i;
    int mb = (vy - meta[32 + e]) * 128;
    int cnt = meta[e];
    int base_e = meta[16 + e];
    int valid = cnt - mb; if (valid > 128) valid = 128;
    int tid = threadIdx.x;
    __shared__ unsigned short As[128][40], Bs[128][40];
    int w = tid >> 6, lane = tid & 63, quad = lane >> 4, l16 = lane & 15;
    int wm = w >> 1, wn = w & 1;
    v4f acc[4][4] = {};
    int ar = tid >> 1, ac = (tid & 1) * 16;
    int nb0 = vx * 128;
    const unsigned short* Wb = W2t + (long)e * Dn * DHALF;
    long arow = (long)base_e + mb + ar;
    if (arow > NROWS - 1) arow = NROWS - 1;
    const unsigned short* apg = eh + arow * DHALF + k0b + ac;
    const unsigned short* bpg = Wb + (long)(nb0 + ar) * DHALF + k0b + ac;
    uint4 a0, a1, b0, b1;
#define LOADK(kt) { int o_ = (kt) * 32; \
    a0 = *(const uint4*)(apg + o_); a1 = *(const uint4*)(apg + o_ + 8); \
    b0 = *(const uint4*)(bpg + o_); b1 = *(const uint4*)(bpg + o_ + 8); }
    LOADK(0);
    constexpr int NK = (DHALF / 2) / 32;   // 24
    for (int kt = 0; kt < NK; ++kt) {
        *(uint4*)&As[ar][ac] = a0;
        *(uint4*)&As[ar][ac + 8] = a1;
        *(uint4*)&Bs[ar][ac] = b0;
        *(uint4*)&Bs[ar][ac + 8] = b1;
        __syncthreads();
        if (kt + 1 < NK) LOADK(kt + 1);
        v8s af[4];
#pragma unroll
        for (int mt = 0; mt < 4; ++mt) af[mt] = *(const v8s*)&As[wm * 64 + mt * 16 + l16][quad * 8];
#pragma unroll
        for (int nt = 0; nt < 4; ++nt) {
            v8s bb = *(const v8s*)&Bs[wn * 64 + nt * 16 + l16][quad * 8];
#pragma unroll
            for (int mt = 0; mt < 4; ++mt) acc[mt][nt] = mfma16(af[mt], bb, acc[mt][nt]);
        }
        __syncthreads();
    }
#undef LOADK
    unsigned short* eo = ks ? eo1 : eo0;
#pragma unroll
    for (int mt = 0; mt < 4; ++mt)
#pragma unroll
        for (int nt = 0; nt < 4; ++nt)
#pragma unroll
            for (int r = 0; r < 4; ++r) {
                int rl = wm * 64 + mt * 16 + quad * 4 + r;
                if (rl < valid) {
                    int col = nb0 + wn * 64 + nt * 16 + l16;
                    long idx = (long)(base_e + mb + rl) * Dn + col;
                    float v = acc[mt][nt][r];
                    if (eb2 && ks == 0) v += eb2[e * Dn + col];
                    if (accum) v += bf2f(eo[idx]);
                    eo[idx] = f2bf(v);
                }
            }
}

// ---------------- final: out = x + x2f + g0*(eo0+eo1)[pos0] + g1*(eo0+eo1)[pos1] --------
__global__ __launch_bounds__(256) void final_add(const float* __restrict__ x2f,
                                                 const float* __restrict__ xres,
                                                 const unsigned short* __restrict__ eo0,
                                                 const unsigned short* __restrict__ eo1,
                                                 const float* __restrict__ gates,
                                                 const int* __restrict__ pos,
                                                 float* __restrict__ out) {
    int t = blockIdx.x, tid = threadIdx.x;
    int p0 = pos[2 * t], p1 = pos[2 * t + 1];
    float g0 = gates[t], g1 = gates[Tn + t];
    long b0 = (long)p0 * Dn, b1 = (long)p1 * Dn;
    long xb = (long)t * Dn;
#pragma unroll
    for (int j = 0; j < 3; ++j) {
        int d = tid + j * 256;
        float m0 = bf2f(eo0[b0 + d]) + bf2f(eo1[b0 + d]);
        float m1 = bf2f(eo0[b1 + d]) + bf2f(eo1[b1 + d]);
        out[xb + d] = x2f[xb + d] + xres[xb + d] + g0 * m0 + g1 * m1;
    }
}

extern "C" void kernel_launch(void* const* d_in, const int* in_sizes, int n_in,
                              void* d_out, int out_size, void* d_ws, size_t ws_size,
                              hipStream_t stream) {
    const float* x     = (const float*)d_in[0];
    const float* noise = (const float*)d_in[1];
    const float* wq = (const float*)d_in[2];
    const float* bq = (const float*)d_in[3];
    const float* wk = (const float*)d_in[4];
    const float* bk = (const float*)d_in[5];
    const float* wv = (const float*)d_in[6];
    const float* bv = (const float*)d_in[7];
    const float* wo = (const float*)d_in[8];
    const float* bo = (const float*)d_in[9];
    const float* ln1_s = (const float*)d_in[10];
    const float* ln1_b = (const float*)d_in[11];
    const float* ln2_s = (const float*)d_in[12];
    const float* ln2_b = (const float*)d_in[13];
    const float* r_w = (const float*)d_in[14];
    const float* r_b = (const float*)d_in[15];
    const float* n_w = (const float*)d_in[16];
    const float* n_b = (const float*)d_in[17];
    const float* e_w1 = (const float*)d_in[18];
    const float* e_b1 = (const float*)d_in[19];
    const float* e_w2 = (const float*)d_in[20];
    const float* e_b2 = (const float*)d_in[21];

    char* ws = (char*)d_ws;
    unsigned short* qhi  = (unsigned short*)(ws + 0);
    unsigned short* qlo  = (unsigned short*)(ws + 6 * MB);
    unsigned short* ohi  = qhi;                              // flash writes O over Q
    unsigned short* olo  = qlo;
    unsigned short* eo1  = (unsigned short*)(ws + 0);        // era D (o dead)
    unsigned short* h1hi = (unsigned short*)(ws + 12 * MB);  // era A
    unsigned short* h1lo = (unsigned short*)(ws + 18 * MB);
    unsigned short* eh   = (unsigned short*)(ws + 12 * MB);  // era D (24 MB)
    unsigned short* khi  = (unsigned short*)(ws + 24 * MB);
    unsigned short* klo  = (unsigned short*)(ws + 30 * MB);
    unsigned short* eo0  = (unsigned short*)(ws + 36 * MB);  // era D (12 MB bf16)
    unsigned short* vhi  = (unsigned short*)(ws + 48 * MB);  // era A
    unsigned short* vlo  = (unsigned short*)(ws + 54 * MB);
    float* x2f  = (float*)(ws + 48 * MB);                    // era C/D (v dead)
    unsigned short* whalf = (unsigned short*)(ws + 60 * MB); // era D (18 MB)
    unsigned short* vthi = (unsigned short*)(ws + 72 * MB);
    unsigned short* vtlo = (unsigned short*)(ws + 78 * MB);
    unsigned short* h2hi  = (unsigned short*)(ws + 78 * MB); // era D (vtlo dead)
    unsigned short* wqkvTh = (unsigned short*)(ws + 84 * MB);          // [2304][768]
    unsigned short* wqkvTl = wqkvTh + (size_t)3 * Dn * Dn;
    unsigned short* woTh = wqkvTl + (size_t)3 * Dn * Dn;
    unsigned short* woTl = woTh + (size_t)Dn * Dn;
    char* misc = (char*)(woTl + (size_t)Dn * Dn);
    float* bqkv = (float*)misc;                          // 2304 f
    float* rwt  = (float*)(misc + 2304 * 4);             // 16*768 f
    float* gates = (float*)(misc + 2304 * 4 + 12288 * 4);
    int* ind  = (int*)((char*)gates + 2 * Tn * 4);
    int* meta = (int*)((char*)ind + 2 * Tn * 4);
    int* rows = (int*)((char*)meta + 256);
    int* pos  = rows + NROWS;

    dim3 blk(256);
    // packed QKV weight transpose ([D,D] f32 -> bf16 hi/lo rows of [2304][768])
    transpose_f32<<<dim3(12, 12, 1), blk, 0, stream>>>(wq, Dn, 0, wqkvTh, wqkvTl, Dn, 0);
    transpose_f32<<<dim3(12, 12, 1), blk, 0, stream>>>(wk, Dn, 0,
        wqkvTh + (size_t)Dn * Dn, wqkvTl + (size_t)Dn * Dn, Dn, 0);
    transpose_f32<<<dim3(12, 12, 1), blk, 0, stream>>>(wv, Dn, 0,
        wqkvTh + (size_t)2 * Dn * Dn, wqkvTl + (size_t)2 * Dn * Dn, Dn, 0);
    transpose_f32<<<dim3(12, 12, 1), blk, 0, stream>>>(wo, Dn, 0, woTh, woTl, Dn, 0);
    pack_bias<<<dim3(9), blk, 0, stream>>>(bq, bk, bv, bqkv);
    pack_router<<<dim3(48), blk, 0, stream>>>(r_w, n_w, rwt);
    // LN1 -> split bf16
    ln1_split<<<dim3(Tn), blk, 0, stream>>>(x, ln1_s, ln1_b, h1hi, h1lo);
    // fused QKV: pipelined split GEMM, direct split-bf16 epilogue (q pre-scaled 1/8)
    gemm_bs<<<dim3(18, 32, 1), blk, 0, stream>>>(h1hi, h1lo, Dn, 0, wqkvTh, wqkvTl, Dn, 0,
        bqkv, nullptr, 0, 0, Dn, 1, 0, 1, qhi, qlo, khi, klo, vhi, vlo);
    vtrans16<<<dim3(16, 1, 48), blk, 0, stream>>>(vhi, vlo, vthi, vtlo);
    // flash attention: 1 launch; writes split-bf16 O over the Q region
    flash_attn<<<dim3(8, 48), blk, 0, stream>>>(qhi, qlo, khi, klo, vthi, vtlo, ohi, olo);
    // output projection (direct store) -> x2f
    gemm_bs<<<dim3(6, 32, 1), blk, 0, stream>>>(ohi, olo, Dn, 0, woTh, woTl, Dn, 0,
        bo, x2f, Dn, 0, Dn, 1, 0, 0, nullptr, nullptr, nullptr, nullptr, nullptr, nullptr);
    // LN2 + router fused (residual x added on the fly; h2 stored bf16 for MoE)
    ln2_router<<<dim3(Tn), blk, 0, stream>>>(x2f, x, ln2_s, ln2_b, rwt, r_b, n_b, noise,
                                             h2hi, gates, ind);
    sort_rows<<<dim3(1), dim3(1024), 0, stream>>>(ind, meta, rows, pos);
    // sparse experts, two DFF halves through one 18 MB transposed-weight region
    for (int h = 0; h < 2; ++h) {
        transpose_f32<<<dim3(24, 12, 8), blk, 0, stream>>>(
            e_w1 + (size_t)h * DHALF, DFFn, (long)Dn * DFFn, whalf, nullptr, Dn, (long)DHALF * Dn);
        moe_gemm1<<<dim3(12, YT, 1), blk, 0, stream>>>(h2hi, whalf, e_b1, rows, meta, eh, h);
        transpose_f32<<<dim3(12, 24, 8), blk, 0, stream>>>(
            e_w2 + (size_t)h * DHALF * Dn, Dn, (long)DFFn * Dn, whalf, nullptr, DHALF, (long)Dn * DHALF);
        moe_gemm2<<<dim3(6, YT, 2), blk, 0, stream>>>(eh, whalf, h == 0 ? e_b2 : nullptr,
                                                      meta, eo0, eo1, h);
    }
    final_add<<<dim3(Tn), blk, 0, stream>>>(x2f, x, eo0, eo1, gates, pos, (float*)d_out);
}